// Round 2
// baseline (13541.185 us; speedup 1.0000x reference)
//
#include <hip/hip_runtime.h>

typedef unsigned int uint;
typedef unsigned long long u64;

__device__ __forceinline__ uint brev8(uint x){ return __brev(x) >> 24; }
__device__ __forceinline__ float geluf(float x){
  return 0.5f*x*(1.f + tanhf(0.7978845608028654f*(x + 0.044715f*x*x*x)));
}

// ---------------- pooled mean (global, all 4 batches) ----------------
__global__ __launch_bounds__(256) void kern_pool(const float* __restrict__ vis,
                                                 const float* __restrict__ irf,
                                                 float* __restrict__ pooled){
  __shared__ float red[256];
  int bc = blockIdx.x;            // b*128 + cc
  int b = bc >> 7, cc = bc & 127;
  const float* src = (cc < 64) ? (vis + (size_t)(b*64+cc)*65536)
                               : (irf + (size_t)(b*64+(cc-64))*65536);
  float s = 0.f;
  for (int i = threadIdx.x; i < 65536; i += 256) s += src[i];
  red[threadIdx.x] = s;
  __syncthreads();
  for (int off = 128; off > 0; off >>= 1){
    if (threadIdx.x < off) red[threadIdx.x] += red[threadIdx.x + off];
    __syncthreads();
  }
  if (threadIdx.x == 0) pooled[bc] = red[0] * (1.f/65536.f);
}

// ---------------- prompt/intent/affine small ops (global) ----------------
__global__ __launch_bounds__(256) void kern_small(const float* __restrict__ pooled,
    const float* __restrict__ Wr, const float* __restrict__ br,
    const float* __restrict__ bank, const float* __restrict__ Wpri,
    const float* __restrict__ Wint, const float* __restrict__ Wa1,
    const float* __restrict__ ba1, const float* __restrict__ Wa2,
    const float* __restrict__ ba2,
    float* __restrict__ IP, float* __restrict__ IPint,
    float* __restrict__ modg, float* __restrict__ modb){
  __shared__ float logit_s[16];
  __shared__ float pw_s[16];
  __shared__ float intent_s[4][64];
  __shared__ float t1_s[4][128];
  int t = threadIdx.x;
  if (t < 16){
    int b = t >> 2, j = t & 3;
    float s = br[j];
    for (int k = 0; k < 128; ++k) s += pooled[b*128+k]*Wr[k*4+j];
    logit_s[t] = s;
  }
  __syncthreads();
  if (t < 4){
    int b = t;
    float m = logit_s[b*4];
    for (int j = 1; j < 4; ++j) m = fmaxf(m, logit_s[b*4+j]);
    float e[4], sum = 0.f;
    for (int j = 0; j < 4; ++j){ e[j] = expf(logit_s[b*4+j]-m); sum += e[j]; }
    for (int j = 0; j < 4; ++j) pw_s[b*4+j] = e[j]/sum;
  }
  __syncthreads();
  {
    int b = t >> 6, p = t & 63;
    float s = 0.f;
    for (int j = 0; j < 4; ++j) s += pw_s[b*4+j]*bank[j*64+p];
    intent_s[b][p] = s;
  }
  __syncthreads();
  for (int o = t; o < 1024; o += 256){
    int i = o >> 9, rem = o & 511, b = rem >> 7, n = rem & 127;
    float s1 = 0.f, s2 = 0.f;
    for (int p = 0; p < 64; ++p){
      float iv = intent_s[b][p];
      s1 += iv * Wpri[(i*64+p)*128 + n];
      s2 += iv * Wint[(i*64+p)*128 + n];
    }
    IP[o] = s1; IPint[o] = s2;
  }
  for (int o = t; o < 512; o += 256){
    int b = o >> 7, n = o & 127;
    float s = ba1[n];
    for (int p = 0; p < 64; ++p) s += intent_s[b][p]*Wa1[p*128+n];
    t1_s[b][n] = geluf(s);
  }
  __syncthreads();
  for (int o = t; o < 512; o += 256){
    int b = o >> 7, n = o & 127;
    float s = ba2[n];
    for (int p = 0; p < 128; ++p) s += t1_s[b][p]*Wa2[p*128+n];
    if (n < 64) modg[b*64+n] = 1.f + 0.1f*tanhf(s);
    else        modb[b*64+(n-64)] = 0.1f*s;
  }
}

// ---------------- coords @ Wco + bs, per branch (batch-independent) ----------------
__global__ __launch_bounds__(256) void kern_cwb(const float* __restrict__ Wco,
    const float* __restrict__ bs, float* __restrict__ CWB){
  int o = blockIdx.x*256 + threadIdx.x;   // 2*4096*128 total
  int i = o >> 19, rem = o & 524287;
  int g = rem >> 7, n = rem & 127;
  int gy = g >> 6, gx = g & 63;
  float cy = ((float)gy + 0.5f)*(1.f/64.f);
  float cx = ((float)gx + 0.5f)*(1.f/64.f);
  CWB[o] = cy*Wco[i*256 + n] + cx*Wco[i*256 + 128 + n] + bs[i*128 + n];
}

// ---------------- forward row FFT (real input), slab-relative ----------------
__global__ __launch_bounds__(256) void kern_fft_rows_fwd(const float* __restrict__ x,
    float* __restrict__ sre, float* __restrict__ sim){
  __shared__ float re[2][256], im[2][256];
  int t = threadIdx.x;
  int r = t >> 7, jj = t & 127;
  size_t row = (size_t)blockIdx.x*2 + r;   // flat row over (b,c,h) within slab
  {
    const float* xp = x + row*256;
    re[r][jj] = xp[jj]; re[r][jj+128] = xp[jj+128];
    im[r][jj] = 0.f;    im[r][jj+128] = 0.f;
  }
  __syncthreads();
  for (int s = 0; s < 8; ++s){
    int half = 128 >> s;
    int j = jj & (half-1);
    int g = jj >> (7-s);
    int k = (g << (8-s)) + j;
    float ang = -6.2831853071795864f * (float)j / (float)(half << 1);
    float ws, wc; sincosf(ang, &ws, &wc);
    float are = re[r][k],      aim = im[r][k];
    float bre = re[r][k+half], bim = im[r][k+half];
    re[r][k] = are + bre; im[r][k] = aim + bim;
    float tr = are - bre, ti = aim - bim;
    re[r][k+half] = tr*wc - ti*ws;
    im[r][k+half] = tr*ws + ti*wc;
    __syncthreads();
  }
  {
    float* orp = sre + row*256; float* oip = sim + row*256;
    int w1 = jj, w2 = jj + 128;
    orp[w1] = re[r][brev8(w1)]; oip[w1] = im[r][brev8(w1)];
    orp[w2] = re[r][brev8(w2)]; oip[w2] = im[r][brev8(w2)];
  }
}

// ---------------- inverse row FFT with spec construction (reads patchified amp/ph) ----
__global__ __launch_bounds__(256) void kern_ifft_rows_spec(const float* __restrict__ famp,
    const float* __restrict__ fph, float* __restrict__ sre, float* __restrict__ sim){
  __shared__ float re[4][256], im[4][256];
  int t = threadIdx.x;
  int R = blockIdx.x * 4;
  {
    int r = t >> 6, q = t & 63;
    int row = R + r;
    int bc = row >> 8, h = row & 255;
    int b = bc >> 6, c = bc & 63;
    size_t addr = ((size_t)(b*4096 + (h>>2)*64 + q))*1024 + c*16 + (h&3)*4;
    float4 a4 = *(const float4*)(famp + addr);
    float4 p4 = *(const float4*)(fph + addr);
    float sn, cs;
    sincosf(p4.x, &sn, &cs); re[r][4*q+0] = a4.x*cs; im[r][4*q+0] = a4.x*sn;
    sincosf(p4.y, &sn, &cs); re[r][4*q+1] = a4.y*cs; im[r][4*q+1] = a4.y*sn;
    sincosf(p4.z, &sn, &cs); re[r][4*q+2] = a4.z*cs; im[r][4*q+2] = a4.z*sn;
    sincosf(p4.w, &sn, &cs); re[r][4*q+3] = a4.w*cs; im[r][4*q+3] = a4.w*sn;
  }
  __syncthreads();
  for (int s = 0; s < 8; ++s){
    int half = 128 >> s;
    #pragma unroll
    for (int bi0 = 0; bi0 < 2; ++bi0){
      int bi = t + bi0*256;
      int r = bi >> 7, tj = bi & 127;
      int j = tj & (half-1);
      int g = tj >> (7-s);
      int k = (g << (8-s)) + j;
      float ang = 6.2831853071795864f * (float)j / (float)(half << 1);
      float ws, wc; sincosf(ang, &ws, &wc);
      float are = re[r][k],      aim = im[r][k];
      float bre = re[r][k+half], bim = im[r][k+half];
      re[r][k] = are + bre; im[r][k] = aim + bim;
      float tr = are - bre, ti = aim - bim;
      re[r][k+half] = tr*wc - ti*ws;
      im[r][k+half] = tr*ws + ti*wc;
    }
    __syncthreads();
  }
  {
    int r = t >> 6, q = t & 63;
    size_t row = (size_t)R + r;
    float4 vr, vi;
    vr.x = re[r][brev8(4*q+0)]; vi.x = im[r][brev8(4*q+0)];
    vr.y = re[r][brev8(4*q+1)]; vi.y = im[r][brev8(4*q+1)];
    vr.z = re[r][brev8(4*q+2)]; vi.z = im[r][brev8(4*q+2)];
    vr.w = re[r][brev8(4*q+3)]; vi.w = im[r][brev8(4*q+3)];
    *(float4*)(sre + row*256 + 4*q) = vr;
    *(float4*)(sim + row*256 + 4*q) = vi;
  }
}

// ---------------- column FFT: DIR=0 fwd (amp/ph patchified out), DIR=1 inv (real out) ----
template<int DIR>
__global__ __launch_bounds__(256) void kern_fft_cols(const float* __restrict__ sre,
    const float* __restrict__ sim, float* __restrict__ out0, float* __restrict__ out1){
  __shared__ float reL[256*17];
  __shared__ float imL[256*17];
  int t = threadIdx.x;
  int img = blockIdx.x >> 4;                 // b*64+c within slab
  int c0 = (blockIdx.x & 15) * 16;
  {
    const float* pr = sre + ((size_t)img*256 + t)*256 + c0;
    const float* pi = sim + ((size_t)img*256 + t)*256 + c0;
    #pragma unroll
    for (int p = 0; p < 4; ++p){
      float4 vr = *(const float4*)(pr + 4*p);
      float4 vi = *(const float4*)(pi + 4*p);
      int base = t*17 + 4*p;
      reL[base+0]=vr.x; reL[base+1]=vr.y; reL[base+2]=vr.z; reL[base+3]=vr.w;
      imL[base+0]=vi.x; imL[base+1]=vi.y; imL[base+2]=vi.z; imL[base+3]=vi.w;
    }
  }
  __syncthreads();
  const float sgn = (DIR == 0) ? -1.f : 1.f;
  int col = t & 15, tb = t >> 4;
  for (int s = 0; s < 8; ++s){
    int half = 128 >> s;
    #pragma unroll
    for (int it = 0; it < 8; ++it){
      int tj = tb + it*16;
      int j = tj & (half-1);
      int g = tj >> (7-s);
      int k = (g << (8-s)) + j;
      float ang = sgn * 6.2831853071795864f * (float)j / (float)(half << 1);
      float ws, wc; sincosf(ang, &ws, &wc);
      int i0 = k*17 + col, i1 = (k+half)*17 + col;
      float are = reL[i0], aim = imL[i0];
      float bre = reL[i1], bim = imL[i1];
      reL[i0] = are + bre; imL[i0] = aim + bim;
      float tr = are - bre, ti = aim - bim;
      reL[i1] = tr*wc - ti*ws;
      imL[i1] = tr*ws + ti*wc;
    }
    __syncthreads();
  }
  int b = img >> 6, c = img & 63;
  int h = t; int src = (int)brev8((uint)h);
  if (DIR == 0){
    int gy = h >> 2, py = h & 3;
    #pragma unroll
    for (int p = 0; p < 4; ++p){
      float4 av, pv;
      int base = src*17 + 4*p;
      float rr, ii;
      rr = reL[base+0]; ii = imL[base+0]; av.x = sqrtf(rr*rr+ii*ii); pv.x = atan2f(ii, rr);
      rr = reL[base+1]; ii = imL[base+1]; av.y = sqrtf(rr*rr+ii*ii); pv.y = atan2f(ii, rr);
      rr = reL[base+2]; ii = imL[base+2]; av.z = sqrtf(rr*rr+ii*ii); pv.z = atan2f(ii, rr);
      rr = reL[base+3]; ii = imL[base+3]; av.w = sqrtf(rr*rr+ii*ii); pv.w = atan2f(ii, rr);
      size_t addr = ((size_t)(b*4096 + gy*64 + (c0>>2) + p))*1024 + c*16 + py*4;
      *(float4*)(out0 + addr) = av;
      *(float4*)(out1 + addr) = pv;
    }
  } else {
    float* op = out0 + ((size_t)img*256 + h)*256 + c0;
    #pragma unroll
    for (int p = 0; p < 4; ++p){
      int base = src*17 + 4*p;
      float4 v;
      v.x = reL[base+0]*(1.f/65536.f);
      v.y = reL[base+1]*(1.f/65536.f);
      v.z = reL[base+2]*(1.f/65536.f);
      v.w = reL[base+3]*(1.f/65536.f);
      *(float4*)(op + 4*p) = v;
    }
  }
}

// ---------------- generic fp32 tiled GEMM ----------------
// AMODE: 0 plain A0 (lda=K), 1 cat(A0|A1) along K (each 1024 wide), 2 gather rows via idx
// EPI:   0 store C[m*N+n], 1 h-epilogue (+IP[b]+CWB[g]), 2 bypass blend, 3 fused_sel scatter
struct GP {
  const float* A0; const float* A1;
  const float* Bm; float* Cm;
  const int* idx;
  const float* ep0; const float* ep1;
  const float* vt; const float* it;
  int M, N, K;
};

template<int AMODE, int EPI>
__global__ __launch_bounds__(256) void kern_gemm(GP p){
  __shared__ float As[16][132];
  __shared__ float Bs[16][64];
  __shared__ int idx_s[128];
  int tid = threadIdx.x;
  int m0 = blockIdx.y * 128;
  int n0 = blockIdx.x * 64;
  int tx = tid & 15, ty = tid >> 4;
  float acc[8][4];
  #pragma unroll
  for (int r = 0; r < 8; ++r){
    #pragma unroll
    for (int c = 0; c < 4; ++c) acc[r][c] = 0.f;
  }
  if (AMODE == 2 || EPI == 3){
    if (tid < 128){
      int m = m0 + tid;
      idx_s[tid] = p.idx[(m >> 10)*1024 + (m & 1023)];
    }
    __syncthreads();
  }
  int gb = m0 >> 10;
  int row0 = tid >> 2, q0 = tid & 3;
  for (int k0 = 0; k0 < p.K; k0 += 16){
    float4 av0, av1, bv;
    {
      int k = k0 + 4*q0;
      const float *ap0, *ap1;
      if (AMODE == 0){
        ap0 = p.A0 + (size_t)(m0+row0)*p.K + k;
        ap1 = p.A0 + (size_t)(m0+row0+64)*p.K + k;
      } else if (AMODE == 1){
        const float* src = (k < 1024) ? p.A0 : p.A1;
        int k2 = (k < 1024) ? k : (k - 1024);
        ap0 = src + (size_t)(m0+row0)*1024 + k2;
        ap1 = src + (size_t)(m0+row0+64)*1024 + k2;
      } else {
        int gt0 = idx_s[row0], gt1 = idx_s[row0+64];
        ap0 = p.A0 + ((size_t)(gb << 12) + gt0)*1024 + k;
        ap1 = p.A0 + ((size_t)(gb << 12) + gt1)*1024 + k;
      }
      av0 = *(const float4*)ap0;     // ws planes: 16B aligned
      av1 = *(const float4*)ap1;
      int kk = tid >> 4, n4 = tid & 15;
      const float* bp = p.Bm + (size_t)(k0+kk)*p.N + n0 + 4*n4;
      bv = make_float4(bp[0], bp[1], bp[2], bp[3]);   // d_in: scalar-safe
    }
    __syncthreads();
    As[4*q0+0][row0] = av0.x; As[4*q0+1][row0] = av0.y;
    As[4*q0+2][row0] = av0.z; As[4*q0+3][row0] = av0.w;
    As[4*q0+0][row0+64] = av1.x; As[4*q0+1][row0+64] = av1.y;
    As[4*q0+2][row0+64] = av1.z; As[4*q0+3][row0+64] = av1.w;
    { int kk = tid >> 4, n4 = tid & 15; *(float4*)&Bs[kk][4*n4] = bv; }
    __syncthreads();
    #pragma unroll
    for (int kk = 0; kk < 16; ++kk){
      float4 a0 = *(const float4*)&As[kk][8*ty];
      float4 a1 = *(const float4*)&As[kk][8*ty+4];
      float4 b0 = *(const float4*)&Bs[kk][4*tx];
      float ar[8] = {a0.x,a0.y,a0.z,a0.w,a1.x,a1.y,a1.z,a1.w};
      float brr[4] = {b0.x,b0.y,b0.z,b0.w};
      #pragma unroll
      for (int r = 0; r < 8; ++r){
        #pragma unroll
        for (int c = 0; c < 4; ++c) acc[r][c] += ar[r]*brr[c];
      }
    }
  }
  #pragma unroll
  for (int r = 0; r < 8; ++r){
    int m = m0 + 8*ty + r;
    int n = n0 + 4*tx;
    if (EPI == 0){
      float4 o = make_float4(acc[r][0], acc[r][1], acc[r][2], acc[r][3]);
      *(float4*)(p.Cm + (size_t)m*p.N + n) = o;
    } else if (EPI == 1){
      int b = m >> 12, g = m & 4095;
      const float* e0 = p.ep0 + b*128 + n;
      const float* e1 = p.ep1 + (size_t)g*128 + n;
      float4 o;
      o.x = acc[r][0] + e0[0] + e1[0];
      o.y = acc[r][1] + e0[1] + e1[1];
      o.z = acc[r][2] + e0[2] + e1[2];
      o.w = acc[r][3] + e0[3] + e1[3];
      *(float4*)(p.Cm + (size_t)m*128 + n) = o;
    } else if (EPI == 2){
      float4 vt4 = *(const float4*)(p.vt + (size_t)m*1024 + n);
      float4 it4 = *(const float4*)(p.it + (size_t)m*1024 + n);
      const float* e0 = p.ep0 + n;
      float4 o; float gg;
      gg = 1.f/(1.f+expf(-(acc[r][0]+e0[0]))); o.x = gg*vt4.x + (1.f-gg)*it4.x;
      gg = 1.f/(1.f+expf(-(acc[r][1]+e0[1]))); o.y = gg*vt4.y + (1.f-gg)*it4.y;
      gg = 1.f/(1.f+expf(-(acc[r][2]+e0[2]))); o.z = gg*vt4.z + (1.f-gg)*it4.z;
      gg = 1.f/(1.f+expf(-(acc[r][3]+e0[3]))); o.w = gg*vt4.w + (1.f-gg)*it4.w;
      *(float4*)(p.Cm + (size_t)m*1024 + n) = o;
    } else {
      int gt = idx_s[8*ty + r];
      size_t off = ((size_t)(gb << 12) + gt)*1024 + n;
      float4 vs4 = *(const float4*)(p.vt + off);
      float4 o = make_float4(acc[r][0]+vs4.x, acc[r][1]+vs4.y,
                             acc[r][2]+vs4.z, acc[r][3]+vs4.w);
      *(float4*)(p.Cm + off) = o;
    }
  }
}

// ---------------- score = gelu(h) @ Wout + bout ----------------
__global__ __launch_bounds__(64) void kern_score(const float* __restrict__ h,
    const float* __restrict__ wout, const float* __restrict__ bout,
    float* __restrict__ score){
  int m = blockIdx.x, t = threadIdx.x;
  const float* hp = h + (size_t)m*128;
  float s = geluf(hp[t])*wout[t] + geluf(hp[t+64])*wout[t+64];
  #pragma unroll
  for (int off = 32; off > 0; off >>= 1) s += __shfl_down(s, off);
  if (t == 0) score[m] = s + bout[0];
}

// ---------------- per-batch top-1024 of 4096 (bitonic, jax tie-break) ----------------
__global__ __launch_bounds__(1024) void kern_topk(const float* __restrict__ score,
    int* __restrict__ idx_out){
  __shared__ u64 keys[4096];
  int b = blockIdx.x, t = threadIdx.x;
  for (int i = t; i < 4096; i += 1024){
    float s = score[b*4096 + i];
    uint u = __float_as_uint(s);
    uint msk = (u & 0x80000000u) ? ~u : (u | 0x80000000u);
    keys[i] = ((u64)msk << 32) | (uint)(4095 - i);
  }
  __syncthreads();
  for (int k = 2; k <= 4096; k <<= 1){
    for (int j = k >> 1; j > 0; j >>= 1){
      for (int i = t; i < 4096; i += 1024){
        int l = i ^ j;
        if (l > i){
          u64 a = keys[i], c = keys[l];
          bool descB = ((i & k) == 0);
          bool sw = descB ? (a < c) : (a > c);
          if (sw){ keys[i] = c; keys[l] = a; }
        }
      }
      __syncthreads();
    }
  }
  idx_out[b*1024 + t] = 4095 - (int)(keys[t] & 0xFFFFFFFFu);
}

// ---------------- attention (flash-style, dh=32, 4 heads) ----------------
__global__ __launch_bounds__(256) void kern_attn(const float* __restrict__ qb,
    const float* __restrict__ kb, const float* __restrict__ vb,
    float* __restrict__ ob, const float* __restrict__ ipint){
  __shared__ float Ks[64][32];
  __shared__ float Vs[64][32];
  int t = threadIdx.x;
  int hh = blockIdx.y, b = blockIdx.z;
  int jq = blockIdx.x*256 + t;
  float qv[32];
  {
    const float4* qp = (const float4*)(qb + ((size_t)(b*1024)+jq)*128 + hh*32);
    #pragma unroll
    for (int d = 0; d < 8; ++d) ((float4*)qv)[d] = qp[d];
  }
  float mrun = -3.0e38f, lrun = 0.f;
  float oa[32];
  #pragma unroll
  for (int d = 0; d < 32; ++d) oa[d] = 0.f;
  for (int kt = 0; kt < 16; ++kt){
    #pragma unroll
    for (int rep = 0; rep < 2; ++rep){
      int f = t + rep*256;
      int r = f >> 3, q4 = f & 7;
      size_t base = ((size_t)(b*1024) + kt*64 + r)*128 + hh*32 + 4*q4;
      *(float4*)&Ks[r][4*q4] = *(const float4*)(kb + base);
      *(float4*)&Vs[r][4*q4] = *(const float4*)(vb + base);
    }
    __syncthreads();
    float mt = -3.0e38f;
    for (int kk = 0; kk < 64; ++kk){
      float s = 0.f;
      #pragma unroll
      for (int d = 0; d < 32; ++d) s += qv[d]*Ks[kk][d];
      s *= 0.17677669529663687f;
      mt = fmaxf(mt, s);
    }
    float mnew = fmaxf(mrun, mt);
    float alpha = expf(mrun - mnew);
    lrun *= alpha;
    #pragma unroll
    for (int d = 0; d < 32; ++d) oa[d] *= alpha;
    for (int kk = 0; kk < 64; ++kk){
      float s = 0.f;
      #pragma unroll
      for (int d = 0; d < 32; ++d) s += qv[d]*Ks[kk][d];
      s *= 0.17677669529663687f;
      float pe = expf(s - mnew);
      lrun += pe;
      #pragma unroll
      for (int d = 0; d < 32; ++d) oa[d] += pe*Vs[kk][d];
    }
    mrun = mnew;
    __syncthreads();
  }
  float inv = 1.f/lrun;
  float* op = ob + ((size_t)(b*1024)+jq)*128 + hh*32;
  const float* ip = ipint + b*128 + hh*32;
  #pragma unroll
  for (int d = 0; d < 32; ++d) op[d] = oa[d]*inv + ip[d];
}

// ---------------- direct 3x3 conv, 4 c_out per block ----------------
__global__ __launch_bounds__(256) void kern_conv(const float* __restrict__ in,
    const float* __restrict__ w, const float* __restrict__ bias,
    float* __restrict__ out, int mode,
    const float* __restrict__ modg, const float* __restrict__ modb,
    const float* __restrict__ vis, const float* __restrict__ irf){
  __shared__ float ls[10*258];
  int t = threadIdx.x;
  int y0 = blockIdx.x * 8;
  int co0 = blockIdx.y * 4;
  int b = blockIdx.z;
  float acc[8][4];
  #pragma unroll
  for (int r = 0; r < 8; ++r){
    #pragma unroll
    for (int c = 0; c < 4; ++c) acc[r][c] = 0.f;
  }
  for (int ci = 0; ci < 64; ++ci){
    const float* ip = in + ((size_t)(b*64+ci))*65536;
    #pragma unroll
    for (int rr = 0; rr < 10; ++rr){
      int y = y0 + rr - 1;
      for (int cc = t; cc < 258; cc += 256){
        int x = cc - 1;
        float v = 0.f;
        if (y >= 0 && y < 256 && x >= 0 && x < 256) v = ip[y*256+x];
        ls[rr*258+cc] = v;
      }
    }
    float wv[4][9];
    #pragma unroll
    for (int cw = 0; cw < 4; ++cw){
      const float* wp = w + ((size_t)(co0+cw)*64 + ci)*9;
      #pragma unroll
      for (int jx = 0; jx < 9; ++jx) wv[cw][jx] = wp[jx];
    }
    __syncthreads();
    int cc = t + 1;
    float a00 = ls[cc-1],      a01 = ls[cc],      a02 = ls[cc+1];
    float a10 = ls[258+cc-1],  a11 = ls[258+cc],  a12 = ls[258+cc+1];
    #pragma unroll
    for (int r = 0; r < 8; ++r){
      float a20 = ls[(r+2)*258+cc-1], a21 = ls[(r+2)*258+cc], a22 = ls[(r+2)*258+cc+1];
      #pragma unroll
      for (int cw = 0; cw < 4; ++cw){
        acc[r][cw] += a00*wv[cw][0]+a01*wv[cw][1]+a02*wv[cw][2]
                     +a10*wv[cw][3]+a11*wv[cw][4]+a12*wv[cw][5]
                     +a20*wv[cw][6]+a21*wv[cw][7]+a22*wv[cw][8];
      }
      a00=a10; a01=a11; a02=a12;
      a10=a20; a11=a21; a12=a22;
    }
    __syncthreads();
  }
  int x = t;
  #pragma unroll
  for (int r = 0; r < 8; ++r){
    int y = y0 + r;
    #pragma unroll
    for (int cw = 0; cw < 4; ++cw){
      int co = co0 + cw;
      float v = acc[r][cw] + bias[co];
      size_t oi = ((size_t)(b*64+co)*256 + y)*256 + x;
      if (mode == 1) out[oi] = fmaxf(v, 0.f);
      else {
        v = v*modg[b*64+co] + modb[b*64+co] + 0.5f*(vis[oi]+irf[oi]);
        out[oi] = v;
      }
    }
  }
}

// ---------------- launch ----------------
extern "C" void kernel_launch(void* const* d_in, const int* in_sizes, int n_in,
                              void* d_out, int out_size, void* d_ws, size_t ws_size,
                              hipStream_t stream){
  (void)in_sizes; (void)n_in; (void)out_size;
  const float* vis  = (const float*)d_in[0];
  const float* irf  = (const float*)d_in[1];
  const float* bank = (const float*)d_in[2];
  const float* Wr   = (const float*)d_in[3];
  const float* br   = (const float*)d_in[4];
  const float* Wtok = (const float*)d_in[5];
  const float* Wpri = (const float*)d_in[6];
  const float* Wco  = (const float*)d_in[7];
  const float* bs   = (const float*)d_in[8];
  const float* Wout = (const float*)d_in[9];
  const float* bout = (const float*)d_in[10];
  const float* Wq   = (const float*)d_in[11];
  const float* Wk   = (const float*)d_in[12];
  const float* Wv   = (const float*)d_in[13];
  const float* Wo   = (const float*)d_in[14];
  const float* Wint = (const float*)d_in[15];
  const float* Wbyp = (const float*)d_in[16];
  const float* bbyp = (const float*)d_in[17];
  const float* c1w  = (const float*)d_in[18];
  const float* c1b  = (const float*)d_in[19];
  const float* c2w  = (const float*)d_in[20];
  const float* c2b  = (const float*)d_in[21];
  const float* Wa1  = (const float*)d_in[22];
  const float* ba1  = (const float*)d_in[23];
  const float* Wa2  = (const float*)d_in[24];
  const float* ba2  = (const float*)d_in[25];

  // Workspace demand: 5 planes of PB*4194304 floats + small buffers.
  // need(PB) floats = 5*PB*4194304 + PB*1053696 + 1051648
  const size_t need4 = ((size_t)5*4*4194304 + 4*1053696 + 1051648)*4;  // ~340 MiB
  const int PB = (ws_size >= need4) ? 4 : 1;   // deterministic (ws_size fixed) -> graph-safe

  float* ws = (float*)d_ws;
  const size_t PLN = (size_t)PB*4194304;
  float* p0 = ws;
  float* p1 = p0 + PLN;
  float* p2 = p1 + PLN;
  float* p3 = p2 + PLN;
  float* tB = p3 + PLN;
  float* sm = tB + PLN;
  float* hbuf  = sm; sm += (size_t)PB*524288;
  float* score = sm; sm += (size_t)PB*4096;
  int*   idxb  = (int*)sm; sm += (size_t)PB*1024;
  float* qbuf  = sm; sm += (size_t)PB*131072;
  float* kbuf  = sm; sm += (size_t)PB*131072;
  float* vbuf  = sm; sm += (size_t)PB*131072;
  float* obuf  = sm; sm += (size_t)PB*131072;
  float* CWB   = sm; sm += 1048576;
  float* pooled= sm; sm += 512;
  float* IP    = sm; sm += 1024;
  float* IPint = sm; sm += 1024;
  float* modg  = sm; sm += 256;
  float* modb  = sm; sm += 256;

  kern_pool <<<512, 256, 0, stream>>>(vis, irf, pooled);
  kern_small<<<1, 256, 0, stream>>>(pooled, Wr, br, bank, Wpri, Wint,
                                    Wa1, ba1, Wa2, ba2, IP, IPint, modg, modb);
  kern_cwb  <<<4096, 256, 0, stream>>>(Wco, bs, CWB);

  for (int b0 = 0; b0 < 4; b0 += PB){
    const float* vis_b = vis + (size_t)b0*4194304;
    const float* ir_b  = irf + (size_t)b0*4194304;
    float* out_b = (float*)d_out + (size_t)b0*4194304;
    float* TA = out_b;   // d_out slab doubles as row-FFT transient (dead before conv2 writes)

    // forward FFT2 + amp/phase (patchified layout)
    kern_fft_rows_fwd<<<PB*8192, 256, 0, stream>>>(vis_b, TA, tB);
    kern_fft_cols<0> <<<PB*1024, 256, 0, stream>>>(TA, tB, p0, p1);   // AMP_V, PH_V
    kern_fft_rows_fwd<<<PB*8192, 256, 0, stream>>>(ir_b, TA, tB);
    kern_fft_cols<0> <<<PB*1024, 256, 0, stream>>>(TA, tB, p2, p3);   // AMP_I, PH_I

    for (int i = 0; i < 2; ++i){
      const float* AV = i ? p1 : p0;
      const float* AI = i ? p3 : p2;
      float* FULL     = i ? p0 : tB;   // i=1 reuses dead AMP_V plane
      {  // h = cat(vt,it)@Wtok + IP[b] + CWB[g]
        GP p{}; p.A0 = AV; p.A1 = AI; p.Bm = Wtok + (size_t)i*262144; p.Cm = hbuf;
        p.ep0 = IP + i*512 + b0*128; p.ep1 = CWB + (size_t)i*524288;
        p.M = PB*4096; p.N = 128; p.K = 2048;
        kern_gemm<1,1><<<dim3(2, PB*32), 256, 0, stream>>>(p);
      }
      kern_score<<<PB*4096, 64, 0, stream>>>(hbuf, Wout + i*128, bout + i, score);
      kern_topk <<<PB, 1024, 0, stream>>>(score, idxb);
      {  // bypass blend into FULL (all tokens)
        GP p{}; p.A0 = AV; p.A1 = AI; p.Bm = Wbyp + (size_t)i*2097152; p.Cm = FULL;
        p.ep0 = bbyp + i*1024; p.vt = AV; p.it = AI;
        p.M = PB*4096; p.N = 1024; p.K = 2048;
        kern_gemm<1,2><<<dim3(16, PB*32), 256, 0, stream>>>(p);
      }
      {  // q, k, v (gathered rows)
        GP p{}; p.A0 = AV; p.Bm = Wq + (size_t)i*131072; p.Cm = qbuf; p.idx = idxb;
        p.M = PB*1024; p.N = 128; p.K = 1024;
        kern_gemm<2,0><<<dim3(2, PB*8), 256, 0, stream>>>(p);
        p.A0 = AI; p.Bm = Wk + (size_t)i*131072; p.Cm = kbuf;
        kern_gemm<2,0><<<dim3(2, PB*8), 256, 0, stream>>>(p);
        p.Bm = Wv + (size_t)i*131072; p.Cm = vbuf;
        kern_gemm<2,0><<<dim3(2, PB*8), 256, 0, stream>>>(p);
      }
      kern_attn<<<dim3(4, 4, PB), 256, 0, stream>>>(qbuf, kbuf, vbuf, obuf,
                                                    IPint + i*512 + b0*128);
      {  // fused_sel = vs + o@Wo, scattered into FULL at selected tokens
        GP p{}; p.A0 = obuf; p.Bm = Wo + (size_t)i*131072; p.Cm = FULL;
        p.idx = idxb; p.vt = AV;
        p.M = PB*1024; p.N = 1024; p.K = 128;
        kern_gemm<0,3><<<dim3(16, PB*8), 256, 0, stream>>>(p);
      }
    }

    // spec = famp * e^{i fph}; inverse FFT2 (famp=tB, fph=p0 -> sre p1, sim p2 -> spatial p3)
    kern_ifft_rows_spec<<<PB*4096, 256, 0, stream>>>(tB, p0, p1, p2);
    kern_fft_cols<1>   <<<PB*1024, 256, 0, stream>>>(p1, p2, p3, nullptr);

    // conv -> relu -> conv -> modulation + residual
    kern_conv<<<dim3(32,16,PB), 256, 0, stream>>>(p3, c1w, c1b, tB, 1,
                                                  nullptr, nullptr, nullptr, nullptr);
    kern_conv<<<dim3(32,16,PB), 256, 0, stream>>>(tB, c2w, c2b, out_b, 2,
                                                  modg + b0*64, modb + b0*64, vis_b, ir_b);
  }
}

// Round 3
// 5826.955 us; speedup vs baseline: 2.3239x; 2.3239x over previous
//
#include <hip/hip_runtime.h>

typedef unsigned int uint;
typedef unsigned long long u64;

__device__ __forceinline__ uint brev8(uint x){ return __brev(x) >> 24; }
__device__ __forceinline__ float geluf(float x){
  return 0.5f*x*(1.f + tanhf(0.7978845608028654f*(x + 0.044715f*x*x*x)));
}

// ---------------- pooled mean (global, all 4 batches) ----------------
__global__ __launch_bounds__(256) void kern_pool(const float* __restrict__ vis,
                                                 const float* __restrict__ irf,
                                                 float* __restrict__ pooled){
  __shared__ float red[256];
  int bc = blockIdx.x;            // b*128 + cc
  int b = bc >> 7, cc = bc & 127;
  const float* src = (cc < 64) ? (vis + (size_t)(b*64+cc)*65536)
                               : (irf + (size_t)(b*64+(cc-64))*65536);
  float s = 0.f;
  for (int i = threadIdx.x; i < 65536; i += 256) s += src[i];
  red[threadIdx.x] = s;
  __syncthreads();
  for (int off = 128; off > 0; off >>= 1){
    if (threadIdx.x < off) red[threadIdx.x] += red[threadIdx.x + off];
    __syncthreads();
  }
  if (threadIdx.x == 0) pooled[bc] = red[0] * (1.f/65536.f);
}

// ---------------- prompt/intent/affine small ops (global) ----------------
__global__ __launch_bounds__(256) void kern_small(const float* __restrict__ pooled,
    const float* __restrict__ Wr, const float* __restrict__ br,
    const float* __restrict__ bank, const float* __restrict__ Wpri,
    const float* __restrict__ Wint, const float* __restrict__ Wa1,
    const float* __restrict__ ba1, const float* __restrict__ Wa2,
    const float* __restrict__ ba2,
    float* __restrict__ IP, float* __restrict__ IPint,
    float* __restrict__ modg, float* __restrict__ modb){
  __shared__ float logit_s[16];
  __shared__ float pw_s[16];
  __shared__ float intent_s[4][64];
  __shared__ float t1_s[4][128];
  int t = threadIdx.x;
  if (t < 16){
    int b = t >> 2, j = t & 3;
    float s = br[j];
    for (int k = 0; k < 128; ++k) s += pooled[b*128+k]*Wr[k*4+j];
    logit_s[t] = s;
  }
  __syncthreads();
  if (t < 4){
    int b = t;
    float m = logit_s[b*4];
    for (int j = 1; j < 4; ++j) m = fmaxf(m, logit_s[b*4+j]);
    float e[4], sum = 0.f;
    for (int j = 0; j < 4; ++j){ e[j] = expf(logit_s[b*4+j]-m); sum += e[j]; }
    for (int j = 0; j < 4; ++j) pw_s[b*4+j] = e[j]/sum;
  }
  __syncthreads();
  {
    int b = t >> 6, p = t & 63;
    float s = 0.f;
    for (int j = 0; j < 4; ++j) s += pw_s[b*4+j]*bank[j*64+p];
    intent_s[b][p] = s;
  }
  __syncthreads();
  for (int o = t; o < 1024; o += 256){
    int i = o >> 9, rem = o & 511, b = rem >> 7, n = rem & 127;
    float s1 = 0.f, s2 = 0.f;
    for (int p = 0; p < 64; ++p){
      float iv = intent_s[b][p];
      s1 += iv * Wpri[(i*64+p)*128 + n];
      s2 += iv * Wint[(i*64+p)*128 + n];
    }
    IP[o] = s1; IPint[o] = s2;
  }
  for (int o = t; o < 512; o += 256){
    int b = o >> 7, n = o & 127;
    float s = ba1[n];
    for (int p = 0; p < 64; ++p) s += intent_s[b][p]*Wa1[p*128+n];
    t1_s[b][n] = geluf(s);
  }
  __syncthreads();
  for (int o = t; o < 512; o += 256){
    int b = o >> 7, n = o & 127;
    float s = ba2[n];
    for (int p = 0; p < 128; ++p) s += t1_s[b][p]*Wa2[p*128+n];
    if (n < 64) modg[b*64+n] = 1.f + 0.1f*tanhf(s);
    else        modb[b*64+(n-64)] = 0.1f*s;
  }
}

// ---------------- forward row FFT (real input), slab-relative ----------------
__global__ __launch_bounds__(256) void kern_fft_rows_fwd(const float* __restrict__ x,
    float* __restrict__ sre, float* __restrict__ sim){
  __shared__ float re[2][256], im[2][256];
  __shared__ float twr[128], twi[128];
  int t = threadIdx.x;
  if (t < 128){
    float a = -6.2831853071795864f * (float)t * (1.f/256.f);
    sincosf(a, &twi[t], &twr[t]);
  }
  int r = t >> 7, jj = t & 127;
  size_t row = (size_t)blockIdx.x*2 + r;   // flat row over (b,c,h) within slab
  {
    const float* xp = x + row*256;
    re[r][jj] = xp[jj]; re[r][jj+128] = xp[jj+128];
    im[r][jj] = 0.f;    im[r][jj+128] = 0.f;
  }
  __syncthreads();
  for (int s = 0; s < 8; ++s){
    int half = 128 >> s;
    int j = jj & (half-1);
    int g = jj >> (7-s);
    int k = (g << (8-s)) + j;
    int m = j << s;
    float wc = twr[m], ws = twi[m];
    float are = re[r][k],      aim = im[r][k];
    float bre = re[r][k+half], bim = im[r][k+half];
    re[r][k] = are + bre; im[r][k] = aim + bim;
    float tr = are - bre, ti = aim - bim;
    re[r][k+half] = tr*wc - ti*ws;
    im[r][k+half] = tr*ws + ti*wc;
    __syncthreads();
  }
  {
    float* orp = sre + row*256; float* oip = sim + row*256;
    int w1 = jj, w2 = jj + 128;
    orp[w1] = re[r][brev8(w1)]; oip[w1] = im[r][brev8(w1)];
    orp[w2] = re[r][brev8(w2)]; oip[w2] = im[r][brev8(w2)];
  }
}

// ---------------- inverse row FFT with spec construction (reads patchified amp/ph) ----
__global__ __launch_bounds__(256) void kern_ifft_rows_spec(const float* __restrict__ famp,
    const float* __restrict__ fph, float* __restrict__ sre, float* __restrict__ sim){
  __shared__ float re[4][256], im[4][256];
  __shared__ float twr[128], twi[128];
  int t = threadIdx.x;
  if (t < 128){
    float a = -6.2831853071795864f * (float)t * (1.f/256.f);
    sincosf(a, &twi[t], &twr[t]);
  }
  int R = blockIdx.x * 4;
  {
    int r = t >> 6, q = t & 63;
    int row = R + r;
    int bc = row >> 8, h = row & 255;
    int b = bc >> 6, c = bc & 63;
    size_t addr = ((size_t)(b*4096 + (h>>2)*64 + q))*1024 + c*16 + (h&3)*4;
    float4 a4 = *(const float4*)(famp + addr);
    float4 p4 = *(const float4*)(fph + addr);
    float sn, cs;
    sincosf(p4.x, &sn, &cs); re[r][4*q+0] = a4.x*cs; im[r][4*q+0] = a4.x*sn;
    sincosf(p4.y, &sn, &cs); re[r][4*q+1] = a4.y*cs; im[r][4*q+1] = a4.y*sn;
    sincosf(p4.z, &sn, &cs); re[r][4*q+2] = a4.z*cs; im[r][4*q+2] = a4.z*sn;
    sincosf(p4.w, &sn, &cs); re[r][4*q+3] = a4.w*cs; im[r][4*q+3] = a4.w*sn;
  }
  __syncthreads();
  for (int s = 0; s < 8; ++s){
    int half = 128 >> s;
    #pragma unroll
    for (int bi0 = 0; bi0 < 2; ++bi0){
      int bi = t + bi0*256;
      int r = bi >> 7, tj = bi & 127;
      int j = tj & (half-1);
      int g = tj >> (7-s);
      int k = (g << (8-s)) + j;
      int m = j << s;
      float wc = twr[m], ws = -twi[m];
      float are = re[r][k],      aim = im[r][k];
      float bre = re[r][k+half], bim = im[r][k+half];
      re[r][k] = are + bre; im[r][k] = aim + bim;
      float tr = are - bre, ti = aim - bim;
      re[r][k+half] = tr*wc - ti*ws;
      im[r][k+half] = tr*ws + ti*wc;
    }
    __syncthreads();
  }
  {
    int r = t >> 6, q = t & 63;
    size_t row = (size_t)R + r;
    float4 vr, vi;
    vr.x = re[r][brev8(4*q+0)]; vi.x = im[r][brev8(4*q+0)];
    vr.y = re[r][brev8(4*q+1)]; vi.y = im[r][brev8(4*q+1)];
    vr.z = re[r][brev8(4*q+2)]; vi.z = im[r][brev8(4*q+2)];
    vr.w = re[r][brev8(4*q+3)]; vi.w = im[r][brev8(4*q+3)];
    *(float4*)(sre + row*256 + 4*q) = vr;
    *(float4*)(sim + row*256 + 4*q) = vi;
  }
}

// ---------------- column FFT: DIR=0 fwd (amp/ph patchified out), DIR=1 inv (real out) ----
template<int DIR>
__global__ __launch_bounds__(256) void kern_fft_cols(const float* __restrict__ sre,
    const float* __restrict__ sim, float* __restrict__ out0, float* __restrict__ out1){
  __shared__ float reL[256*17];
  __shared__ float imL[256*17];
  __shared__ float twr[128], twi[128];
  int t = threadIdx.x;
  if (t < 128){
    float a = -6.2831853071795864f * (float)t * (1.f/256.f);
    sincosf(a, &twi[t], &twr[t]);
  }
  int img = blockIdx.x >> 4;                 // b*64+c within slab
  int c0 = (blockIdx.x & 15) * 16;
  {
    const float* pr = sre + ((size_t)img*256 + t)*256 + c0;
    const float* pi = sim + ((size_t)img*256 + t)*256 + c0;
    #pragma unroll
    for (int p = 0; p < 4; ++p){
      float4 vr = *(const float4*)(pr + 4*p);
      float4 vi = *(const float4*)(pi + 4*p);
      int base = t*17 + 4*p;
      reL[base+0]=vr.x; reL[base+1]=vr.y; reL[base+2]=vr.z; reL[base+3]=vr.w;
      imL[base+0]=vi.x; imL[base+1]=vi.y; imL[base+2]=vi.z; imL[base+3]=vi.w;
    }
  }
  __syncthreads();
  int col = t & 15, tb = t >> 4;
  for (int s = 0; s < 8; ++s){
    int half = 128 >> s;
    #pragma unroll
    for (int it = 0; it < 8; ++it){
      int tj = tb + it*16;
      int j = tj & (half-1);
      int g = tj >> (7-s);
      int k = (g << (8-s)) + j;
      int m = j << s;
      float wc = twr[m];
      float ws = (DIR == 0) ? twi[m] : -twi[m];
      int i0 = k*17 + col, i1 = (k+half)*17 + col;
      float are = reL[i0], aim = imL[i0];
      float bre = reL[i1], bim = imL[i1];
      reL[i0] = are + bre; imL[i0] = aim + bim;
      float tr = are - bre, ti = aim - bim;
      reL[i1] = tr*wc - ti*ws;
      imL[i1] = tr*ws + ti*wc;
    }
    __syncthreads();
  }
  int b = img >> 6, c = img & 63;
  int h = t; int src = (int)brev8((uint)h);
  if (DIR == 0){
    int gy = h >> 2, py = h & 3;
    #pragma unroll
    for (int p = 0; p < 4; ++p){
      float4 av, pv;
      int base = src*17 + 4*p;
      float rr, ii;
      rr = reL[base+0]; ii = imL[base+0]; av.x = sqrtf(rr*rr+ii*ii); pv.x = atan2f(ii, rr);
      rr = reL[base+1]; ii = imL[base+1]; av.y = sqrtf(rr*rr+ii*ii); pv.y = atan2f(ii, rr);
      rr = reL[base+2]; ii = imL[base+2]; av.z = sqrtf(rr*rr+ii*ii); pv.z = atan2f(ii, rr);
      rr = reL[base+3]; ii = imL[base+3]; av.w = sqrtf(rr*rr+ii*ii); pv.w = atan2f(ii, rr);
      size_t addr = ((size_t)(b*4096 + gy*64 + (c0>>2) + p))*1024 + c*16 + py*4;
      *(float4*)(out0 + addr) = av;
      *(float4*)(out1 + addr) = pv;
    }
  } else {
    float* op = out0 + ((size_t)img*256 + h)*256 + c0;
    #pragma unroll
    for (int p = 0; p < 4; ++p){
      int base = src*17 + 4*p;
      float4 v;
      v.x = reL[base+0]*(1.f/65536.f);
      v.y = reL[base+1]*(1.f/65536.f);
      v.z = reL[base+2]*(1.f/65536.f);
      v.w = reL[base+3]*(1.f/65536.f);
      *(float4*)(op + 4*p) = v;
    }
  }
}

// ---------------- generic fp32 tiled GEMM, z-fused over branches/matrices ----------
// AMODE: 0 plain A0 (lda=K), 1 cat(A0|A1) along K (each 1024 wide), 2 gather rows via idx
// EPI:   0 store C[m*N+n], 1 h-epi (+IP[b]+coords@Wco+bs), 2 bypass blend, 3 scatter
struct GP {
  const float* A0[6];
  const float* A1[2];
  const float* Bm[6];
  float*       Cm[6];
  const int*   idxp[6];
  const float* ep0[2];
  const float* ep1[2];
  const float* ep2[2];
  const float* vt[2];
  const float* it[2];
  int M, N, K;
};

template<int AMODE, int EPI>
__global__ __launch_bounds__(256) void kern_gemm(GP p){
  __shared__ float As[16][132];
  __shared__ float Bs[16][64];
  __shared__ int idx_s[128];
  int z = blockIdx.z;
  const float* A0 = p.A0[z];
  const float* Bm = p.Bm[z];
  float* Cm = p.Cm[z];
  int tid = threadIdx.x;
  int m0 = blockIdx.y * 128;
  int n0 = blockIdx.x * 64;
  int tx = tid & 15, ty = tid >> 4;
  float acc[8][4];
  #pragma unroll
  for (int r = 0; r < 8; ++r){
    #pragma unroll
    for (int c = 0; c < 4; ++c) acc[r][c] = 0.f;
  }
  if (AMODE == 2 || EPI == 3){
    const int* idxp = p.idxp[z];
    if (tid < 128){
      int m = m0 + tid;
      idx_s[tid] = idxp[(m >> 10)*1024 + (m & 1023)];
    }
    __syncthreads();
  }
  int gb = m0 >> 10;   // batch-local index (M = PB*1024 for gather/scatter paths)
  int row0 = tid >> 2, q0 = tid & 3;
  for (int k0 = 0; k0 < p.K; k0 += 16){
    float4 av0, av1, bv;
    {
      int k = k0 + 4*q0;
      const float *ap0, *ap1;
      if (AMODE == 0){
        ap0 = A0 + (size_t)(m0+row0)*p.K + k;
        ap1 = A0 + (size_t)(m0+row0+64)*p.K + k;
      } else if (AMODE == 1){
        const float* src = (k < 1024) ? A0 : p.A1[z];
        int k2 = (k < 1024) ? k : (k - 1024);
        ap0 = src + (size_t)(m0+row0)*1024 + k2;
        ap1 = src + (size_t)(m0+row0+64)*1024 + k2;
      } else {
        int gt0 = idx_s[row0], gt1 = idx_s[row0+64];
        ap0 = A0 + ((size_t)(gb << 12) + gt0)*1024 + k;
        ap1 = A0 + ((size_t)(gb << 12) + gt1)*1024 + k;
      }
      av0 = *(const float4*)ap0;     // ws planes: 16B aligned
      av1 = *(const float4*)ap1;
      int kk = tid >> 4, n4 = tid & 15;
      const float* bp = Bm + (size_t)(k0+kk)*p.N + n0 + 4*n4;
      bv = make_float4(bp[0], bp[1], bp[2], bp[3]);   // d_in: scalar-safe
    }
    __syncthreads();
    As[4*q0+0][row0] = av0.x; As[4*q0+1][row0] = av0.y;
    As[4*q0+2][row0] = av0.z; As[4*q0+3][row0] = av0.w;
    As[4*q0+0][row0+64] = av1.x; As[4*q0+1][row0+64] = av1.y;
    As[4*q0+2][row0+64] = av1.z; As[4*q0+3][row0+64] = av1.w;
    { int kk = tid >> 4, n4 = tid & 15; *(float4*)&Bs[kk][4*n4] = bv; }
    __syncthreads();
    #pragma unroll
    for (int kk = 0; kk < 16; ++kk){
      float4 a0 = *(const float4*)&As[kk][8*ty];
      float4 a1 = *(const float4*)&As[kk][8*ty+4];
      float4 b0 = *(const float4*)&Bs[kk][4*tx];
      float ar[8] = {a0.x,a0.y,a0.z,a0.w,a1.x,a1.y,a1.z,a1.w};
      float brr[4] = {b0.x,b0.y,b0.z,b0.w};
      #pragma unroll
      for (int r = 0; r < 8; ++r){
        #pragma unroll
        for (int c = 0; c < 4; ++c) acc[r][c] += ar[r]*brr[c];
      }
    }
  }
  #pragma unroll
  for (int r = 0; r < 8; ++r){
    int m = m0 + 8*ty + r;
    int n = n0 + 4*tx;
    if (EPI == 0){
      float4 o = make_float4(acc[r][0], acc[r][1], acc[r][2], acc[r][3]);
      *(float4*)(Cm + (size_t)m*p.N + n) = o;
    } else if (EPI == 1){
      int bl = m >> 12, g = m & 4095;
      int gy = g >> 6, gx = g & 63;
      float cy = ((float)gy + 0.5f)*(1.f/64.f);
      float cx = ((float)gx + 0.5f)*(1.f/64.f);
      const float* e0 = p.ep0[z] + bl*128 + n;   // IP (intent @ Wpri)
      const float* w0 = p.ep1[z] + n;            // Wco row y
      const float* w1 = p.ep1[z] + 128 + n;      // Wco row x
      const float* bsv = p.ep2[z] + n;           // bs
      float4 o;
      o.x = acc[r][0] + e0[0] + cy*w0[0] + cx*w1[0] + bsv[0];
      o.y = acc[r][1] + e0[1] + cy*w0[1] + cx*w1[1] + bsv[1];
      o.z = acc[r][2] + e0[2] + cy*w0[2] + cx*w1[2] + bsv[2];
      o.w = acc[r][3] + e0[3] + cy*w0[3] + cx*w1[3] + bsv[3];
      *(float4*)(Cm + (size_t)m*128 + n) = o;
    } else if (EPI == 2){
      float4 vt4 = *(const float4*)(p.vt[z] + (size_t)m*1024 + n);
      float4 it4 = *(const float4*)(p.it[z] + (size_t)m*1024 + n);
      const float* e0 = p.ep0[z] + n;
      float4 o; float gg;
      gg = 1.f/(1.f+expf(-(acc[r][0]+e0[0]))); o.x = gg*vt4.x + (1.f-gg)*it4.x;
      gg = 1.f/(1.f+expf(-(acc[r][1]+e0[1]))); o.y = gg*vt4.y + (1.f-gg)*it4.y;
      gg = 1.f/(1.f+expf(-(acc[r][2]+e0[2]))); o.z = gg*vt4.z + (1.f-gg)*it4.z;
      gg = 1.f/(1.f+expf(-(acc[r][3]+e0[3]))); o.w = gg*vt4.w + (1.f-gg)*it4.w;
      *(float4*)(Cm + (size_t)m*1024 + n) = o;
    } else {
      int gt = idx_s[8*ty + r];
      size_t off = ((size_t)(gb << 12) + gt)*1024 + n;
      float4 vs4 = *(const float4*)(p.vt[z] + off);
      float4 o = make_float4(acc[r][0]+vs4.x, acc[r][1]+vs4.y,
                             acc[r][2]+vs4.z, acc[r][3]+vs4.w);
      *(float4*)(Cm + off) = o;
    }
  }
}

// ---------------- score = gelu(h) @ Wout + bout (branch via blockIdx.y) -----------
__global__ __launch_bounds__(64) void kern_score(const float* __restrict__ h,
    const float* __restrict__ wout, const float* __restrict__ bout,
    float* __restrict__ score, int Mper){
  int m = blockIdx.x, br = blockIdx.y, t = threadIdx.x;
  const float* hp = h + ((size_t)br*Mper + m)*128;
  const float* wp = wout + br*128;
  float s = geluf(hp[t])*wp[t] + geluf(hp[t+64])*wp[t+64];
  #pragma unroll
  for (int off = 32; off > 0; off >>= 1) s += __shfl_down(s, off);
  if (t == 0) score[(size_t)br*Mper + m] = s + bout[br];
}

// ---------------- per-(branch,batch) top-1024 of 4096 (bitonic, jax tie-break) ----
__global__ __launch_bounds__(1024) void kern_topk(const float* __restrict__ score,
    int* __restrict__ idx_out){
  __shared__ u64 keys[4096];
  int b = blockIdx.x, t = threadIdx.x;
  for (int i = t; i < 4096; i += 1024){
    float s = score[b*4096 + i];
    uint u = __float_as_uint(s);
    uint msk = (u & 0x80000000u) ? ~u : (u | 0x80000000u);
    keys[i] = ((u64)msk << 32) | (uint)(4095 - i);
  }
  __syncthreads();
  for (int k = 2; k <= 4096; k <<= 1){
    for (int j = k >> 1; j > 0; j >>= 1){
      for (int i = t; i < 4096; i += 1024){
        int l = i ^ j;
        if (l > i){
          u64 a = keys[i], c = keys[l];
          bool descB = ((i & k) == 0);
          bool sw = descB ? (a < c) : (a > c);
          if (sw){ keys[i] = c; keys[l] = a; }
        }
      }
      __syncthreads();
    }
  }
  idx_out[b*1024 + t] = 4095 - (int)(keys[t] & 0xFFFFFFFFu);
}

// ---------------- attention (flash-style, dh=32, 4 heads, z = br*PB+bb) ----------
__global__ __launch_bounds__(256) void kern_attn(const float* __restrict__ qb,
    const float* __restrict__ kb, const float* __restrict__ vb,
    float* __restrict__ ob, const float* __restrict__ ipint,
    int PB, int b0){
  __shared__ float Ks[64][32];
  __shared__ float Vs[64][32];
  int t = threadIdx.x;
  int hh = blockIdx.y, zf = blockIdx.z;
  size_t boff = (size_t)zf*131072;
  int jq = blockIdx.x*256 + t;
  float qv[32];
  {
    const float4* qp = (const float4*)(qb + boff + (size_t)jq*128 + hh*32);
    #pragma unroll
    for (int d = 0; d < 8; ++d) ((float4*)qv)[d] = qp[d];
  }
  float mrun = -3.0e38f, lrun = 0.f;
  float oa[32];
  #pragma unroll
  for (int d = 0; d < 32; ++d) oa[d] = 0.f;
  for (int kt = 0; kt < 16; ++kt){
    #pragma unroll
    for (int rep = 0; rep < 2; ++rep){
      int f = t + rep*256;
      int r = f >> 3, q4 = f & 7;
      size_t base = boff + (size_t)(kt*64 + r)*128 + hh*32 + 4*q4;
      *(float4*)&Ks[r][4*q4] = *(const float4*)(kb + base);
      *(float4*)&Vs[r][4*q4] = *(const float4*)(vb + base);
    }
    __syncthreads();
    float mt = -3.0e38f;
    for (int kk = 0; kk < 64; ++kk){
      float s = 0.f;
      #pragma unroll
      for (int d = 0; d < 32; ++d) s += qv[d]*Ks[kk][d];
      s *= 0.17677669529663687f;
      mt = fmaxf(mt, s);
    }
    float mnew = fmaxf(mrun, mt);
    float alpha = expf(mrun - mnew);
    lrun *= alpha;
    #pragma unroll
    for (int d = 0; d < 32; ++d) oa[d] *= alpha;
    for (int kk = 0; kk < 64; ++kk){
      float s = 0.f;
      #pragma unroll
      for (int d = 0; d < 32; ++d) s += qv[d]*Ks[kk][d];
      s *= 0.17677669529663687f;
      float pe = expf(s - mnew);
      lrun += pe;
      #pragma unroll
      for (int d = 0; d < 32; ++d) oa[d] += pe*Vs[kk][d];
    }
    mrun = mnew;
    __syncthreads();
  }
  float inv = 1.f/lrun;
  int br = (zf >= PB) ? 1 : 0;
  int bb = zf - br*PB;
  float* op = ob + boff + (size_t)jq*128 + hh*32;
  const float* ip = ipint + br*512 + (b0+bb)*128 + hh*32;
  #pragma unroll
  for (int d = 0; d < 32; ++d) op[d] = oa[d]*inv + ip[d];
}

// ---------------- direct 3x3 conv, 4 c_out per block, batch-wide ----------------
__global__ __launch_bounds__(256) void kern_conv(const float* __restrict__ in,
    const float* __restrict__ w, const float* __restrict__ bias,
    float* __restrict__ out, int mode,
    const float* __restrict__ modg, const float* __restrict__ modb,
    const float* __restrict__ vis, const float* __restrict__ irf){
  __shared__ float ls[10*258];
  int t = threadIdx.x;
  int y0 = blockIdx.x * 8;
  int co0 = blockIdx.y * 4;
  int b = blockIdx.z;
  float acc[8][4];
  #pragma unroll
  for (int r = 0; r < 8; ++r){
    #pragma unroll
    for (int c = 0; c < 4; ++c) acc[r][c] = 0.f;
  }
  for (int ci = 0; ci < 64; ++ci){
    const float* ip = in + ((size_t)(b*64+ci))*65536;
    #pragma unroll
    for (int rr = 0; rr < 10; ++rr){
      int y = y0 + rr - 1;
      for (int cc = t; cc < 258; cc += 256){
        int x = cc - 1;
        float v = 0.f;
        if (y >= 0 && y < 256 && x >= 0 && x < 256) v = ip[y*256+x];
        ls[rr*258+cc] = v;
      }
    }
    float wv[4][9];
    #pragma unroll
    for (int cw = 0; cw < 4; ++cw){
      const float* wp = w + ((size_t)(co0+cw)*64 + ci)*9;
      #pragma unroll
      for (int jx = 0; jx < 9; ++jx) wv[cw][jx] = wp[jx];
    }
    __syncthreads();
    int cc = t + 1;
    float a00 = ls[cc-1],      a01 = ls[cc],      a02 = ls[cc+1];
    float a10 = ls[258+cc-1],  a11 = ls[258+cc],  a12 = ls[258+cc+1];
    #pragma unroll
    for (int r = 0; r < 8; ++r){
      float a20 = ls[(r+2)*258+cc-1], a21 = ls[(r+2)*258+cc], a22 = ls[(r+2)*258+cc+1];
      #pragma unroll
      for (int cw = 0; cw < 4; ++cw){
        acc[r][cw] += a00*wv[cw][0]+a01*wv[cw][1]+a02*wv[cw][2]
                     +a10*wv[cw][3]+a11*wv[cw][4]+a12*wv[cw][5]
                     +a20*wv[cw][6]+a21*wv[cw][7]+a22*wv[cw][8];
      }
      a00=a10; a01=a11; a02=a12;
      a10=a20; a11=a21; a12=a22;
    }
    __syncthreads();
  }
  int x = t;
  #pragma unroll
  for (int r = 0; r < 8; ++r){
    int y = y0 + r;
    #pragma unroll
    for (int cw = 0; cw < 4; ++cw){
      int co = co0 + cw;
      float v = acc[r][cw] + bias[co];
      size_t oi = ((size_t)(b*64+co)*256 + y)*256 + x;
      if (mode == 1) out[oi] = fmaxf(v, 0.f);
      else {
        v = v*modg[b*64+co] + modb[b*64+co] + 0.5f*(vis[oi]+irf[oi]);
        out[oi] = v;
      }
    }
  }
}

// ---------------- launch ----------------
extern "C" void kernel_launch(void* const* d_in, const int* in_sizes, int n_in,
                              void* d_out, int out_size, void* d_ws, size_t ws_size,
                              hipStream_t stream){
  (void)in_sizes; (void)n_in; (void)out_size;
  const float* vis  = (const float*)d_in[0];
  const float* irf  = (const float*)d_in[1];
  const float* bank = (const float*)d_in[2];
  const float* Wr   = (const float*)d_in[3];
  const float* br   = (const float*)d_in[4];
  const float* Wtok = (const float*)d_in[5];
  const float* Wpri = (const float*)d_in[6];
  const float* Wco  = (const float*)d_in[7];
  const float* bs   = (const float*)d_in[8];
  const float* Wout = (const float*)d_in[9];
  const float* bout = (const float*)d_in[10];
  const float* Wq   = (const float*)d_in[11];
  const float* Wk   = (const float*)d_in[12];
  const float* Wv   = (const float*)d_in[13];
  const float* Wo   = (const float*)d_in[14];
  const float* Wint = (const float*)d_in[15];
  const float* Wbyp = (const float*)d_in[16];
  const float* bbyp = (const float*)d_in[17];
  const float* c1w  = (const float*)d_in[18];
  const float* c1b  = (const float*)d_in[19];
  const float* c2w  = (const float*)d_in[20];
  const float* c2b  = (const float*)d_in[21];
  const float* Wa1  = (const float*)d_in[22];
  const float* ba1  = (const float*)d_in[23];
  const float* Wa2  = (const float*)d_in[24];
  const float* ba2  = (const float*)d_in[25];

  // exact byte needs per PB (floats*4): planes 5*PB*4194304, hbuf 2*PB*524288,
  // score 2*PB*4096, idx 2*PB*1024, qkvo 4*2*PB*131072, misc 3072
  auto needB = [](int PB)->size_t{
    return ((size_t)5*PB*4194304 + (size_t)2*PB*524288 + (size_t)2*PB*4096
          + (size_t)2*PB*1024 + (size_t)8*PB*131072 + 4096) * 4;
  };
  const int PB = (ws_size >= needB(4)) ? 4 : (ws_size >= needB(2)) ? 2 : 1;

  float* ws = (float*)d_ws;
  const size_t SL = (size_t)PB*4194304;    // per-group slab (floats)
  float* P0 = ws;
  float* P1 = P0 + SL;
  float* P2 = P1 + SL;
  float* P3 = P2 + SL;
  float* P4 = P3 + SL;
  float* sm = P4 + SL;
  float* hbuf  = sm; sm += (size_t)2*PB*524288;    // [2][PB*4096][128]
  float* score = sm; sm += (size_t)2*PB*4096;      // [2*PB][4096]
  int*   idxb  = (int*)sm; sm += (size_t)2*PB*1024;// [2*PB][1024]
  float* qbuf  = sm; sm += (size_t)2*PB*131072;    // [2*PB][1024][128]
  float* kbuf  = sm; sm += (size_t)2*PB*131072;
  float* vbuf  = sm; sm += (size_t)2*PB*131072;
  float* obuf  = sm; sm += (size_t)2*PB*131072;
  float* pooled= sm; sm += 512;
  float* IP    = sm; sm += 1024;
  float* IPint = sm; sm += 1024;
  float* modg  = sm; sm += 256;
  float* modb  = sm; sm += 256;

  kern_pool <<<512, 256, 0, stream>>>(vis, irf, pooled);
  kern_small<<<1, 256, 0, stream>>>(pooled, Wr, br, bank, Wpri, Wint,
                                    Wa1, ba1, Wa2, ba2, IP, IPint, modg, modb);

  for (int b0 = 0; b0 < 4; b0 += PB){
    const float* vis_b = vis + (size_t)b0*4194304;
    const float* ir_b  = irf + (size_t)b0*4194304;
    float* OUT = (float*)d_out + (size_t)b0*4194304;  // transient re / FULL_amp / spatial

    // forward FFT2 + amp/phase (patchified layout)
    kern_fft_rows_fwd<<<PB*8192, 256, 0, stream>>>(vis_b, OUT, P4);
    kern_fft_cols<0> <<<PB*1024, 256, 0, stream>>>(OUT, P4, P0, P1);  // AMP_V, PH_V
    kern_fft_rows_fwd<<<PB*8192, 256, 0, stream>>>(ir_b, OUT, P4);
    kern_fft_cols<0> <<<PB*1024, 256, 0, stream>>>(OUT, P4, P2, P3);  // AMP_I, PH_I

    {  // h = cat(vt,it)@Wtok + IP[b] + coords@Wco + bs   (both branches, z=2)
      GP p{};
      p.A0[0]=P0; p.A1[0]=P2; p.A0[1]=P1; p.A1[1]=P3;
      for (int z = 0; z < 2; ++z){
        p.Bm[z] = Wtok + (size_t)z*262144;
        p.Cm[z] = hbuf + (size_t)z*PB*524288;
        p.ep0[z] = IP + z*512 + b0*128;
        p.ep1[z] = Wco + z*256;
        p.ep2[z] = bs + z*128;
      }
      p.M = PB*4096; p.N = 128; p.K = 2048;
      kern_gemm<1,1><<<dim3(2, PB*32, 2), 256, 0, stream>>>(p);
    }
    kern_score<<<dim3(PB*4096, 2), 64, 0, stream>>>(hbuf, Wout, bout, score, PB*4096);
    kern_topk <<<2*PB, 1024, 0, stream>>>(score, idxb);
    {  // bypass blend into FULL (amp -> OUT, ph -> P4), both branches
      GP p{};
      p.A0[0]=P0; p.A1[0]=P2; p.A0[1]=P1; p.A1[1]=P3;
      p.vt[0]=P0; p.it[0]=P2; p.vt[1]=P1; p.it[1]=P3;
      p.Cm[0]=OUT; p.Cm[1]=P4;
      for (int z = 0; z < 2; ++z){
        p.Bm[z] = Wbyp + (size_t)z*2097152;
        p.ep0[z] = bbyp + z*1024;
      }
      p.M = PB*4096; p.N = 1024; p.K = 2048;
      kern_gemm<1,2><<<dim3(16, PB*32, 2), 256, 0, stream>>>(p);
    }
    {  // q,k,v gathered rows: z = br*3 + {q,k,v}
      GP p{};
      const float* Aplanes[6] = {P0, P2, P2, P1, P3, P3};
      const float* Bmats[6] = {Wq, Wk, Wv, Wq+131072, Wk+131072, Wv+131072};
      float* Cms[6] = {qbuf, kbuf, vbuf,
                       qbuf+(size_t)PB*131072, kbuf+(size_t)PB*131072, vbuf+(size_t)PB*131072};
      for (int z = 0; z < 6; ++z){
        p.A0[z] = Aplanes[z]; p.Bm[z] = Bmats[z]; p.Cm[z] = Cms[z];
        p.idxp[z] = idxb + (z < 3 ? 0 : PB*1024);
      }
      p.M = PB*1024; p.N = 128; p.K = 1024;
      kern_gemm<2,0><<<dim3(2, PB*8, 6), 256, 0, stream>>>(p);
    }
    kern_attn<<<dim3(4, 4, 2*PB), 256, 0, stream>>>(qbuf, kbuf, vbuf, obuf,
                                                    IPint, PB, b0);
    {  // fused_sel = vs + o@Wo scattered into FULL, both branches
      GP p{};
      p.A0[0]=obuf; p.A0[1]=obuf+(size_t)PB*131072;
      p.Bm[0]=Wo; p.Bm[1]=Wo+131072;
      p.Cm[0]=OUT; p.Cm[1]=P4;
      p.vt[0]=P0; p.vt[1]=P1;
      p.idxp[0]=idxb; p.idxp[1]=idxb+PB*1024;
      p.M = PB*1024; p.N = 1024; p.K = 128;
      kern_gemm<0,3><<<dim3(16, PB*8, 2), 256, 0, stream>>>(p);
    }

    // spec = famp * e^{i fph}; inverse FFT2 -> spatial into OUT (d_out slab)
    kern_ifft_rows_spec<<<PB*4096, 256, 0, stream>>>(OUT, P4, P0, P1);
    kern_fft_cols<1>   <<<PB*1024, 256, 0, stream>>>(P0, P1, OUT, nullptr);
  }

  // batch-wide convs: d_out(spatial all 4) -> ws (conv1) -> d_out (conv2+mod+residual)
  kern_conv<<<dim3(32,16,4), 256, 0, stream>>>((float*)d_out, c1w, c1b, ws, 1,
                                               nullptr, nullptr, nullptr, nullptr);
  kern_conv<<<dim3(32,16,4), 256, 0, stream>>>(ws, c2w, c2b, (float*)d_out, 2,
                                               modg, modb, vis, irf);
}

// Round 4
// 4145.576 us; speedup vs baseline: 3.2664x; 1.4056x over previous
//
#include <hip/hip_runtime.h>

typedef unsigned int uint;
typedef unsigned long long u64;
typedef __attribute__((ext_vector_type(8))) short short8;
typedef __attribute__((ext_vector_type(4))) float f32x4;

__device__ __forceinline__ uint brev8(uint x){ return __brev(x) >> 24; }
__device__ __forceinline__ float geluf(float x){
  return 0.5f*x*(1.f + tanhf(0.7978845608028654f*(x + 0.044715f*x*x*x)));
}
__device__ __forceinline__ unsigned short f2bf(float f){
  unsigned u = __float_as_uint(f);
  unsigned r = u + 0x7FFFu + ((u >> 16) & 1u);
  return (unsigned short)(r >> 16);
}

// ---------------- pooled mean (global, all 4 batches) ----------------
__global__ __launch_bounds__(256) void kern_pool(const float* __restrict__ vis,
                                                 const float* __restrict__ irf,
                                                 float* __restrict__ pooled){
  __shared__ float red[256];
  int bc = blockIdx.x;            // b*128 + cc
  int b = bc >> 7, cc = bc & 127;
  const float* src = (cc < 64) ? (vis + (size_t)(b*64+cc)*65536)
                               : (irf + (size_t)(b*64+(cc-64))*65536);
  float s = 0.f;
  for (int i = threadIdx.x; i < 65536; i += 256) s += src[i];
  red[threadIdx.x] = s;
  __syncthreads();
  for (int off = 128; off > 0; off >>= 1){
    if (threadIdx.x < off) red[threadIdx.x] += red[threadIdx.x + off];
    __syncthreads();
  }
  if (threadIdx.x == 0) pooled[bc] = red[0] * (1.f/65536.f);
}

// ---------------- prompt/intent/affine small ops (global) ----------------
__global__ __launch_bounds__(256) void kern_small(const float* __restrict__ pooled,
    const float* __restrict__ Wr, const float* __restrict__ br,
    const float* __restrict__ bank, const float* __restrict__ Wpri,
    const float* __restrict__ Wint, const float* __restrict__ Wa1,
    const float* __restrict__ ba1, const float* __restrict__ Wa2,
    const float* __restrict__ ba2,
    float* __restrict__ IP, float* __restrict__ IPint,
    float* __restrict__ modg, float* __restrict__ modb){
  __shared__ float logit_s[16];
  __shared__ float pw_s[16];
  __shared__ float intent_s[4][64];
  __shared__ float t1_s[4][128];
  int t = threadIdx.x;
  if (t < 16){
    int b = t >> 2, j = t & 3;
    float s = br[j];
    for (int k = 0; k < 128; ++k) s += pooled[b*128+k]*Wr[k*4+j];
    logit_s[t] = s;
  }
  __syncthreads();
  if (t < 4){
    int b = t;
    float m = logit_s[b*4];
    for (int j = 1; j < 4; ++j) m = fmaxf(m, logit_s[b*4+j]);
    float e[4], sum = 0.f;
    for (int j = 0; j < 4; ++j){ e[j] = expf(logit_s[b*4+j]-m); sum += e[j]; }
    for (int j = 0; j < 4; ++j) pw_s[b*4+j] = e[j]/sum;
  }
  __syncthreads();
  {
    int b = t >> 6, p = t & 63;
    float s = 0.f;
    for (int j = 0; j < 4; ++j) s += pw_s[b*4+j]*bank[j*64+p];
    intent_s[b][p] = s;
  }
  __syncthreads();
  for (int o = t; o < 1024; o += 256){
    int i = o >> 9, rem = o & 511, b = rem >> 7, n = rem & 127;
    float s1 = 0.f, s2 = 0.f;
    for (int p = 0; p < 64; ++p){
      float iv = intent_s[b][p];
      s1 += iv * Wpri[(i*64+p)*128 + n];
      s2 += iv * Wint[(i*64+p)*128 + n];
    }
    IP[o] = s1; IPint[o] = s2;
  }
  for (int o = t; o < 512; o += 256){
    int b = o >> 7, n = o & 127;
    float s = ba1[n];
    for (int p = 0; p < 64; ++p) s += intent_s[b][p]*Wa1[p*128+n];
    t1_s[b][n] = geluf(s);
  }
  __syncthreads();
  for (int o = t; o < 512; o += 256){
    int b = o >> 7, n = o & 127;
    float s = ba2[n];
    for (int p = 0; p < 128; ++p) s += t1_s[b][p]*Wa2[p*128+n];
    if (n < 64) modg[b*64+n] = 1.f + 0.1f*tanhf(s);
    else        modb[b*64+(n-64)] = 0.1f*s;
  }
}

// ---------------- forward row FFT (real input), slab-relative ----------------
__global__ __launch_bounds__(256) void kern_fft_rows_fwd(const float* __restrict__ x,
    float* __restrict__ sre, float* __restrict__ sim){
  __shared__ float re[2][256], im[2][256];
  __shared__ float twr[128], twi[128];
  int t = threadIdx.x;
  if (t < 128){
    float a = -6.2831853071795864f * (float)t * (1.f/256.f);
    sincosf(a, &twi[t], &twr[t]);
  }
  int r = t >> 7, jj = t & 127;
  size_t row = (size_t)blockIdx.x*2 + r;   // flat row over (b,c,h) within slab
  {
    const float* xp = x + row*256;
    re[r][jj] = xp[jj]; re[r][jj+128] = xp[jj+128];
    im[r][jj] = 0.f;    im[r][jj+128] = 0.f;
  }
  __syncthreads();
  for (int s = 0; s < 8; ++s){
    int half = 128 >> s;
    int j = jj & (half-1);
    int g = jj >> (7-s);
    int k = (g << (8-s)) + j;
    int m = j << s;
    float wc = twr[m], ws = twi[m];
    float are = re[r][k],      aim = im[r][k];
    float bre = re[r][k+half], bim = im[r][k+half];
    re[r][k] = are + bre; im[r][k] = aim + bim;
    float tr = are - bre, ti = aim - bim;
    re[r][k+half] = tr*wc - ti*ws;
    im[r][k+half] = tr*ws + ti*wc;
    __syncthreads();
  }
  {
    float* orp = sre + row*256; float* oip = sim + row*256;
    int w1 = jj, w2 = jj + 128;
    orp[w1] = re[r][brev8(w1)]; oip[w1] = im[r][brev8(w1)];
    orp[w2] = re[r][brev8(w2)]; oip[w2] = im[r][brev8(w2)];
  }
}

// ---------------- inverse row FFT with spec construction (reads patchified amp/ph) ----
__global__ __launch_bounds__(256) void kern_ifft_rows_spec(const float* __restrict__ famp,
    const float* __restrict__ fph, float* __restrict__ sre, float* __restrict__ sim){
  __shared__ float re[4][256], im[4][256];
  __shared__ float twr[128], twi[128];
  int t = threadIdx.x;
  if (t < 128){
    float a = -6.2831853071795864f * (float)t * (1.f/256.f);
    sincosf(a, &twi[t], &twr[t]);
  }
  int R = blockIdx.x * 4;
  {
    int r = t >> 6, q = t & 63;
    int row = R + r;
    int bc = row >> 8, h = row & 255;
    int b = bc >> 6, c = bc & 63;
    size_t addr = ((size_t)(b*4096 + (h>>2)*64 + q))*1024 + c*16 + (h&3)*4;
    float4 a4 = *(const float4*)(famp + addr);
    float4 p4 = *(const float4*)(fph + addr);
    float sn, cs;
    sincosf(p4.x, &sn, &cs); re[r][4*q+0] = a4.x*cs; im[r][4*q+0] = a4.x*sn;
    sincosf(p4.y, &sn, &cs); re[r][4*q+1] = a4.y*cs; im[r][4*q+1] = a4.y*sn;
    sincosf(p4.z, &sn, &cs); re[r][4*q+2] = a4.z*cs; im[r][4*q+2] = a4.z*sn;
    sincosf(p4.w, &sn, &cs); re[r][4*q+3] = a4.w*cs; im[r][4*q+3] = a4.w*sn;
  }
  __syncthreads();
  for (int s = 0; s < 8; ++s){
    int half = 128 >> s;
    #pragma unroll
    for (int bi0 = 0; bi0 < 2; ++bi0){
      int bi = t + bi0*256;
      int r = bi >> 7, tj = bi & 127;
      int j = tj & (half-1);
      int g = tj >> (7-s);
      int k = (g << (8-s)) + j;
      int m = j << s;
      float wc = twr[m], ws = -twi[m];
      float are = re[r][k],      aim = im[r][k];
      float bre = re[r][k+half], bim = im[r][k+half];
      re[r][k] = are + bre; im[r][k] = aim + bim;
      float tr = are - bre, ti = aim - bim;
      re[r][k+half] = tr*wc - ti*ws;
      im[r][k+half] = tr*ws + ti*wc;
    }
    __syncthreads();
  }
  {
    int r = t >> 6, q = t & 63;
    size_t row = (size_t)R + r;
    float4 vr, vi;
    vr.x = re[r][brev8(4*q+0)]; vi.x = im[r][brev8(4*q+0)];
    vr.y = re[r][brev8(4*q+1)]; vi.y = im[r][brev8(4*q+1)];
    vr.z = re[r][brev8(4*q+2)]; vi.z = im[r][brev8(4*q+2)];
    vr.w = re[r][brev8(4*q+3)]; vi.w = im[r][brev8(4*q+3)];
    *(float4*)(sre + row*256 + 4*q) = vr;
    *(float4*)(sim + row*256 + 4*q) = vi;
  }
}

// ---------------- column FFT: DIR=0 fwd (amp/ph patchified out), DIR=1 inv (real out) ----
template<int DIR>
__global__ __launch_bounds__(256) void kern_fft_cols(const float* __restrict__ sre,
    const float* __restrict__ sim, float* __restrict__ out0, float* __restrict__ out1){
  __shared__ float reL[256*17];
  __shared__ float imL[256*17];
  __shared__ float twr[128], twi[128];
  int t = threadIdx.x;
  if (t < 128){
    float a = -6.2831853071795864f * (float)t * (1.f/256.f);
    sincosf(a, &twi[t], &twr[t]);
  }
  int img = blockIdx.x >> 4;                 // b*64+c within slab
  int c0 = (blockIdx.x & 15) * 16;
  {
    const float* pr = sre + ((size_t)img*256 + t)*256 + c0;
    const float* pi = sim + ((size_t)img*256 + t)*256 + c0;
    #pragma unroll
    for (int p = 0; p < 4; ++p){
      float4 vr = *(const float4*)(pr + 4*p);
      float4 vi = *(const float4*)(pi + 4*p);
      int base = t*17 + 4*p;
      reL[base+0]=vr.x; reL[base+1]=vr.y; reL[base+2]=vr.z; reL[base+3]=vr.w;
      imL[base+0]=vi.x; imL[base+1]=vi.y; imL[base+2]=vi.z; imL[base+3]=vi.w;
    }
  }
  __syncthreads();
  int col = t & 15, tb = t >> 4;
  for (int s = 0; s < 8; ++s){
    int half = 128 >> s;
    #pragma unroll
    for (int it = 0; it < 8; ++it){
      int tj = tb + it*16;
      int j = tj & (half-1);
      int g = tj >> (7-s);
      int k = (g << (8-s)) + j;
      int m = j << s;
      float wc = twr[m];
      float ws = (DIR == 0) ? twi[m] : -twi[m];
      int i0 = k*17 + col, i1 = (k+half)*17 + col;
      float are = reL[i0], aim = imL[i0];
      float bre = reL[i1], bim = imL[i1];
      reL[i0] = are + bre; imL[i0] = aim + bim;
      float tr = are - bre, ti = aim - bim;
      reL[i1] = tr*wc - ti*ws;
      imL[i1] = tr*ws + ti*wc;
    }
    __syncthreads();
  }
  int b = img >> 6, c = img & 63;
  int h = t; int src = (int)brev8((uint)h);
  if (DIR == 0){
    int gy = h >> 2, py = h & 3;
    #pragma unroll
    for (int p = 0; p < 4; ++p){
      float4 av, pv;
      int base = src*17 + 4*p;
      float rr, ii;
      rr = reL[base+0]; ii = imL[base+0]; av.x = sqrtf(rr*rr+ii*ii); pv.x = atan2f(ii, rr);
      rr = reL[base+1]; ii = imL[base+1]; av.y = sqrtf(rr*rr+ii*ii); pv.y = atan2f(ii, rr);
      rr = reL[base+2]; ii = imL[base+2]; av.z = sqrtf(rr*rr+ii*ii); pv.z = atan2f(ii, rr);
      rr = reL[base+3]; ii = imL[base+3]; av.w = sqrtf(rr*rr+ii*ii); pv.w = atan2f(ii, rr);
      size_t addr = ((size_t)(b*4096 + gy*64 + (c0>>2) + p))*1024 + c*16 + py*4;
      *(float4*)(out0 + addr) = av;
      *(float4*)(out1 + addr) = pv;
    }
  } else {
    float* op = out0 + ((size_t)img*256 + h)*256 + c0;
    #pragma unroll
    for (int p = 0; p < 4; ++p){
      int base = src*17 + 4*p;
      float4 v;
      v.x = reL[base+0]*(1.f/65536.f);
      v.y = reL[base+1]*(1.f/65536.f);
      v.z = reL[base+2]*(1.f/65536.f);
      v.w = reL[base+3]*(1.f/65536.f);
      *(float4*)(op + 4*p) = v;
    }
  }
}

// ---------------- MFMA bf16 tiled GEMM, z-fused over branches/matrices ----------
// Tile BM x 128, BK=32, 4 waves (2x2), wave tile (BM/2) x 64 of 16x16x32 frags.
// AMODE: 0 plain A0 (lda=K), 1 cat(A0|A1) along K (each 1024 wide), 2 gather via idx
// EPI:   0 store C, 1 h-epi (+IP[b]+coords@Wco+bs), 2 bypass blend, 3 scatter+vs
struct GP {
  const float* A0[6];
  const float* A1[2];
  const float* Bm[6];
  float*       Cm[6];
  const int*   idxp[6];
  const float* ep0[2];
  const float* ep1[2];
  const float* ep2[2];
  const float* vt[2];
  const float* it[2];
  int M, N, K;
};

template<int BM, int AMODE, int EPI>
__global__ __launch_bounds__(256) void kern_mgemm(GP p){
  constexpr int LBM = (BM == 128) ? 7 : 6;
  constexpr int FR  = BM / 32;          // frags per wave in M
  constexpr int HB  = BM / 2;           // wave rows
  __shared__ __align__(16) unsigned short Asb[BM*40];
  __shared__ __align__(16) unsigned short Bsb[128*40];
  __shared__ int idx_s[BM];
  int z = blockIdx.z;
  const float* A0 = p.A0[z];
  const float* Bm = p.Bm[z];
  float* Cm = p.Cm[z];
  int tid = threadIdx.x;
  int m0 = blockIdx.y * BM;
  int n0 = blockIdx.x * 128;
  int lane = tid & 63;
  int w = tid >> 6;
  int wr = w & 1, wc = w >> 1;
  int lr = lane & 15, ql = lane >> 4;

  if (AMODE == 2 || EPI == 3){
    if (tid < BM){
      int m = m0 + tid;
      idx_s[tid] = p.idxp[z][(m >> 10)*1024 + (m & 1023)];
    }
    __syncthreads();
  }
  int gb = m0 >> 10;

  f32x4 acc[FR][4];
  #pragma unroll
  for (int i = 0; i < FR; ++i)
    #pragma unroll
    for (int j = 0; j < 4; ++j) acc[i][j] = (f32x4){0.f,0.f,0.f,0.f};

  for (int k0 = 0; k0 < p.K; k0 += 32){
    // ---- stage A (BM x 32 fp32 -> bf16 LDS, row stride 40) ----
    #pragma unroll
    for (int e0 = 0; e0 < BM*4; e0 += 256){
      int e = e0 + tid;
      int m = e & (BM-1);
      int kh = (e >> LBM) * 8;
      int k2 = k0 + kh;
      const float* ap;
      if (AMODE == 0){
        ap = A0 + (size_t)(m0+m)*p.K + k2;
      } else if (AMODE == 1){
        const float* src = (k2 < 1024) ? A0 : p.A1[z];
        int kk = (k2 < 1024) ? k2 : (k2 - 1024);
        ap = src + (size_t)(m0+m)*1024 + kk;
      } else {
        ap = A0 + ((size_t)(gb << 12) + idx_s[m])*(size_t)p.K + k2;
      }
      float4 f0 = *(const float4*)ap;
      float4 f1 = *(const float4*)(ap + 4);
      short8 v;
      v[0]=(short)f2bf(f0.x); v[1]=(short)f2bf(f0.y);
      v[2]=(short)f2bf(f0.z); v[3]=(short)f2bf(f0.w);
      v[4]=(short)f2bf(f1.x); v[5]=(short)f2bf(f1.y);
      v[6]=(short)f2bf(f1.z); v[7]=(short)f2bf(f1.w);
      *(short8*)&Asb[m*40 + kh] = v;
    }
    // ---- stage B (32 x 128 fp32 -> bf16 LDS transposed [n][k], stride 40) ----
    #pragma unroll
    for (int e0 = 0; e0 < 512; e0 += 256){
      int e = e0 + tid;
      int n = e & 127;
      int kh = (e >> 7) * 8;
      const float* bp = Bm + (size_t)(k0+kh)*p.N + n0 + n;
      short8 v;
      #pragma unroll
      for (int j = 0; j < 8; ++j) v[j] = (short)f2bf(bp[(size_t)j*p.N]);
      *(short8*)&Bsb[n*40 + kh] = v;
    }
    __syncthreads();
    // ---- fragments + MFMA ----
    short8 af[FR], bf[4];
    #pragma unroll
    for (int fr = 0; fr < FR; ++fr)
      af[fr] = *(const short8*)&Asb[(wr*HB + fr*16 + lr)*40 + ql*8];
    #pragma unroll
    for (int fc = 0; fc < 4; ++fc)
      bf[fc] = *(const short8*)&Bsb[(wc*64 + fc*16 + lr)*40 + ql*8];
    #pragma unroll
    for (int fr = 0; fr < FR; ++fr)
      #pragma unroll
      for (int fc = 0; fc < 4; ++fc)
        acc[fr][fc] = __builtin_amdgcn_mfma_f32_16x16x32_bf16(af[fr], bf[fc],
                                                              acc[fr][fc], 0, 0, 0);
    __syncthreads();
  }

  // ---- epilogue: D lane map col = lane&15, row = (lane>>4)*4 + reg ----
  #pragma unroll
  for (int fr = 0; fr < FR; ++fr){
    #pragma unroll
    for (int fc = 0; fc < 4; ++fc){
      int n = n0 + wc*64 + fc*16 + lr;
      #pragma unroll
      for (int reg = 0; reg < 4; ++reg){
        int mloc = wr*HB + fr*16 + ql*4 + reg;
        int m = m0 + mloc;
        float v = acc[fr][fc][reg];
        if (EPI == 0){
          Cm[(size_t)m*p.N + n] = v;
        } else if (EPI == 1){
          int bl = m >> 12, g = m & 4095;
          int gy = g >> 6, gx = g & 63;
          float cy = ((float)gy + 0.5f)*(1.f/64.f);
          float cx = ((float)gx + 0.5f)*(1.f/64.f);
          float o = v + p.ep0[z][bl*128 + n] + cy*p.ep1[z][n]
                  + cx*p.ep1[z][128 + n] + p.ep2[z][n];
          Cm[(size_t)m*128 + n] = o;
        } else if (EPI == 2){
          float vt = p.vt[z][(size_t)m*1024 + n];
          float it = p.it[z][(size_t)m*1024 + n];
          float gg = 1.f/(1.f + expf(-(v + p.ep0[z][n])));
          Cm[(size_t)m*1024 + n] = gg*vt + (1.f-gg)*it;
        } else {
          int gt = idx_s[mloc];
          size_t off = ((size_t)(gb << 12) + gt)*1024 + n;
          Cm[off] = v + p.vt[z][off];
        }
      }
    }
  }
}

// ---------------- score = gelu(h) @ Wout + bout (branch via blockIdx.y) -----------
__global__ __launch_bounds__(64) void kern_score(const float* __restrict__ h,
    const float* __restrict__ wout, const float* __restrict__ bout,
    float* __restrict__ score, int Mper){
  int m = blockIdx.x, br = blockIdx.y, t = threadIdx.x;
  const float* hp = h + ((size_t)br*Mper + m)*128;
  const float* wp = wout + br*128;
  float s = geluf(hp[t])*wp[t] + geluf(hp[t+64])*wp[t+64];
  #pragma unroll
  for (int off = 32; off > 0; off >>= 1) s += __shfl_down(s, off);
  if (t == 0) score[(size_t)br*Mper + m] = s + bout[br];
}

// ---------------- per-(branch,batch) top-1024 of 4096 (bitonic, jax tie-break) ----
__global__ __launch_bounds__(1024) void kern_topk(const float* __restrict__ score,
    int* __restrict__ idx_out){
  __shared__ u64 keys[4096];
  int b = blockIdx.x, t = threadIdx.x;
  for (int i = t; i < 4096; i += 1024){
    float s = score[b*4096 + i];
    uint u = __float_as_uint(s);
    uint msk = (u & 0x80000000u) ? ~u : (u | 0x80000000u);
    keys[i] = ((u64)msk << 32) | (uint)(4095 - i);
  }
  __syncthreads();
  for (int k = 2; k <= 4096; k <<= 1){
    for (int j = k >> 1; j > 0; j >>= 1){
      for (int i = t; i < 4096; i += 1024){
        int l = i ^ j;
        if (l > i){
          u64 a = keys[i], c = keys[l];
          bool descB = ((i & k) == 0);
          bool sw = descB ? (a < c) : (a > c);
          if (sw){ keys[i] = c; keys[l] = a; }
        }
      }
      __syncthreads();
    }
  }
  idx_out[b*1024 + t] = 4095 - (int)(keys[t] & 0xFFFFFFFFu);
}

// ---------------- attention (flash-style, dh=32, 4 heads, z = br*PB+bb) ----------
__global__ __launch_bounds__(256) void kern_attn(const float* __restrict__ qb,
    const float* __restrict__ kb, const float* __restrict__ vb,
    float* __restrict__ ob, const float* __restrict__ ipint,
    int PB, int b0){
  __shared__ float Ks[64][32];
  __shared__ float Vs[64][32];
  int t = threadIdx.x;
  int hh = blockIdx.y, zf = blockIdx.z;
  size_t boff = (size_t)zf*131072;
  int jq = blockIdx.x*256 + t;
  float qv[32];
  {
    const float4* qp = (const float4*)(qb + boff + (size_t)jq*128 + hh*32);
    #pragma unroll
    for (int d = 0; d < 8; ++d) ((float4*)qv)[d] = qp[d];
  }
  float mrun = -3.0e38f, lrun = 0.f;
  float oa[32];
  #pragma unroll
  for (int d = 0; d < 32; ++d) oa[d] = 0.f;
  for (int kt = 0; kt < 16; ++kt){
    #pragma unroll
    for (int rep = 0; rep < 2; ++rep){
      int f = t + rep*256;
      int r = f >> 3, q4 = f & 7;
      size_t base = boff + (size_t)(kt*64 + r)*128 + hh*32 + 4*q4;
      *(float4*)&Ks[r][4*q4] = *(const float4*)(kb + base);
      *(float4*)&Vs[r][4*q4] = *(const float4*)(vb + base);
    }
    __syncthreads();
    float mt = -3.0e38f;
    for (int kk = 0; kk < 64; ++kk){
      float s = 0.f;
      #pragma unroll
      for (int d = 0; d < 32; ++d) s += qv[d]*Ks[kk][d];
      s *= 0.17677669529663687f;
      mt = fmaxf(mt, s);
    }
    float mnew = fmaxf(mrun, mt);
    float alpha = expf(mrun - mnew);
    lrun *= alpha;
    #pragma unroll
    for (int d = 0; d < 32; ++d) oa[d] *= alpha;
    for (int kk = 0; kk < 64; ++kk){
      float s = 0.f;
      #pragma unroll
      for (int d = 0; d < 32; ++d) s += qv[d]*Ks[kk][d];
      s *= 0.17677669529663687f;
      float pe = expf(s - mnew);
      lrun += pe;
      #pragma unroll
      for (int d = 0; d < 32; ++d) oa[d] += pe*Vs[kk][d];
    }
    mrun = mnew;
    __syncthreads();
  }
  float inv = 1.f/lrun;
  int br = (zf >= PB) ? 1 : 0;
  int bb = zf - br*PB;
  float* op = ob + boff + (size_t)jq*128 + hh*32;
  const float* ip = ipint + br*512 + (b0+bb)*128 + hh*32;
  #pragma unroll
  for (int d = 0; d < 32; ++d) op[d] = oa[d]*inv + ip[d];
}

// ---------------- direct 3x3 conv, 4 c_out per block, batch-wide ----------------
__global__ __launch_bounds__(256) void kern_conv(const float* __restrict__ in,
    const float* __restrict__ w, const float* __restrict__ bias,
    float* __restrict__ out, int mode,
    const float* __restrict__ modg, const float* __restrict__ modb,
    const float* __restrict__ vis, const float* __restrict__ irf){
  __shared__ float ls[10*258];
  int t = threadIdx.x;
  int y0 = blockIdx.x * 8;
  int co0 = blockIdx.y * 4;
  int b = blockIdx.z;
  float acc[8][4];
  #pragma unroll
  for (int r = 0; r < 8; ++r){
    #pragma unroll
    for (int c = 0; c < 4; ++c) acc[r][c] = 0.f;
  }
  for (int ci = 0; ci < 64; ++ci){
    const float* ip = in + ((size_t)(b*64+ci))*65536;
    #pragma unroll
    for (int rr = 0; rr < 10; ++rr){
      int y = y0 + rr - 1;
      for (int cc = t; cc < 258; cc += 256){
        int x = cc - 1;
        float v = 0.f;
        if (y >= 0 && y < 256 && x >= 0 && x < 256) v = ip[y*256+x];
        ls[rr*258+cc] = v;
      }
    }
    float wv[4][9];
    #pragma unroll
    for (int cw = 0; cw < 4; ++cw){
      const float* wp = w + ((size_t)(co0+cw)*64 + ci)*9;
      #pragma unroll
      for (int jx = 0; jx < 9; ++jx) wv[cw][jx] = wp[jx];
    }
    __syncthreads();
    int cc = t + 1;
    float a00 = ls[cc-1],      a01 = ls[cc],      a02 = ls[cc+1];
    float a10 = ls[258+cc-1],  a11 = ls[258+cc],  a12 = ls[258+cc+1];
    #pragma unroll
    for (int r = 0; r < 8; ++r){
      float a20 = ls[(r+2)*258+cc-1], a21 = ls[(r+2)*258+cc], a22 = ls[(r+2)*258+cc+1];
      #pragma unroll
      for (int cw = 0; cw < 4; ++cw){
        acc[r][cw] += a00*wv[cw][0]+a01*wv[cw][1]+a02*wv[cw][2]
                     +a10*wv[cw][3]+a11*wv[cw][4]+a12*wv[cw][5]
                     +a20*wv[cw][6]+a21*wv[cw][7]+a22*wv[cw][8];
      }
      a00=a10; a01=a11; a02=a12;
      a10=a20; a11=a12=0.f;  // overwritten below
      a10=a20; a11=ls[(r+2)*258+cc]; a12=ls[(r+2)*258+cc+1];
    }
    __syncthreads();
  }
  int x = t;
  #pragma unroll
  for (int r = 0; r < 8; ++r){
    int y = y0 + r;
    #pragma unroll
    for (int cw = 0; cw < 4; ++cw){
      int co = co0 + cw;
      float v = acc[r][cw] + bias[co];
      size_t oi = ((size_t)(b*64+co)*256 + y)*256 + x;
      if (mode == 1) out[oi] = fmaxf(v, 0.f);
      else {
        v = v*modg[b*64+co] + modb[b*64+co] + 0.5f*(vis[oi]+irf[oi]);
        out[oi] = v;
      }
    }
  }
}

// ---------------- launch ----------------
extern "C" void kernel_launch(void* const* d_in, const int* in_sizes, int n_in,
                              void* d_out, int out_size, void* d_ws, size_t ws_size,
                              hipStream_t stream){
  (void)in_sizes; (void)n_in; (void)out_size;
  const float* vis  = (const float*)d_in[0];
  const float* irf  = (const float*)d_in[1];
  const float* bank = (const float*)d_in[2];
  const float* Wr   = (const float*)d_in[3];
  const float* br   = (const float*)d_in[4];
  const float* Wtok = (const float*)d_in[5];
  const float* Wpri = (const float*)d_in[6];
  const float* Wco  = (const float*)d_in[7];
  const float* bs   = (const float*)d_in[8];
  const float* Wout = (const float*)d_in[9];
  const float* bout = (const float*)d_in[10];
  const float* Wq   = (const float*)d_in[11];
  const float* Wk   = (const float*)d_in[12];
  const float* Wv   = (const float*)d_in[13];
  const float* Wo   = (const float*)d_in[14];
  const float* Wint = (const float*)d_in[15];
  const float* Wbyp = (const float*)d_in[16];
  const float* bbyp = (const float*)d_in[17];
  const float* c1w  = (const float*)d_in[18];
  const float* c1b  = (const float*)d_in[19];
  const float* c2w  = (const float*)d_in[20];
  const float* c2b  = (const float*)d_in[21];
  const float* Wa1  = (const float*)d_in[22];
  const float* ba1  = (const float*)d_in[23];
  const float* Wa2  = (const float*)d_in[24];
  const float* ba2  = (const float*)d_in[25];

  auto needB = [](int PB)->size_t{
    return ((size_t)5*PB*4194304 + (size_t)2*PB*524288 + (size_t)2*PB*4096
          + (size_t)2*PB*1024 + (size_t)8*PB*131072 + 4096) * 4;
  };
  const int PB = (ws_size >= needB(4)) ? 4 : (ws_size >= needB(2)) ? 2 : 1;

  float* ws = (float*)d_ws;
  const size_t SL = (size_t)PB*4194304;    // per-group slab (floats)
  float* P0 = ws;
  float* P1 = P0 + SL;
  float* P2 = P1 + SL;
  float* P3 = P2 + SL;
  float* P4 = P3 + SL;
  float* sm = P4 + SL;
  float* hbuf  = sm; sm += (size_t)2*PB*524288;    // [2][PB*4096][128]
  float* score = sm; sm += (size_t)2*PB*4096;      // [2*PB][4096]
  int*   idxb  = (int*)sm; sm += (size_t)2*PB*1024;// [2*PB][1024]
  float* qbuf  = sm; sm += (size_t)2*PB*131072;    // [2*PB][1024][128]
  float* kbuf  = sm; sm += (size_t)2*PB*131072;
  float* vbuf  = sm; sm += (size_t)2*PB*131072;
  float* obuf  = sm; sm += (size_t)2*PB*131072;
  float* pooled= sm; sm += 512;
  float* IP    = sm; sm += 1024;
  float* IPint = sm; sm += 1024;
  float* modg  = sm; sm += 256;
  float* modb  = sm; sm += 256;

  kern_pool <<<512, 256, 0, stream>>>(vis, irf, pooled);
  kern_small<<<1, 256, 0, stream>>>(pooled, Wr, br, bank, Wpri, Wint,
                                    Wa1, ba1, Wa2, ba2, IP, IPint, modg, modb);

  for (int b0 = 0; b0 < 4; b0 += PB){
    const float* vis_b = vis + (size_t)b0*4194304;
    const float* ir_b  = irf + (size_t)b0*4194304;
    float* OUT = (float*)d_out + (size_t)b0*4194304;  // transient re / FULL_amp / spatial

    // forward FFT2 + amp/phase (patchified layout)
    kern_fft_rows_fwd<<<PB*8192, 256, 0, stream>>>(vis_b, OUT, P4);
    kern_fft_cols<0> <<<PB*1024, 256, 0, stream>>>(OUT, P4, P0, P1);  // AMP_V, PH_V
    kern_fft_rows_fwd<<<PB*8192, 256, 0, stream>>>(ir_b, OUT, P4);
    kern_fft_cols<0> <<<PB*1024, 256, 0, stream>>>(OUT, P4, P2, P3);  // AMP_I, PH_I

    {  // h = cat(vt,it)@Wtok + IP[b] + coords@Wco + bs   (both branches, z=2)
      GP p{};
      p.A0[0]=P0; p.A1[0]=P2; p.A0[1]=P1; p.A1[1]=P3;
      for (int z = 0; z < 2; ++z){
        p.Bm[z] = Wtok + (size_t)z*262144;
        p.Cm[z] = hbuf + (size_t)z*PB*524288;
        p.ep0[z] = IP + z*512 + b0*128;
        p.ep1[z] = Wco + z*256;
        p.ep2[z] = bs + z*128;
      }
      p.M = PB*4096; p.N = 128; p.K = 2048;
      kern_mgemm<64,1,1><<<dim3(1, PB*64, 2), 256, 0, stream>>>(p);
    }
    kern_score<<<dim3(PB*4096, 2), 64, 0, stream>>>(hbuf, Wout, bout, score, PB*4096);
    kern_topk <<<2*PB, 1024, 0, stream>>>(score, idxb);
    {  // bypass blend into FULL (amp -> OUT, ph -> P4), both branches
      GP p{};
      p.A0[0]=P0; p.A1[0]=P2; p.A0[1]=P1; p.A1[1]=P3;
      p.vt[0]=P0; p.it[0]=P2; p.vt[1]=P1; p.it[1]=P3;
      p.Cm[0]=OUT; p.Cm[1]=P4;
      for (int z = 0; z < 2; ++z){
        p.Bm[z] = Wbyp + (size_t)z*2097152;
        p.ep0[z] = bbyp + z*1024;
      }
      p.M = PB*4096; p.N = 1024; p.K = 2048;
      kern_mgemm<128,1,2><<<dim3(8, PB*32, 2), 256, 0, stream>>>(p);
    }
    {  // q,k,v gathered rows: z = br*3 + {q,k,v}
      GP p{};
      const float* Aplanes[6] = {P0, P2, P2, P1, P3, P3};
      const float* Bmats[6] = {Wq, Wk, Wv, Wq+131072, Wk+131072, Wv+131072};
      float* Cms[6] = {qbuf, kbuf, vbuf,
                       qbuf+(size_t)PB*131072, kbuf+(size_t)PB*131072, vbuf+(size_t)PB*131072};
      for (int z = 0; z < 6; ++z){
        p.A0[z] = Aplanes[z]; p.Bm[z] = Bmats[z]; p.Cm[z] = Cms[z];
        p.idxp[z] = idxb + (z < 3 ? 0 : PB*1024);
      }
      p.M = PB*1024; p.N = 128; p.K = 1024;
      kern_mgemm<64,2,0><<<dim3(1, PB*16, 6), 256, 0, stream>>>(p);
    }
    kern_attn<<<dim3(4, 4, 2*PB), 256, 0, stream>>>(qbuf, kbuf, vbuf, obuf,
                                                    IPint, PB, b0);
    {  // fused_sel = vs + o@Wo scattered into FULL, both branches
      GP p{};
      p.A0[0]=obuf; p.A0[1]=obuf+(size_t)PB*131072;
      p.Bm[0]=Wo; p.Bm[1]=Wo+131072;
      p.Cm[0]=OUT; p.Cm[1]=P4;
      p.vt[0]=P0; p.vt[1]=P1;
      p.idxp[0]=idxb; p.idxp[1]=idxb+PB*1024;
      p.M = PB*1024; p.N = 1024; p.K = 128;
      kern_mgemm<64,0,3><<<dim3(8, PB*16, 2), 256, 0, stream>>>(p);
    }

    // spec = famp * e^{i fph}; inverse FFT2 -> spatial into OUT (d_out slab)
    kern_ifft_rows_spec<<<PB*4096, 256, 0, stream>>>(OUT, P4, P0, P1);
    kern_fft_cols<1>   <<<PB*1024, 256, 0, stream>>>(P0, P1, OUT, nullptr);
  }

  // batch-wide convs: d_out(spatial all 4) -> ws (conv1) -> d_out (conv2+mod+residual)
  kern_conv<<<dim3(32,16,4), 256, 0, stream>>>((float*)d_out, c1w, c1b, ws, 1,
                                               nullptr, nullptr, nullptr, nullptr);
  kern_conv<<<dim3(32,16,4), 256, 0, stream>>>(ws, c2w, c2b, (float*)d_out, 2,
                                               modg, modb, vis, irf);
}

// Round 5
// 2676.425 us; speedup vs baseline: 5.0594x; 1.5489x over previous
//
#include <hip/hip_runtime.h>

typedef unsigned int uint;
typedef unsigned long long u64;
typedef __attribute__((ext_vector_type(8))) short short8;
typedef __attribute__((ext_vector_type(4))) float f32x4;

__device__ __forceinline__ uint brev8(uint x){ return __brev(x) >> 24; }
__device__ __forceinline__ float geluf(float x){
  return 0.5f*x*(1.f + tanhf(0.7978845608028654f*(x + 0.044715f*x*x*x)));
}
__device__ __forceinline__ unsigned short f2bf(float f){
  unsigned u = __float_as_uint(f);
  unsigned r = u + 0x7FFFu + ((u >> 16) & 1u);
  return (unsigned short)(r >> 16);
}

// ---------------- pooled mean (global, all 4 batches) ----------------
__global__ __launch_bounds__(256) void kern_pool(const float* __restrict__ vis,
                                                 const float* __restrict__ irf,
                                                 float* __restrict__ pooled){
  __shared__ float red[256];
  int bc = blockIdx.x;            // b*128 + cc
  int b = bc >> 7, cc = bc & 127;
  const float* src = (cc < 64) ? (vis + (size_t)(b*64+cc)*65536)
                               : (irf + (size_t)(b*64+(cc-64))*65536);
  float s = 0.f;
  for (int i = threadIdx.x; i < 65536; i += 256) s += src[i];
  red[threadIdx.x] = s;
  __syncthreads();
  for (int off = 128; off > 0; off >>= 1){
    if (threadIdx.x < off) red[threadIdx.x] += red[threadIdx.x + off];
    __syncthreads();
  }
  if (threadIdx.x == 0) pooled[bc] = red[0] * (1.f/65536.f);
}

// ---------------- prompt/intent/affine small ops (global) ----------------
__global__ __launch_bounds__(256) void kern_small(const float* __restrict__ pooled,
    const float* __restrict__ Wr, const float* __restrict__ br,
    const float* __restrict__ bank, const float* __restrict__ Wpri,
    const float* __restrict__ Wint, const float* __restrict__ Wa1,
    const float* __restrict__ ba1, const float* __restrict__ Wa2,
    const float* __restrict__ ba2,
    float* __restrict__ IP, float* __restrict__ IPint,
    float* __restrict__ modg, float* __restrict__ modb){
  __shared__ float logit_s[16];
  __shared__ float pw_s[16];
  __shared__ float intent_s[4][64];
  __shared__ float t1_s[4][128];
  int t = threadIdx.x;
  if (t < 16){
    int b = t >> 2, j = t & 3;
    float s = br[j];
    for (int k = 0; k < 128; ++k) s += pooled[b*128+k]*Wr[k*4+j];
    logit_s[t] = s;
  }
  __syncthreads();
  if (t < 4){
    int b = t;
    float m = logit_s[b*4];
    for (int j = 1; j < 4; ++j) m = fmaxf(m, logit_s[b*4+j]);
    float e[4], sum = 0.f;
    for (int j = 0; j < 4; ++j){ e[j] = expf(logit_s[b*4+j]-m); sum += e[j]; }
    for (int j = 0; j < 4; ++j) pw_s[b*4+j] = e[j]/sum;
  }
  __syncthreads();
  {
    int b = t >> 6, p = t & 63;
    float s = 0.f;
    for (int j = 0; j < 4; ++j) s += pw_s[b*4+j]*bank[j*64+p];
    intent_s[b][p] = s;
  }
  __syncthreads();
  for (int o = t; o < 1024; o += 256){
    int i = o >> 9, rem = o & 511, b = rem >> 7, n = rem & 127;
    float s1 = 0.f, s2 = 0.f;
    for (int p = 0; p < 64; ++p){
      float iv = intent_s[b][p];
      s1 += iv * Wpri[(i*64+p)*128 + n];
      s2 += iv * Wint[(i*64+p)*128 + n];
    }
    IP[o] = s1; IPint[o] = s2;
  }
  for (int o = t; o < 512; o += 256){
    int b = o >> 7, n = o & 127;
    float s = ba1[n];
    for (int p = 0; p < 64; ++p) s += intent_s[b][p]*Wa1[p*128+n];
    t1_s[b][n] = geluf(s);
  }
  __syncthreads();
  for (int o = t; o < 512; o += 256){
    int b = o >> 7, n = o & 127;
    float s = ba2[n];
    for (int p = 0; p < 128; ++p) s += t1_s[b][p]*Wa2[p*128+n];
    if (n < 64) modg[b*64+n] = 1.f + 0.1f*tanhf(s);
    else        modb[b*64+(n-64)] = 0.1f*s;
  }
}

// ---------------- forward row FFT (real input), slab-relative ----------------
__global__ __launch_bounds__(256) void kern_fft_rows_fwd(const float* __restrict__ x,
    float* __restrict__ sre, float* __restrict__ sim){
  __shared__ float re[2][256], im[2][256];
  __shared__ float twr[128], twi[128];
  int t = threadIdx.x;
  if (t < 128){
    float a = -6.2831853071795864f * (float)t * (1.f/256.f);
    sincosf(a, &twi[t], &twr[t]);
  }
  int r = t >> 7, jj = t & 127;
  size_t row = (size_t)blockIdx.x*2 + r;   // flat row over (b,c,h) within slab
  {
    const float* xp = x + row*256;
    re[r][jj] = xp[jj]; re[r][jj+128] = xp[jj+128];
    im[r][jj] = 0.f;    im[r][jj+128] = 0.f;
  }
  __syncthreads();
  for (int s = 0; s < 8; ++s){
    int half = 128 >> s;
    int j = jj & (half-1);
    int g = jj >> (7-s);
    int k = (g << (8-s)) + j;
    int m = j << s;
    float wc = twr[m], ws = twi[m];
    float are = re[r][k],      aim = im[r][k];
    float bre = re[r][k+half], bim = im[r][k+half];
    re[r][k] = are + bre; im[r][k] = aim + bim;
    float tr = are - bre, ti = aim - bim;
    re[r][k+half] = tr*wc - ti*ws;
    im[r][k+half] = tr*ws + ti*wc;
    __syncthreads();
  }
  {
    float* orp = sre + row*256; float* oip = sim + row*256;
    int w1 = jj, w2 = jj + 128;
    orp[w1] = re[r][brev8(w1)]; oip[w1] = im[r][brev8(w1)];
    orp[w2] = re[r][brev8(w2)]; oip[w2] = im[r][brev8(w2)];
  }
}

// ---------------- inverse row FFT with spec construction (reads patchified amp/ph) ----
__global__ __launch_bounds__(256) void kern_ifft_rows_spec(const float* __restrict__ famp,
    const float* __restrict__ fph, float* __restrict__ sre, float* __restrict__ sim){
  __shared__ float re[4][256], im[4][256];
  __shared__ float twr[128], twi[128];
  int t = threadIdx.x;
  if (t < 128){
    float a = -6.2831853071795864f * (float)t * (1.f/256.f);
    sincosf(a, &twi[t], &twr[t]);
  }
  int R = blockIdx.x * 4;
  {
    int r = t >> 6, q = t & 63;
    int row = R + r;
    int bc = row >> 8, h = row & 255;
    int b = bc >> 6, c = bc & 63;
    size_t addr = ((size_t)(b*4096 + (h>>2)*64 + q))*1024 + c*16 + (h&3)*4;
    float4 a4 = *(const float4*)(famp + addr);
    float4 p4 = *(const float4*)(fph + addr);
    float sn, cs;
    sincosf(p4.x, &sn, &cs); re[r][4*q+0] = a4.x*cs; im[r][4*q+0] = a4.x*sn;
    sincosf(p4.y, &sn, &cs); re[r][4*q+1] = a4.y*cs; im[r][4*q+1] = a4.y*sn;
    sincosf(p4.z, &sn, &cs); re[r][4*q+2] = a4.z*cs; im[r][4*q+2] = a4.z*sn;
    sincosf(p4.w, &sn, &cs); re[r][4*q+3] = a4.w*cs; im[r][4*q+3] = a4.w*sn;
  }
  __syncthreads();
  for (int s = 0; s < 8; ++s){
    int half = 128 >> s;
    #pragma unroll
    for (int bi0 = 0; bi0 < 2; ++bi0){
      int bi = t + bi0*256;
      int r = bi >> 7, tj = bi & 127;
      int j = tj & (half-1);
      int g = tj >> (7-s);
      int k = (g << (8-s)) + j;
      int m = j << s;
      float wc = twr[m], ws = -twi[m];
      float are = re[r][k],      aim = im[r][k];
      float bre = re[r][k+half], bim = im[r][k+half];
      re[r][k] = are + bre; im[r][k] = aim + bim;
      float tr = are - bre, ti = aim - bim;
      re[r][k+half] = tr*wc - ti*ws;
      im[r][k+half] = tr*ws + ti*wc;
    }
    __syncthreads();
  }
  {
    int r = t >> 6, q = t & 63;
    size_t row = (size_t)R + r;
    float4 vr, vi;
    vr.x = re[r][brev8(4*q+0)]; vi.x = im[r][brev8(4*q+0)];
    vr.y = re[r][brev8(4*q+1)]; vi.y = im[r][brev8(4*q+1)];
    vr.z = re[r][brev8(4*q+2)]; vi.z = im[r][brev8(4*q+2)];
    vr.w = re[r][brev8(4*q+3)]; vi.w = im[r][brev8(4*q+3)];
    *(float4*)(sre + row*256 + 4*q) = vr;
    *(float4*)(sim + row*256 + 4*q) = vi;
  }
}

// ---------------- column FFT: DIR=0 fwd (amp/ph patchified out), DIR=1 inv (real out) ----
template<int DIR>
__global__ __launch_bounds__(256) void kern_fft_cols(const float* __restrict__ sre,
    const float* __restrict__ sim, float* __restrict__ out0, float* __restrict__ out1){
  __shared__ float reL[256*17];
  __shared__ float imL[256*17];
  __shared__ float twr[128], twi[128];
  int t = threadIdx.x;
  if (t < 128){
    float a = -6.2831853071795864f * (float)t * (1.f/256.f);
    sincosf(a, &twi[t], &twr[t]);
  }
  int img = blockIdx.x >> 4;                 // b*64+c within slab
  int c0 = (blockIdx.x & 15) * 16;
  {
    const float* pr = sre + ((size_t)img*256 + t)*256 + c0;
    const float* pi = sim + ((size_t)img*256 + t)*256 + c0;
    #pragma unroll
    for (int p = 0; p < 4; ++p){
      float4 vr = *(const float4*)(pr + 4*p);
      float4 vi = *(const float4*)(pi + 4*p);
      int base = t*17 + 4*p;
      reL[base+0]=vr.x; reL[base+1]=vr.y; reL[base+2]=vr.z; reL[base+3]=vr.w;
      imL[base+0]=vi.x; imL[base+1]=vi.y; imL[base+2]=vi.z; imL[base+3]=vi.w;
    }
  }
  __syncthreads();
  int col = t & 15, tb = t >> 4;
  for (int s = 0; s < 8; ++s){
    int half = 128 >> s;
    #pragma unroll
    for (int it = 0; it < 8; ++it){
      int tj = tb + it*16;
      int j = tj & (half-1);
      int g = tj >> (7-s);
      int k = (g << (8-s)) + j;
      int m = j << s;
      float wc = twr[m];
      float ws = (DIR == 0) ? twi[m] : -twi[m];
      int i0 = k*17 + col, i1 = (k+half)*17 + col;
      float are = reL[i0], aim = imL[i0];
      float bre = reL[i1], bim = imL[i1];
      reL[i0] = are + bre; imL[i0] = aim + bim;
      float tr = are - bre, ti = aim - bim;
      reL[i1] = tr*wc - ti*ws;
      imL[i1] = tr*ws + ti*wc;
    }
    __syncthreads();
  }
  int b = img >> 6, c = img & 63;
  int h = t; int src = (int)brev8((uint)h);
  if (DIR == 0){
    int gy = h >> 2, py = h & 3;
    #pragma unroll
    for (int p = 0; p < 4; ++p){
      float4 av, pv;
      int base = src*17 + 4*p;
      float rr, ii;
      rr = reL[base+0]; ii = imL[base+0]; av.x = sqrtf(rr*rr+ii*ii); pv.x = atan2f(ii, rr);
      rr = reL[base+1]; ii = imL[base+1]; av.y = sqrtf(rr*rr+ii*ii); pv.y = atan2f(ii, rr);
      rr = reL[base+2]; ii = imL[base+2]; av.z = sqrtf(rr*rr+ii*ii); pv.z = atan2f(ii, rr);
      rr = reL[base+3]; ii = imL[base+3]; av.w = sqrtf(rr*rr+ii*ii); pv.w = atan2f(ii, rr);
      size_t addr = ((size_t)(b*4096 + gy*64 + (c0>>2) + p))*1024 + c*16 + py*4;
      *(float4*)(out0 + addr) = av;
      *(float4*)(out1 + addr) = pv;
    }
  } else {
    float* op = out0 + ((size_t)img*256 + h)*256 + c0;
    #pragma unroll
    for (int p = 0; p < 4; ++p){
      int base = src*17 + 4*p;
      float4 v;
      v.x = reL[base+0]*(1.f/65536.f);
      v.y = reL[base+1]*(1.f/65536.f);
      v.z = reL[base+2]*(1.f/65536.f);
      v.w = reL[base+3]*(1.f/65536.f);
      *(float4*)(op + 4*p) = v;
    }
  }
}

// ---------------- MFMA bf16 tiled GEMM, z-fused over branches/matrices ----------
struct GP {
  const float* A0[6];
  const float* A1[2];
  const float* Bm[6];
  float*       Cm[6];
  const int*   idxp[6];
  const float* ep0[2];
  const float* ep1[2];
  const float* ep2[2];
  const float* vt[2];
  const float* it[2];
  int M, N, K;
};

template<int BM, int AMODE, int EPI>
__global__ __launch_bounds__(256) void kern_mgemm(GP p){
  constexpr int LBM = (BM == 128) ? 7 : 6;
  constexpr int FR  = BM / 32;          // frags per wave in M
  constexpr int HB  = BM / 2;           // wave rows
  __shared__ __align__(16) unsigned short Asb[BM*40];
  __shared__ __align__(16) unsigned short Bsb[128*40];
  __shared__ int idx_s[BM];
  int z = blockIdx.z;
  const float* A0 = p.A0[z];
  const float* Bm = p.Bm[z];
  float* Cm = p.Cm[z];
  int tid = threadIdx.x;
  int m0 = blockIdx.y * BM;
  int n0 = blockIdx.x * 128;
  int lane = tid & 63;
  int w = tid >> 6;
  int wr = w & 1, wc = w >> 1;
  int lr = lane & 15, ql = lane >> 4;

  if (AMODE == 2 || EPI == 3){
    if (tid < BM){
      int m = m0 + tid;
      idx_s[tid] = p.idxp[z][(m >> 10)*1024 + (m & 1023)];
    }
    __syncthreads();
  }
  int gb = m0 >> 10;

  f32x4 acc[FR][4];
  #pragma unroll
  for (int i = 0; i < FR; ++i)
    #pragma unroll
    for (int j = 0; j < 4; ++j) acc[i][j] = (f32x4){0.f,0.f,0.f,0.f};

  for (int k0 = 0; k0 < p.K; k0 += 32){
    // ---- stage A (BM x 32 fp32 -> bf16 LDS, row stride 40) ----
    #pragma unroll
    for (int e0 = 0; e0 < BM*4; e0 += 256){
      int e = e0 + tid;
      int m = e & (BM-1);
      int kh = (e >> LBM) * 8;
      int k2 = k0 + kh;
      const float* ap;
      if (AMODE == 0){
        ap = A0 + (size_t)(m0+m)*p.K + k2;
      } else if (AMODE == 1){
        const float* src = (k2 < 1024) ? A0 : p.A1[z];
        int kk = (k2 < 1024) ? k2 : (k2 - 1024);
        ap = src + (size_t)(m0+m)*1024 + kk;
      } else {
        ap = A0 + ((size_t)(gb << 12) + idx_s[m])*(size_t)p.K + k2;
      }
      float4 f0 = *(const float4*)ap;
      float4 f1 = *(const float4*)(ap + 4);
      short8 v;
      v[0]=(short)f2bf(f0.x); v[1]=(short)f2bf(f0.y);
      v[2]=(short)f2bf(f0.z); v[3]=(short)f2bf(f0.w);
      v[4]=(short)f2bf(f1.x); v[5]=(short)f2bf(f1.y);
      v[6]=(short)f2bf(f1.z); v[7]=(short)f2bf(f1.w);
      *(short8*)&Asb[m*40 + kh] = v;
    }
    // ---- stage B (32 x 128 fp32 -> bf16 LDS transposed [n][k], stride 40) ----
    #pragma unroll
    for (int e0 = 0; e0 < 512; e0 += 256){
      int e = e0 + tid;
      int n = e & 127;
      int kh = (e >> 7) * 8;
      const float* bp = Bm + (size_t)(k0+kh)*p.N + n0 + n;
      short8 v;
      #pragma unroll
      for (int j = 0; j < 8; ++j) v[j] = (short)f2bf(bp[(size_t)j*p.N]);
      *(short8*)&Bsb[n*40 + kh] = v;
    }
    __syncthreads();
    short8 af[FR], bf[4];
    #pragma unroll
    for (int fr = 0; fr < FR; ++fr)
      af[fr] = *(const short8*)&Asb[(wr*HB + fr*16 + lr)*40 + ql*8];
    #pragma unroll
    for (int fc = 0; fc < 4; ++fc)
      bf[fc] = *(const short8*)&Bsb[(wc*64 + fc*16 + lr)*40 + ql*8];
    #pragma unroll
    for (int fr = 0; fr < FR; ++fr)
      #pragma unroll
      for (int fc = 0; fc < 4; ++fc)
        acc[fr][fc] = __builtin_amdgcn_mfma_f32_16x16x32_bf16(af[fr], bf[fc],
                                                              acc[fr][fc], 0, 0, 0);
    __syncthreads();
  }

  #pragma unroll
  for (int fr = 0; fr < FR; ++fr){
    #pragma unroll
    for (int fc = 0; fc < 4; ++fc){
      int n = n0 + wc*64 + fc*16 + lr;
      #pragma unroll
      for (int reg = 0; reg < 4; ++reg){
        int mloc = wr*HB + fr*16 + ql*4 + reg;
        int m = m0 + mloc;
        float v = acc[fr][fc][reg];
        if (EPI == 0){
          Cm[(size_t)m*p.N + n] = v;
        } else if (EPI == 1){
          int bl = m >> 12, g = m & 4095;
          int gy = g >> 6, gx = g & 63;
          float cy = ((float)gy + 0.5f)*(1.f/64.f);
          float cx = ((float)gx + 0.5f)*(1.f/64.f);
          float o = v + p.ep0[z][bl*128 + n] + cy*p.ep1[z][n]
                  + cx*p.ep1[z][128 + n] + p.ep2[z][n];
          Cm[(size_t)m*128 + n] = o;
        } else if (EPI == 2){
          float vt = p.vt[z][(size_t)m*1024 + n];
          float it = p.it[z][(size_t)m*1024 + n];
          float gg = 1.f/(1.f + expf(-(v + p.ep0[z][n])));
          Cm[(size_t)m*1024 + n] = gg*vt + (1.f-gg)*it;
        } else {
          int gt = idx_s[mloc];
          size_t off = ((size_t)(gb << 12) + gt)*1024 + n;
          Cm[off] = v + p.vt[z][off];
        }
      }
    }
  }
}

// ---------------- score = gelu(h) @ Wout + bout (branch via blockIdx.y) -----------
__global__ __launch_bounds__(64) void kern_score(const float* __restrict__ h,
    const float* __restrict__ wout, const float* __restrict__ bout,
    float* __restrict__ score, int Mper){
  int m = blockIdx.x, br = blockIdx.y, t = threadIdx.x;
  const float* hp = h + ((size_t)br*Mper + m)*128;
  const float* wp = wout + br*128;
  float s = geluf(hp[t])*wp[t] + geluf(hp[t+64])*wp[t+64];
  #pragma unroll
  for (int off = 32; off > 0; off >>= 1) s += __shfl_down(s, off);
  if (t == 0) score[(size_t)br*Mper + m] = s + bout[br];
}

// ---------------- per-(branch,batch) top-1024 of 4096 (bitonic, jax tie-break) ----
__global__ __launch_bounds__(1024) void kern_topk(const float* __restrict__ score,
    int* __restrict__ idx_out){
  __shared__ u64 keys[4096];
  int b = blockIdx.x, t = threadIdx.x;
  for (int i = t; i < 4096; i += 1024){
    float s = score[b*4096 + i];
    uint u = __float_as_uint(s);
    uint msk = (u & 0x80000000u) ? ~u : (u | 0x80000000u);
    keys[i] = ((u64)msk << 32) | (uint)(4095 - i);
  }
  __syncthreads();
  for (int k = 2; k <= 4096; k <<= 1){
    for (int j = k >> 1; j > 0; j >>= 1){
      for (int i = t; i < 4096; i += 1024){
        int l = i ^ j;
        if (l > i){
          u64 a = keys[i], c = keys[l];
          bool descB = ((i & k) == 0);
          bool sw = descB ? (a < c) : (a > c);
          if (sw){ keys[i] = c; keys[l] = a; }
        }
      }
      __syncthreads();
    }
  }
  idx_out[b*1024 + t] = 4095 - (int)(keys[t] & 0xFFFFFFFFu);
}

// ---------------- attention (flash-style, dh=32, 4 heads, z = br*PB+bb) ----------
__global__ __launch_bounds__(256) void kern_attn(const float* __restrict__ qb,
    const float* __restrict__ kb, const float* __restrict__ vb,
    float* __restrict__ ob, const float* __restrict__ ipint,
    int PB, int b0){
  __shared__ float Ks[64][32];
  __shared__ float Vs[64][32];
  int t = threadIdx.x;
  int hh = blockIdx.y, zf = blockIdx.z;
  size_t boff = (size_t)zf*131072;
  int jq = blockIdx.x*256 + t;
  float qv[32];
  {
    const float4* qp = (const float4*)(qb + boff + (size_t)jq*128 + hh*32);
    #pragma unroll
    for (int d = 0; d < 8; ++d) ((float4*)qv)[d] = qp[d];
  }
  float mrun = -3.0e38f, lrun = 0.f;
  float oa[32];
  #pragma unroll
  for (int d = 0; d < 32; ++d) oa[d] = 0.f;
  for (int kt = 0; kt < 16; ++kt){
    #pragma unroll
    for (int rep = 0; rep < 2; ++rep){
      int f = t + rep*256;
      int r = f >> 3, q4 = f & 7;
      size_t base = boff + (size_t)(kt*64 + r)*128 + hh*32 + 4*q4;
      *(float4*)&Ks[r][4*q4] = *(const float4*)(kb + base);
      *(float4*)&Vs[r][4*q4] = *(const float4*)(vb + base);
    }
    __syncthreads();
    float mt = -3.0e38f;
    for (int kk = 0; kk < 64; ++kk){
      float s = 0.f;
      #pragma unroll
      for (int d = 0; d < 32; ++d) s += qv[d]*Ks[kk][d];
      s *= 0.17677669529663687f;
      mt = fmaxf(mt, s);
    }
    float mnew = fmaxf(mrun, mt);
    float alpha = expf(mrun - mnew);
    lrun *= alpha;
    #pragma unroll
    for (int d = 0; d < 32; ++d) oa[d] *= alpha;
    for (int kk = 0; kk < 64; ++kk){
      float s = 0.f;
      #pragma unroll
      for (int d = 0; d < 32; ++d) s += qv[d]*Ks[kk][d];
      s *= 0.17677669529663687f;
      float pe = expf(s - mnew);
      lrun += pe;
      #pragma unroll
      for (int d = 0; d < 32; ++d) oa[d] += pe*Vs[kk][d];
    }
    mrun = mnew;
    __syncthreads();
  }
  float inv = 1.f/lrun;
  int br = (zf >= PB) ? 1 : 0;
  int bb = zf - br*PB;
  float* op = ob + boff + (size_t)jq*128 + hh*32;
  const float* ip = ipint + br*512 + (b0+bb)*128 + hh*32;
  #pragma unroll
  for (int d = 0; d < 32; ++d) op[d] = oa[d]*inv + ip[d];
}

// ---------------- weight transform: w[co][ci][3][3] fp32 -> wt[set][tap][co][ci] bf16 ----
__global__ __launch_bounds__(256) void kern_wt(const float* __restrict__ w1,
    const float* __restrict__ w2, unsigned short* __restrict__ wt){
  int blk = blockIdx.x;                 // 0..17: set = blk/9, tap = blk%9
  const float* src = (blk < 9) ? w1 : w2;
  int tap = blk - (blk < 9 ? 0 : 9);
  unsigned short* dst = wt + (blk < 9 ? 0 : 36864) + tap*4096;
  for (int e = threadIdx.x; e < 4096; e += 256){
    dst[e] = f2bf(src[(size_t)e*9 + tap]);
  }
}

// ---------------- implicit-GEMM 3x3 conv via MFMA ----------------
// Block: (b, y); 4 waves = 2 co-groups x 2 x-groups; wave = 32co x 128x.
// LDS: input row slab [64ci][268] bf16 (idx = x+4; halos x=-1,256 at 3,260).
template<int MODE>
__global__ __launch_bounds__(256) void kern_cmfma(const float* __restrict__ in,
    const unsigned short* __restrict__ wt, const float* __restrict__ bias,
    float* __restrict__ out,
    const float* __restrict__ modg, const float* __restrict__ modb,
    const float* __restrict__ vis, const float* __restrict__ irf){
  __shared__ __align__(16) unsigned short ins[64][268];
  int t = threadIdx.x;
  int y = blockIdx.x, b = blockIdx.y;
  int lane = t & 63, w = t >> 6;
  int wc = w & 1, wx = w >> 1;
  int lr = lane & 15, ql = lane >> 4;

  f32x4 acc[2][8];
  #pragma unroll
  for (int f = 0; f < 2; ++f)
    #pragma unroll
    for (int xf = 0; xf < 8; ++xf) acc[f][xf] = (f32x4){0.f,0.f,0.f,0.f};

  for (int dy = 0; dy < 3; ++dy){
    int yy = y + dy - 1;
    if (yy < 0 || yy > 255) continue;
    // ---- stage 64ci x 256x (bf16), coalesced float4 reads, b64 writes ----
    const float* src = in + ((size_t)(b*64)*256 + yy)*256;
    #pragma unroll
    for (int s = 0; s < 16; ++s){
      int e = t + s*256;
      int ci = e >> 6, q = e & 63;
      float4 f4 = *(const float4*)(src + (size_t)ci*65536 + 4*q);
      uint lo = (uint)f2bf(f4.x) | ((uint)f2bf(f4.y) << 16);
      uint hi = (uint)f2bf(f4.z) | ((uint)f2bf(f4.w) << 16);
      *(uint2*)&ins[ci][4*q + 4] = make_uint2(lo, hi);
    }
    if (t < 128){
      int r = t & 63;
      ins[r][(t >> 6) ? 260 : 3] = 0;
    }
    __syncthreads();
    // ---- weights for this dy: 12 frags in registers (L2-hot global loads) ----
    short8 wf[2][3][2];   // [kk][dx][f]
    #pragma unroll
    for (int kk = 0; kk < 2; ++kk)
      #pragma unroll
      for (int dx = 0; dx < 3; ++dx)
        #pragma unroll
        for (int f = 0; f < 2; ++f)
          wf[kk][dx][f] = *(const short8*)(wt +
            (size_t)((dy*3 + dx)*64 + 32*wc + 16*f + lr)*64 + kk*32 + ql*8);
    // ---- MFMA: B-frags gathered from LDS (8 x u16, const offsets) ----
    #pragma unroll
    for (int kk = 0; kk < 2; ++kk){
      const unsigned short* bp = &ins[kk*32 + ql*8][0];
      #pragma unroll
      for (int dx = 0; dx < 3; ++dx){
        int xb = 128*wx + lr + dx + 3;
        #pragma unroll
        for (int xf = 0; xf < 8; ++xf){
          int xi = xb + 16*xf;
          short8 bf;
          #pragma unroll
          for (int e = 0; e < 8; ++e) bf[e] = (short)bp[e*268 + xi];
          acc[0][xf] = __builtin_amdgcn_mfma_f32_16x16x32_bf16(wf[kk][dx][0], bf,
                                                               acc[0][xf], 0, 0, 0);
          acc[1][xf] = __builtin_amdgcn_mfma_f32_16x16x32_bf16(wf[kk][dx][1], bf,
                                                               acc[1][xf], 0, 0, 0);
        }
      }
    }
    __syncthreads();
  }

  // ---- epilogue: D col(lane&15)=x, row=(lane>>4)*4+reg=co ----
  #pragma unroll
  for (int f = 0; f < 2; ++f){
    #pragma unroll
    for (int xf = 0; xf < 8; ++xf){
      int x = 128*wx + 16*xf + lr;
      #pragma unroll
      for (int reg = 0; reg < 4; ++reg){
        int co = 32*wc + 16*f + ql*4 + reg;
        float v = acc[f][xf][reg] + bias[co];
        size_t oi = ((size_t)(b*64 + co)*256 + y)*256 + x;
        if (MODE == 1){
          out[oi] = fmaxf(v, 0.f);
        } else {
          out[oi] = v*modg[b*64+co] + modb[b*64+co] + 0.5f*(vis[oi] + irf[oi]);
        }
      }
    }
  }
}

// ---------------- launch ----------------
extern "C" void kernel_launch(void* const* d_in, const int* in_sizes, int n_in,
                              void* d_out, int out_size, void* d_ws, size_t ws_size,
                              hipStream_t stream){
  (void)in_sizes; (void)n_in; (void)out_size;
  const float* vis  = (const float*)d_in[0];
  const float* irf  = (const float*)d_in[1];
  const float* bank = (const float*)d_in[2];
  const float* Wr   = (const float*)d_in[3];
  const float* br   = (const float*)d_in[4];
  const float* Wtok = (const float*)d_in[5];
  const float* Wpri = (const float*)d_in[6];
  const float* Wco  = (const float*)d_in[7];
  const float* bs   = (const float*)d_in[8];
  const float* Wout = (const float*)d_in[9];
  const float* bout = (const float*)d_in[10];
  const float* Wq   = (const float*)d_in[11];
  const float* Wk   = (const float*)d_in[12];
  const float* Wv   = (const float*)d_in[13];
  const float* Wo   = (const float*)d_in[14];
  const float* Wint = (const float*)d_in[15];
  const float* Wbyp = (const float*)d_in[16];
  const float* bbyp = (const float*)d_in[17];
  const float* c1w  = (const float*)d_in[18];
  const float* c1b  = (const float*)d_in[19];
  const float* c2w  = (const float*)d_in[20];
  const float* c2b  = (const float*)d_in[21];
  const float* Wa1  = (const float*)d_in[22];
  const float* ba1  = (const float*)d_in[23];
  const float* Wa2  = (const float*)d_in[24];
  const float* ba2  = (const float*)d_in[25];

  auto needB = [](int PB)->size_t{
    return ((size_t)5*PB*4194304 + (size_t)2*PB*524288 + (size_t)2*PB*4096
          + (size_t)2*PB*1024 + (size_t)8*PB*131072 + 4096 + 36864) * 4;
  };
  const int PB = (ws_size >= needB(4)) ? 4 : (ws_size >= needB(2)) ? 2 : 1;

  float* ws = (float*)d_ws;
  const size_t SL = (size_t)PB*4194304;    // per-group slab (floats)
  float* P0 = ws;
  float* P1 = P0 + SL;
  float* P2 = P1 + SL;
  float* P3 = P2 + SL;
  float* P4 = P3 + SL;
  float* sm = P4 + SL;
  float* hbuf  = sm; sm += (size_t)2*PB*524288;    // [2][PB*4096][128]
  float* score = sm; sm += (size_t)2*PB*4096;      // [2*PB][4096]
  int*   idxb  = (int*)sm; sm += (size_t)2*PB*1024;// [2*PB][1024]
  float* qbuf  = sm; sm += (size_t)2*PB*131072;    // [2*PB][1024][128]
  float* kbuf  = sm; sm += (size_t)2*PB*131072;
  float* vbuf  = sm; sm += (size_t)2*PB*131072;
  float* obuf  = sm; sm += (size_t)2*PB*131072;
  float* pooled= sm; sm += 512;
  float* IP    = sm; sm += 1024;
  float* IPint = sm; sm += 1024;
  float* modg  = sm; sm += 256;
  float* modb  = sm; sm += 256;
  unsigned short* wtb = (unsigned short*)sm; sm += 36864;  // [2][9][64][64] bf16

  kern_pool <<<512, 256, 0, stream>>>(vis, irf, pooled);
  kern_small<<<1, 256, 0, stream>>>(pooled, Wr, br, bank, Wpri, Wint,
                                    Wa1, ba1, Wa2, ba2, IP, IPint, modg, modb);
  kern_wt   <<<18, 256, 0, stream>>>(c1w, c2w, wtb);

  for (int b0 = 0; b0 < 4; b0 += PB){
    const float* vis_b = vis + (size_t)b0*4194304;
    const float* ir_b  = irf + (size_t)b0*4194304;
    float* OUT = (float*)d_out + (size_t)b0*4194304;  // transient re / FULL_amp / spatial

    // forward FFT2 + amp/phase (patchified layout)
    kern_fft_rows_fwd<<<PB*8192, 256, 0, stream>>>(vis_b, OUT, P4);
    kern_fft_cols<0> <<<PB*1024, 256, 0, stream>>>(OUT, P4, P0, P1);  // AMP_V, PH_V
    kern_fft_rows_fwd<<<PB*8192, 256, 0, stream>>>(ir_b, OUT, P4);
    kern_fft_cols<0> <<<PB*1024, 256, 0, stream>>>(OUT, P4, P2, P3);  // AMP_I, PH_I

    {  // h = cat(vt,it)@Wtok + IP[b] + coords@Wco + bs   (both branches, z=2)
      GP p{};
      p.A0[0]=P0; p.A1[0]=P2; p.A0[1]=P1; p.A1[1]=P3;
      for (int z = 0; z < 2; ++z){
        p.Bm[z] = Wtok + (size_t)z*262144;
        p.Cm[z] = hbuf + (size_t)z*PB*524288;
        p.ep0[z] = IP + z*512 + b0*128;
        p.ep1[z] = Wco + z*256;
        p.ep2[z] = bs + z*128;
      }
      p.M = PB*4096; p.N = 128; p.K = 2048;
      kern_mgemm<64,1,1><<<dim3(1, PB*64, 2), 256, 0, stream>>>(p);
    }
    kern_score<<<dim3(PB*4096, 2), 64, 0, stream>>>(hbuf, Wout, bout, score, PB*4096);
    kern_topk <<<2*PB, 1024, 0, stream>>>(score, idxb);
    {  // bypass blend into FULL (amp -> OUT, ph -> P4), both branches
      GP p{};
      p.A0[0]=P0; p.A1[0]=P2; p.A0[1]=P1; p.A1[1]=P3;
      p.vt[0]=P0; p.it[0]=P2; p.vt[1]=P1; p.it[1]=P3;
      p.Cm[0]=OUT; p.Cm[1]=P4;
      for (int z = 0; z < 2; ++z){
        p.Bm[z] = Wbyp + (size_t)z*2097152;
        p.ep0[z] = bbyp + z*1024;
      }
      p.M = PB*4096; p.N = 1024; p.K = 2048;
      kern_mgemm<128,1,2><<<dim3(8, PB*32, 2), 256, 0, stream>>>(p);
    }
    {  // q,k,v gathered rows: z = br*3 + {q,k,v}
      GP p{};
      const float* Aplanes[6] = {P0, P2, P2, P1, P3, P3};
      const float* Bmats[6] = {Wq, Wk, Wv, Wq+131072, Wk+131072, Wv+131072};
      float* Cms[6] = {qbuf, kbuf, vbuf,
                       qbuf+(size_t)PB*131072, kbuf+(size_t)PB*131072, vbuf+(size_t)PB*131072};
      for (int z = 0; z < 6; ++z){
        p.A0[z] = Aplanes[z]; p.Bm[z] = Bmats[z]; p.Cm[z] = Cms[z];
        p.idxp[z] = idxb + (z < 3 ? 0 : PB*1024);
      }
      p.M = PB*1024; p.N = 128; p.K = 1024;
      kern_mgemm<64,2,0><<<dim3(1, PB*16, 6), 256, 0, stream>>>(p);
    }
    kern_attn<<<dim3(4, 4, 2*PB), 256, 0, stream>>>(qbuf, kbuf, vbuf, obuf,
                                                    IPint, PB, b0);
    {  // fused_sel = vs + o@Wo scattered into FULL, both branches
      GP p{};
      p.A0[0]=obuf; p.A0[1]=obuf+(size_t)PB*131072;
      p.Bm[0]=Wo; p.Bm[1]=Wo+131072;
      p.Cm[0]=OUT; p.Cm[1]=P4;
      p.vt[0]=P0; p.vt[1]=P1;
      p.idxp[0]=idxb; p.idxp[1]=idxb+PB*1024;
      p.M = PB*1024; p.N = 1024; p.K = 128;
      kern_mgemm<64,0,3><<<dim3(8, PB*16, 2), 256, 0, stream>>>(p);
    }

    // spec = famp * e^{i fph}; inverse FFT2 -> spatial into OUT (d_out slab)
    kern_ifft_rows_spec<<<PB*4096, 256, 0, stream>>>(OUT, P4, P0, P1);
    kern_fft_cols<1>   <<<PB*1024, 256, 0, stream>>>(P0, P1, OUT, nullptr);
  }

  // convs (MFMA implicit GEMM): d_out(spatial) -> ws (conv1+relu) -> d_out (conv2+mod+res)
  kern_cmfma<1><<<dim3(256, 4), 256, 0, stream>>>((float*)d_out, wtb, c1b, ws,
                                                  nullptr, nullptr, nullptr, nullptr);
  kern_cmfma<2><<<dim3(256, 4), 256, 0, stream>>>(ws, wtb + 36864, c2b, (float*)d_out,
                                                  modg, modb, vis, irf);
}

// Round 6
// 2258.238 us; speedup vs baseline: 5.9963x; 1.1852x over previous
//
#include <hip/hip_runtime.h>

typedef unsigned int uint;
typedef unsigned long long u64;
typedef __attribute__((ext_vector_type(8))) short short8;
typedef __attribute__((ext_vector_type(4))) float f32x4;

__device__ __forceinline__ uint brev8(uint x){ return __brev(x) >> 24; }
__device__ __forceinline__ float geluf(float x){
  return 0.5f*x*(1.f + tanhf(0.7978845608028654f*(x + 0.044715f*x*x*x)));
}
__device__ __forceinline__ unsigned short f2bf(float f){
  unsigned u = __float_as_uint(f);
  unsigned r = u + 0x7FFFu + ((u >> 16) & 1u);
  return (unsigned short)(r >> 16);
}

// ---------------- pooled mean (global, all 4 batches) ----------------
__global__ __launch_bounds__(256) void kern_pool(const float* __restrict__ vis,
                                                 const float* __restrict__ irf,
                                                 float* __restrict__ pooled){
  __shared__ float red[256];
  int bc = blockIdx.x;            // b*128 + cc
  int b = bc >> 7, cc = bc & 127;
  const float* src = (cc < 64) ? (vis + (size_t)(b*64+cc)*65536)
                               : (irf + (size_t)(b*64+(cc-64))*65536);
  float s = 0.f;
  for (int i = threadIdx.x; i < 65536; i += 256) s += src[i];
  red[threadIdx.x] = s;
  __syncthreads();
  for (int off = 128; off > 0; off >>= 1){
    if (threadIdx.x < off) red[threadIdx.x] += red[threadIdx.x + off];
    __syncthreads();
  }
  if (threadIdx.x == 0) pooled[bc] = red[0] * (1.f/65536.f);
}

// ---------------- prompt/intent/affine small ops (global) ----------------
__global__ __launch_bounds__(256) void kern_small(const float* __restrict__ pooled,
    const float* __restrict__ Wr, const float* __restrict__ br,
    const float* __restrict__ bank, const float* __restrict__ Wpri,
    const float* __restrict__ Wint, const float* __restrict__ Wa1,
    const float* __restrict__ ba1, const float* __restrict__ Wa2,
    const float* __restrict__ ba2,
    float* __restrict__ IP, float* __restrict__ IPint,
    float* __restrict__ modg, float* __restrict__ modb){
  __shared__ float logit_s[16];
  __shared__ float pw_s[16];
  __shared__ float intent_s[4][64];
  __shared__ float t1_s[4][128];
  int t = threadIdx.x;
  if (t < 16){
    int b = t >> 2, j = t & 3;
    float s = br[j];
    for (int k = 0; k < 128; ++k) s += pooled[b*128+k]*Wr[k*4+j];
    logit_s[t] = s;
  }
  __syncthreads();
  if (t < 4){
    int b = t;
    float m = logit_s[b*4];
    for (int j = 1; j < 4; ++j) m = fmaxf(m, logit_s[b*4+j]);
    float e[4], sum = 0.f;
    for (int j = 0; j < 4; ++j){ e[j] = expf(logit_s[b*4+j]-m); sum += e[j]; }
    for (int j = 0; j < 4; ++j) pw_s[b*4+j] = e[j]/sum;
  }
  __syncthreads();
  {
    int b = t >> 6, p = t & 63;
    float s = 0.f;
    for (int j = 0; j < 4; ++j) s += pw_s[b*4+j]*bank[j*64+p];
    intent_s[b][p] = s;
  }
  __syncthreads();
  for (int o = t; o < 1024; o += 256){
    int i = o >> 9, rem = o & 511, b = rem >> 7, n = rem & 127;
    float s1 = 0.f, s2 = 0.f;
    for (int p = 0; p < 64; ++p){
      float iv = intent_s[b][p];
      s1 += iv * Wpri[(i*64+p)*128 + n];
      s2 += iv * Wint[(i*64+p)*128 + n];
    }
    IP[o] = s1; IPint[o] = s2;
  }
  for (int o = t; o < 512; o += 256){
    int b = o >> 7, n = o & 127;
    float s = ba1[n];
    for (int p = 0; p < 64; ++p) s += intent_s[b][p]*Wa1[p*128+n];
    t1_s[b][n] = geluf(s);
  }
  __syncthreads();
  for (int o = t; o < 512; o += 256){
    int b = o >> 7, n = o & 127;
    float s = ba2[n];
    for (int p = 0; p < 128; ++p) s += t1_s[b][p]*Wa2[p*128+n];
    if (n < 64) modg[b*64+n] = 1.f + 0.1f*tanhf(s);
    else        modb[b*64+(n-64)] = 0.1f*s;
  }
}

// ---------------- forward row FFT (real input), slab-relative ----------------
__global__ __launch_bounds__(256) void kern_fft_rows_fwd(const float* __restrict__ x,
    float* __restrict__ sre, float* __restrict__ sim){
  __shared__ float re[2][256], im[2][256];
  __shared__ float twr[128], twi[128];
  int t = threadIdx.x;
  if (t < 128){
    float a = -6.2831853071795864f * (float)t * (1.f/256.f);
    sincosf(a, &twi[t], &twr[t]);
  }
  int r = t >> 7, jj = t & 127;
  size_t row = (size_t)blockIdx.x*2 + r;   // flat row over (b,c,h) within slab
  {
    const float* xp = x + row*256;
    re[r][jj] = xp[jj]; re[r][jj+128] = xp[jj+128];
    im[r][jj] = 0.f;    im[r][jj+128] = 0.f;
  }
  __syncthreads();
  for (int s = 0; s < 8; ++s){
    int half = 128 >> s;
    int j = jj & (half-1);
    int g = jj >> (7-s);
    int k = (g << (8-s)) + j;
    int m = j << s;
    float wc = twr[m], ws = twi[m];
    float are = re[r][k],      aim = im[r][k];
    float bre = re[r][k+half], bim = im[r][k+half];
    re[r][k] = are + bre; im[r][k] = aim + bim;
    float tr = are - bre, ti = aim - bim;
    re[r][k+half] = tr*wc - ti*ws;
    im[r][k+half] = tr*ws + ti*wc;
    __syncthreads();
  }
  {
    float* orp = sre + row*256; float* oip = sim + row*256;
    int w1 = jj, w2 = jj + 128;
    orp[w1] = re[r][brev8(w1)]; oip[w1] = im[r][brev8(w1)];
    orp[w2] = re[r][brev8(w2)]; oip[w2] = im[r][brev8(w2)];
  }
}

// ---------------- inverse row FFT with spec construction (reads patchified amp/ph) ----
__global__ __launch_bounds__(256) void kern_ifft_rows_spec(const float* __restrict__ famp,
    const float* __restrict__ fph, float* __restrict__ sre, float* __restrict__ sim){
  __shared__ float re[4][256], im[4][256];
  __shared__ float twr[128], twi[128];
  int t = threadIdx.x;
  if (t < 128){
    float a = -6.2831853071795864f * (float)t * (1.f/256.f);
    sincosf(a, &twi[t], &twr[t]);
  }
  int R = blockIdx.x * 4;
  {
    int r = t >> 6, q = t & 63;
    int row = R + r;
    int bc = row >> 8, h = row & 255;
    int b = bc >> 6, c = bc & 63;
    size_t addr = ((size_t)(b*4096 + (h>>2)*64 + q))*1024 + c*16 + (h&3)*4;
    float4 a4 = *(const float4*)(famp + addr);
    float4 p4 = *(const float4*)(fph + addr);
    float sn, cs;
    sincosf(p4.x, &sn, &cs); re[r][4*q+0] = a4.x*cs; im[r][4*q+0] = a4.x*sn;
    sincosf(p4.y, &sn, &cs); re[r][4*q+1] = a4.y*cs; im[r][4*q+1] = a4.y*sn;
    sincosf(p4.z, &sn, &cs); re[r][4*q+2] = a4.z*cs; im[r][4*q+2] = a4.z*sn;
    sincosf(p4.w, &sn, &cs); re[r][4*q+3] = a4.w*cs; im[r][4*q+3] = a4.w*sn;
  }
  __syncthreads();
  for (int s = 0; s < 8; ++s){
    int half = 128 >> s;
    #pragma unroll
    for (int bi0 = 0; bi0 < 2; ++bi0){
      int bi = t + bi0*256;
      int r = bi >> 7, tj = bi & 127;
      int j = tj & (half-1);
      int g = tj >> (7-s);
      int k = (g << (8-s)) + j;
      int m = j << s;
      float wc = twr[m], ws = -twi[m];
      float are = re[r][k],      aim = im[r][k];
      float bre = re[r][k+half], bim = im[r][k+half];
      re[r][k] = are + bre; im[r][k] = aim + bim;
      float tr = are - bre, ti = aim - bim;
      re[r][k+half] = tr*wc - ti*ws;
      im[r][k+half] = tr*ws + ti*wc;
    }
    __syncthreads();
  }
  {
    int r = t >> 6, q = t & 63;
    size_t row = (size_t)R + r;
    float4 vr, vi;
    vr.x = re[r][brev8(4*q+0)]; vi.x = im[r][brev8(4*q+0)];
    vr.y = re[r][brev8(4*q+1)]; vi.y = im[r][brev8(4*q+1)];
    vr.z = re[r][brev8(4*q+2)]; vi.z = im[r][brev8(4*q+2)];
    vr.w = re[r][brev8(4*q+3)]; vi.w = im[r][brev8(4*q+3)];
    *(float4*)(sre + row*256 + 4*q) = vr;
    *(float4*)(sim + row*256 + 4*q) = vi;
  }
}

// ---------------- column FFT: DIR=0 fwd (amp/ph patchified out), DIR=1 inv (real out) ----
template<int DIR>
__global__ __launch_bounds__(256) void kern_fft_cols(const float* __restrict__ sre,
    const float* __restrict__ sim, float* __restrict__ out0, float* __restrict__ out1){
  __shared__ float reL[256*17];
  __shared__ float imL[256*17];
  __shared__ float twr[128], twi[128];
  int t = threadIdx.x;
  if (t < 128){
    float a = -6.2831853071795864f * (float)t * (1.f/256.f);
    sincosf(a, &twi[t], &twr[t]);
  }
  int img = blockIdx.x >> 4;                 // b*64+c within slab
  int c0 = (blockIdx.x & 15) * 16;
  {
    const float* pr = sre + ((size_t)img*256 + t)*256 + c0;
    const float* pi = sim + ((size_t)img*256 + t)*256 + c0;
    #pragma unroll
    for (int p = 0; p < 4; ++p){
      float4 vr = *(const float4*)(pr + 4*p);
      float4 vi = *(const float4*)(pi + 4*p);
      int base = t*17 + 4*p;
      reL[base+0]=vr.x; reL[base+1]=vr.y; reL[base+2]=vr.z; reL[base+3]=vr.w;
      imL[base+0]=vi.x; imL[base+1]=vi.y; imL[base+2]=vi.z; imL[base+3]=vi.w;
    }
  }
  __syncthreads();
  int col = t & 15, tb = t >> 4;
  for (int s = 0; s < 8; ++s){
    int half = 128 >> s;
    #pragma unroll
    for (int it = 0; it < 8; ++it){
      int tj = tb + it*16;
      int j = tj & (half-1);
      int g = tj >> (7-s);
      int k = (g << (8-s)) + j;
      int m = j << s;
      float wc = twr[m];
      float ws = (DIR == 0) ? twi[m] : -twi[m];
      int i0 = k*17 + col, i1 = (k+half)*17 + col;
      float are = reL[i0], aim = imL[i0];
      float bre = reL[i1], bim = imL[i1];
      reL[i0] = are + bre; imL[i0] = aim + bim;
      float tr = are - bre, ti = aim - bim;
      reL[i1] = tr*wc - ti*ws;
      reL[i1] = tr*wc - ti*ws;
      imL[i1] = tr*ws + ti*wc;
    }
    __syncthreads();
  }
  int b = img >> 6, c = img & 63;
  int h = t; int src = (int)brev8((uint)h);
  if (DIR == 0){
    int gy = h >> 2, py = h & 3;
    #pragma unroll
    for (int p = 0; p < 4; ++p){
      float4 av, pv;
      int base = src*17 + 4*p;
      float rr, ii;
      rr = reL[base+0]; ii = imL[base+0]; av.x = sqrtf(rr*rr+ii*ii); pv.x = atan2f(ii, rr);
      rr = reL[base+1]; ii = imL[base+1]; av.y = sqrtf(rr*rr+ii*ii); pv.y = atan2f(ii, rr);
      rr = reL[base+2]; ii = imL[base+2]; av.z = sqrtf(rr*rr+ii*ii); pv.z = atan2f(ii, rr);
      rr = reL[base+3]; ii = imL[base+3]; av.w = sqrtf(rr*rr+ii*ii); pv.w = atan2f(ii, rr);
      size_t addr = ((size_t)(b*4096 + gy*64 + (c0>>2) + p))*1024 + c*16 + py*4;
      *(float4*)(out0 + addr) = av;
      *(float4*)(out1 + addr) = pv;
    }
  } else {
    float* op = out0 + ((size_t)img*256 + h)*256 + c0;
    #pragma unroll
    for (int p = 0; p < 4; ++p){
      int base = src*17 + 4*p;
      float4 v;
      v.x = reL[base+0]*(1.f/65536.f);
      v.y = reL[base+1]*(1.f/65536.f);
      v.z = reL[base+2]*(1.f/65536.f);
      v.w = reL[base+3]*(1.f/65536.f);
      *(float4*)(op + 4*p) = v;
    }
  }
}

// ---------------- MFMA bf16 tiled GEMM, z-fused over branches/matrices ----------
struct GP {
  const float* A0[6];
  const float* A1[2];
  const float* Bm[6];
  float*       Cm[6];
  const int*   idxp[6];
  const float* ep0[2];
  const float* ep1[2];
  const float* ep2[2];
  const float* vt[2];
  const float* it[2];
  int M, N, K;
};

template<int BM, int AMODE, int EPI>
__global__ __launch_bounds__(256) void kern_mgemm(GP p){
  constexpr int LBM = (BM == 128) ? 7 : 6;
  constexpr int FR  = BM / 32;          // frags per wave in M
  constexpr int HB  = BM / 2;           // wave rows
  __shared__ __align__(16) unsigned short Asb[BM*40];
  __shared__ __align__(16) unsigned short Bsb[128*40];
  __shared__ int idx_s[BM];
  int z = blockIdx.z;
  const float* A0 = p.A0[z];
  const float* Bm = p.Bm[z];
  float* Cm = p.Cm[z];
  int tid = threadIdx.x;
  int m0 = blockIdx.y * BM;
  int n0 = blockIdx.x * 128;
  int lane = tid & 63;
  int w = tid >> 6;
  int wr = w & 1, wc = w >> 1;
  int lr = lane & 15, ql = lane >> 4;

  if (AMODE == 2 || EPI == 3){
    if (tid < BM){
      int m = m0 + tid;
      idx_s[tid] = p.idxp[z][(m >> 10)*1024 + (m & 1023)];
    }
    __syncthreads();
  }
  int gb = m0 >> 10;

  f32x4 acc[FR][4];
  #pragma unroll
  for (int i = 0; i < FR; ++i)
    #pragma unroll
    for (int j = 0; j < 4; ++j) acc[i][j] = (f32x4){0.f,0.f,0.f,0.f};

  for (int k0 = 0; k0 < p.K; k0 += 32){
    // ---- stage A (BM x 32 fp32 -> bf16 LDS, row stride 40) ----
    #pragma unroll
    for (int e0 = 0; e0 < BM*4; e0 += 256){
      int e = e0 + tid;
      int m = e & (BM-1);
      int kh = (e >> LBM) * 8;
      int k2 = k0 + kh;
      const float* ap;
      if (AMODE == 0){
        ap = A0 + (size_t)(m0+m)*p.K + k2;
      } else if (AMODE == 1){
        const float* src = (k2 < 1024) ? A0 : p.A1[z];
        int kk = (k2 < 1024) ? k2 : (k2 - 1024);
        ap = src + (size_t)(m0+m)*1024 + kk;
      } else {
        ap = A0 + ((size_t)(gb << 12) + idx_s[m])*(size_t)p.K + k2;
      }
      float4 f0 = *(const float4*)ap;
      float4 f1 = *(const float4*)(ap + 4);
      short8 v;
      v[0]=(short)f2bf(f0.x); v[1]=(short)f2bf(f0.y);
      v[2]=(short)f2bf(f0.z); v[3]=(short)f2bf(f0.w);
      v[4]=(short)f2bf(f1.x); v[5]=(short)f2bf(f1.y);
      v[6]=(short)f2bf(f1.z); v[7]=(short)f2bf(f1.w);
      *(short8*)&Asb[m*40 + kh] = v;
    }
    // ---- stage B (32 x 128 fp32 -> bf16 LDS transposed [n][k], stride 40) ----
    #pragma unroll
    for (int e0 = 0; e0 < 512; e0 += 256){
      int e = e0 + tid;
      int n = e & 127;
      int kh = (e >> 7) * 8;
      const float* bp = Bm + (size_t)(k0+kh)*p.N + n0 + n;
      short8 v;
      #pragma unroll
      for (int j = 0; j < 8; ++j) v[j] = (short)f2bf(bp[(size_t)j*p.N]);
      *(short8*)&Bsb[n*40 + kh] = v;
    }
    __syncthreads();
    short8 af[FR], bf[4];
    #pragma unroll
    for (int fr = 0; fr < FR; ++fr)
      af[fr] = *(const short8*)&Asb[(wr*HB + fr*16 + lr)*40 + ql*8];
    #pragma unroll
    for (int fc = 0; fc < 4; ++fc)
      bf[fc] = *(const short8*)&Bsb[(wc*64 + fc*16 + lr)*40 + ql*8];
    #pragma unroll
    for (int fr = 0; fr < FR; ++fr)
      #pragma unroll
      for (int fc = 0; fc < 4; ++fc)
        acc[fr][fc] = __builtin_amdgcn_mfma_f32_16x16x32_bf16(af[fr], bf[fc],
                                                              acc[fr][fc], 0, 0, 0);
    __syncthreads();
  }

  #pragma unroll
  for (int fr = 0; fr < FR; ++fr){
    #pragma unroll
    for (int fc = 0; fc < 4; ++fc){
      int n = n0 + wc*64 + fc*16 + lr;
      #pragma unroll
      for (int reg = 0; reg < 4; ++reg){
        int mloc = wr*HB + fr*16 + ql*4 + reg;
        int m = m0 + mloc;
        float v = acc[fr][fc][reg];
        if (EPI == 0){
          Cm[(size_t)m*p.N + n] = v;
        } else if (EPI == 1){
          int bl = m >> 12, g = m & 4095;
          int gy = g >> 6, gx = g & 63;
          float cy = ((float)gy + 0.5f)*(1.f/64.f);
          float cx = ((float)gx + 0.5f)*(1.f/64.f);
          float o = v + p.ep0[z][bl*128 + n] + cy*p.ep1[z][n]
                  + cx*p.ep1[z][128 + n] + p.ep2[z][n];
          Cm[(size_t)m*128 + n] = o;
        } else if (EPI == 2){
          float vt = p.vt[z][(size_t)m*1024 + n];
          float it = p.it[z][(size_t)m*1024 + n];
          float gg = 1.f/(1.f + expf(-(v + p.ep0[z][n])));
          Cm[(size_t)m*1024 + n] = gg*vt + (1.f-gg)*it;
        } else {
          int gt = idx_s[mloc];
          size_t off = ((size_t)(gb << 12) + gt)*1024 + n;
          Cm[off] = v + p.vt[z][off];
        }
      }
    }
  }
}

// ---------------- score = gelu(h) @ Wout + bout (branch via blockIdx.y) -----------
__global__ __launch_bounds__(64) void kern_score(const float* __restrict__ h,
    const float* __restrict__ wout, const float* __restrict__ bout,
    float* __restrict__ score, int Mper){
  int m = blockIdx.x, br = blockIdx.y, t = threadIdx.x;
  const float* hp = h + ((size_t)br*Mper + m)*128;
  const float* wp = wout + br*128;
  float s = geluf(hp[t])*wp[t] + geluf(hp[t+64])*wp[t+64];
  #pragma unroll
  for (int off = 32; off > 0; off >>= 1) s += __shfl_down(s, off);
  if (t == 0) score[(size_t)br*Mper + m] = s + bout[br];
}

// ---------------- per-(branch,batch) top-1024 of 4096 (bitonic, jax tie-break) ----
__global__ __launch_bounds__(1024) void kern_topk(const float* __restrict__ score,
    int* __restrict__ idx_out){
  __shared__ u64 keys[4096];
  int b = blockIdx.x, t = threadIdx.x;
  for (int i = t; i < 4096; i += 1024){
    float s = score[b*4096 + i];
    uint u = __float_as_uint(s);
    uint msk = (u & 0x80000000u) ? ~u : (u | 0x80000000u);
    keys[i] = ((u64)msk << 32) | (uint)(4095 - i);
  }
  __syncthreads();
  for (int k = 2; k <= 4096; k <<= 1){
    for (int j = k >> 1; j > 0; j >>= 1){
      for (int i = t; i < 4096; i += 1024){
        int l = i ^ j;
        if (l > i){
          u64 a = keys[i], c = keys[l];
          bool descB = ((i & k) == 0);
          bool sw = descB ? (a < c) : (a > c);
          if (sw){ keys[i] = c; keys[l] = a; }
        }
      }
      __syncthreads();
    }
  }
  idx_out[b*1024 + t] = 4095 - (int)(keys[t] & 0xFFFFFFFFu);
}

// ---------------- attention partials: k-split flash (KC=4 chunks of 256) ----------
// grid (4 qblk, 4 head, 2PB*4); thread = one q; partial (m,l,oa[32]) out.
__global__ __launch_bounds__(256) void kern_attn_part(const float* __restrict__ qb,
    const float* __restrict__ kb, const float* __restrict__ vb,
    float* __restrict__ paoa, float* __restrict__ pml){
  __shared__ float Ks[64][32];
  __shared__ float Vs[64][32];
  int t = threadIdx.x;
  int hh = blockIdx.y;
  int zc = blockIdx.z;
  int zf = zc >> 2, c = zc & 3;
  size_t boff = (size_t)zf*131072;
  int jq = blockIdx.x*256 + t;
  float qv[32];
  {
    const float4* qp = (const float4*)(qb + boff + (size_t)jq*128 + hh*32);
    #pragma unroll
    for (int d = 0; d < 8; ++d) ((float4*)qv)[d] = qp[d];
  }
  float mrun = -3.0e38f, lrun = 0.f;
  float oa[32];
  #pragma unroll
  for (int d = 0; d < 32; ++d) oa[d] = 0.f;
  for (int kt = 0; kt < 4; ++kt){
    int k0 = c*256 + kt*64;
    #pragma unroll
    for (int rep = 0; rep < 2; ++rep){
      int f = t + rep*256;
      int r = f >> 3, q4 = f & 7;
      size_t base = boff + (size_t)(k0 + r)*128 + hh*32 + 4*q4;
      *(float4*)&Ks[r][4*q4] = *(const float4*)(kb + base);
      *(float4*)&Vs[r][4*q4] = *(const float4*)(vb + base);
    }
    __syncthreads();
    #pragma unroll
    for (int st = 0; st < 4; ++st){
      float s[16];
      #pragma unroll
      for (int j = 0; j < 16; ++j){
        float v = 0.f;
        #pragma unroll
        for (int d = 0; d < 32; ++d) v += qv[d]*Ks[st*16+j][d];
        s[j] = v * 0.17677669529663687f;
      }
      float mt = s[0];
      #pragma unroll
      for (int j = 1; j < 16; ++j) mt = fmaxf(mt, s[j]);
      float mnew = fmaxf(mrun, mt);
      float alpha = expf(mrun - mnew);
      lrun *= alpha;
      #pragma unroll
      for (int d = 0; d < 32; ++d) oa[d] *= alpha;
      #pragma unroll
      for (int j = 0; j < 16; ++j){
        float pe = expf(s[j] - mnew);
        lrun += pe;
        #pragma unroll
        for (int d = 0; d < 32; ++d) oa[d] += pe*Vs[st*16+j][d];
      }
      mrun = mnew;
    }
    __syncthreads();
  }
  size_t rec = (((size_t)zf*4 + hh)*4 + c)*1024 + jq;
  float* pp = paoa + rec*32;
  #pragma unroll
  for (int d = 0; d < 8; ++d) ((float4*)pp)[d] = ((float4*)oa)[d];
  pml[rec*2]   = mrun;
  pml[rec*2+1] = lrun;
}

// ---------------- attention combine: 4 chunks -> obuf (+ intent term) -------------
__global__ __launch_bounds__(256) void kern_attn_comb(const float* __restrict__ paoa,
    const float* __restrict__ pml, float* __restrict__ ob,
    const float* __restrict__ ipint, int PB, int b0){
  int t = threadIdx.x;
  int hh = blockIdx.y, zf = blockIdx.z;
  int jq = blockIdx.x*256 + t;
  size_t rbase = (((size_t)zf*4 + hh)*4)*1024 + jq;
  float mc[4], lc[4];
  #pragma unroll
  for (int c = 0; c < 4; ++c){
    mc[c] = pml[(rbase + c*1024)*2];
    lc[c] = pml[(rbase + c*1024)*2 + 1];
  }
  float M = fmaxf(fmaxf(mc[0], mc[1]), fmaxf(mc[2], mc[3]));
  float wgt[4], L = 0.f;
  #pragma unroll
  for (int c = 0; c < 4; ++c){ wgt[c] = expf(mc[c] - M); L += lc[c]*wgt[c]; }
  float inv = 1.f/L;
  int br = (zf >= PB) ? 1 : 0;
  int bb = zf - br*PB;
  const float* ip = ipint + br*512 + (b0+bb)*128 + hh*32;
  float* op = ob + (size_t)zf*131072 + (size_t)jq*128 + hh*32;
  #pragma unroll
  for (int d = 0; d < 32; ++d){
    float o = 0.f;
    #pragma unroll
    for (int c = 0; c < 4; ++c) o += paoa[(rbase + c*1024)*32 + d]*wgt[c];
    op[d] = o*inv + ip[d];
  }
}

// ---------------- weight transform: w[co][ci][3][3] fp32 -> wt[set][tap][co][ci] bf16 ----
__global__ __launch_bounds__(256) void kern_wt(const float* __restrict__ w1,
    const float* __restrict__ w2, unsigned short* __restrict__ wt){
  int blk = blockIdx.x;                 // 0..17: set = blk/9, tap = blk%9
  const float* src = (blk < 9) ? w1 : w2;
  int tap = blk - (blk < 9 ? 0 : 9);
  unsigned short* dst = wt + (blk < 9 ? 0 : 36864) + tap*4096;
  for (int e = threadIdx.x; e < 4096; e += 256){
    dst[e] = f2bf(src[(size_t)e*9 + tap]);
  }
}

// ---------------- implicit-GEMM 3x3 conv via MFMA ----------------
template<int MODE>
__global__ __launch_bounds__(256) void kern_cmfma(const float* __restrict__ in,
    const unsigned short* __restrict__ wt, const float* __restrict__ bias,
    float* __restrict__ out,
    const float* __restrict__ modg, const float* __restrict__ modb,
    const float* __restrict__ vis, const float* __restrict__ irf){
  __shared__ __align__(16) unsigned short ins[64][268];
  int t = threadIdx.x;
  int y = blockIdx.x, b = blockIdx.y;
  int lane = t & 63, w = t >> 6;
  int wc = w & 1, wx = w >> 1;
  int lr = lane & 15, ql = lane >> 4;

  f32x4 acc[2][8];
  #pragma unroll
  for (int f = 0; f < 2; ++f)
    #pragma unroll
    for (int xf = 0; xf < 8; ++xf) acc[f][xf] = (f32x4){0.f,0.f,0.f,0.f};

  for (int dy = 0; dy < 3; ++dy){
    int yy = y + dy - 1;
    if (yy < 0 || yy > 255) continue;
    const float* src = in + ((size_t)(b*64)*256 + yy)*256;
    #pragma unroll
    for (int s = 0; s < 16; ++s){
      int e = t + s*256;
      int ci = e >> 6, q = e & 63;
      float4 f4 = *(const float4*)(src + (size_t)ci*65536 + 4*q);
      uint lo = (uint)f2bf(f4.x) | ((uint)f2bf(f4.y) << 16);
      uint hi = (uint)f2bf(f4.z) | ((uint)f2bf(f4.w) << 16);
      *(uint2*)&ins[ci][4*q + 4] = make_uint2(lo, hi);
    }
    if (t < 128){
      int r = t & 63;
      ins[r][(t >> 6) ? 260 : 3] = 0;
    }
    __syncthreads();
    short8 wf[2][3][2];   // [kk][dx][f]
    #pragma unroll
    for (int kk = 0; kk < 2; ++kk)
      #pragma unroll
      for (int dx = 0; dx < 3; ++dx)
        #pragma unroll
        for (int f = 0; f < 2; ++f)
          wf[kk][dx][f] = *(const short8*)(wt +
            (size_t)((dy*3 + dx)*64 + 32*wc + 16*f + lr)*64 + kk*32 + ql*8);
    #pragma unroll
    for (int kk = 0; kk < 2; ++kk){
      const unsigned short* bp = &ins[kk*32 + ql*8][0];
      #pragma unroll
      for (int dx = 0; dx < 3; ++dx){
        int xb = 128*wx + lr + dx + 3;
        #pragma unroll
        for (int xf = 0; xf < 8; ++xf){
          int xi = xb + 16*xf;
          short8 bf;
          #pragma unroll
          for (int e = 0; e < 8; ++e) bf[e] = (short)bp[e*268 + xi];
          acc[0][xf] = __builtin_amdgcn_mfma_f32_16x16x32_bf16(wf[kk][dx][0], bf,
                                                               acc[0][xf], 0, 0, 0);
          acc[1][xf] = __builtin_amdgcn_mfma_f32_16x16x32_bf16(wf[kk][dx][1], bf,
                                                               acc[1][xf], 0, 0, 0);
        }
      }
    }
    __syncthreads();
  }

  #pragma unroll
  for (int f = 0; f < 2; ++f){
    #pragma unroll
    for (int xf = 0; xf < 8; ++xf){
      int x = 128*wx + 16*xf + lr;
      #pragma unroll
      for (int reg = 0; reg < 4; ++reg){
        int co = 32*wc + 16*f + ql*4 + reg;
        float v = acc[f][xf][reg] + bias[co];
        size_t oi = ((size_t)(b*64 + co)*256 + y)*256 + x;
        if (MODE == 1){
          out[oi] = fmaxf(v, 0.f);
        } else {
          out[oi] = v*modg[b*64+co] + modb[b*64+co] + 0.5f*(vis[oi] + irf[oi]);
        }
      }
    }
  }
}

// ---------------- launch ----------------
extern "C" void kernel_launch(void* const* d_in, const int* in_sizes, int n_in,
                              void* d_out, int out_size, void* d_ws, size_t ws_size,
                              hipStream_t stream){
  (void)in_sizes; (void)n_in; (void)out_size;
  const float* vis  = (const float*)d_in[0];
  const float* irf  = (const float*)d_in[1];
  const float* bank = (const float*)d_in[2];
  const float* Wr   = (const float*)d_in[3];
  const float* br   = (const float*)d_in[4];
  const float* Wtok = (const float*)d_in[5];
  const float* Wpri = (const float*)d_in[6];
  const float* Wco  = (const float*)d_in[7];
  const float* bs   = (const float*)d_in[8];
  const float* Wout = (const float*)d_in[9];
  const float* bout = (const float*)d_in[10];
  const float* Wq   = (const float*)d_in[11];
  const float* Wk   = (const float*)d_in[12];
  const float* Wv   = (const float*)d_in[13];
  const float* Wo   = (const float*)d_in[14];
  const float* Wint = (const float*)d_in[15];
  const float* Wbyp = (const float*)d_in[16];
  const float* bbyp = (const float*)d_in[17];
  const float* c1w  = (const float*)d_in[18];
  const float* c1b  = (const float*)d_in[19];
  const float* c2w  = (const float*)d_in[20];
  const float* c2b  = (const float*)d_in[21];
  const float* Wa1  = (const float*)d_in[22];
  const float* ba1  = (const float*)d_in[23];
  const float* Wa2  = (const float*)d_in[24];
  const float* ba2  = (const float*)d_in[25];

  auto needB = [](int PB)->size_t{
    return ((size_t)5*PB*4194304 + (size_t)2*PB*524288 + (size_t)2*PB*4096
          + (size_t)2*PB*1024 + (size_t)8*PB*131072 + (size_t)PB*65536
          + 4096 + 36864) * 4;
  };
  const int PB = (ws_size >= needB(4)) ? 4 : (ws_size >= needB(2)) ? 2 : 1;

  float* ws = (float*)d_ws;
  const size_t SL = (size_t)PB*4194304;    // per-group slab (floats)
  float* P0 = ws;
  float* P1 = P0 + SL;
  float* P2 = P1 + SL;
  float* P3 = P2 + SL;
  float* P4 = P3 + SL;
  float* sm = P4 + SL;
  float* hbuf  = sm; sm += (size_t)2*PB*524288;    // [2][PB*4096][128]; aliased by paoa
  float* score = sm; sm += (size_t)2*PB*4096;      // [2*PB][4096]
  int*   idxb  = (int*)sm; sm += (size_t)2*PB*1024;// [2*PB][1024]
  float* qbuf  = sm; sm += (size_t)2*PB*131072;    // [2*PB][1024][128]
  float* kbuf  = sm; sm += (size_t)2*PB*131072;
  float* vbuf  = sm; sm += (size_t)2*PB*131072;
  float* obuf  = sm; sm += (size_t)2*PB*131072;
  float* pml   = sm; sm += (size_t)PB*65536;       // [2PB][4][4][1024][2]
  float* pooled= sm; sm += 512;
  float* IP    = sm; sm += 1024;
  float* IPint = sm; sm += 1024;
  float* modg  = sm; sm += 256;
  float* modb  = sm; sm += 256;
  unsigned short* wtb = (unsigned short*)sm; sm += 36864;  // [2][9][64][64] bf16
  float* paoa = hbuf;   // [2PB][4][4][1024][32] fp32 == 2*PB*524288 exactly (h dead)

  kern_pool <<<512, 256, 0, stream>>>(vis, irf, pooled);
  kern_small<<<1, 256, 0, stream>>>(pooled, Wr, br, bank, Wpri, Wint,
                                    Wa1, ba1, Wa2, ba2, IP, IPint, modg, modb);
  kern_wt   <<<18, 256, 0, stream>>>(c1w, c2w, wtb);

  for (int b0 = 0; b0 < 4; b0 += PB){
    const float* vis_b = vis + (size_t)b0*4194304;
    const float* ir_b  = irf + (size_t)b0*4194304;
    float* OUT = (float*)d_out + (size_t)b0*4194304;  // transient re / FULL_amp / spatial

    // forward FFT2 + amp/phase (patchified layout)
    kern_fft_rows_fwd<<<PB*8192, 256, 0, stream>>>(vis_b, OUT, P4);
    kern_fft_cols<0> <<<PB*1024, 256, 0, stream>>>(OUT, P4, P0, P1);  // AMP_V, PH_V
    kern_fft_rows_fwd<<<PB*8192, 256, 0, stream>>>(ir_b, OUT, P4);
    kern_fft_cols<0> <<<PB*1024, 256, 0, stream>>>(OUT, P4, P2, P3);  // AMP_I, PH_I

    {  // h = cat(vt,it)@Wtok + IP[b] + coords@Wco + bs   (both branches, z=2)
      GP p{};
      p.A0[0]=P0; p.A1[0]=P2; p.A0[1]=P1; p.A1[1]=P3;
      for (int z = 0; z < 2; ++z){
        p.Bm[z] = Wtok + (size_t)z*262144;
        p.Cm[z] = hbuf + (size_t)z*PB*524288;
        p.ep0[z] = IP + z*512 + b0*128;
        p.ep1[z] = Wco + z*256;
        p.ep2[z] = bs + z*128;
      }
      p.M = PB*4096; p.N = 128; p.K = 2048;
      kern_mgemm<64,1,1><<<dim3(1, PB*64, 2), 256, 0, stream>>>(p);
    }
    kern_score<<<dim3(PB*4096, 2), 64, 0, stream>>>(hbuf, Wout, bout, score, PB*4096);
    kern_topk <<<2*PB, 1024, 0, stream>>>(score, idxb);
    {  // bypass blend into FULL (amp -> OUT, ph -> P4), both branches
      GP p{};
      p.A0[0]=P0; p.A1[0]=P2; p.A0[1]=P1; p.A1[1]=P3;
      p.vt[0]=P0; p.it[0]=P2; p.vt[1]=P1; p.it[1]=P3;
      p.Cm[0]=OUT; p.Cm[1]=P4;
      for (int z = 0; z < 2; ++z){
        p.Bm[z] = Wbyp + (size_t)z*2097152;
        p.ep0[z] = bbyp + z*1024;
      }
      p.M = PB*4096; p.N = 1024; p.K = 2048;
      kern_mgemm<128,1,2><<<dim3(8, PB*32, 2), 256, 0, stream>>>(p);
    }
    {  // q,k,v gathered rows: z = br*3 + {q,k,v}
      GP p{};
      const float* Aplanes[6] = {P0, P2, P2, P1, P3, P3};
      const float* Bmats[6] = {Wq, Wk, Wv, Wq+131072, Wk+131072, Wv+131072};
      float* Cms[6] = {qbuf, kbuf, vbuf,
                       qbuf+(size_t)PB*131072, kbuf+(size_t)PB*131072, vbuf+(size_t)PB*131072};
      for (int z = 0; z < 6; ++z){
        p.A0[z] = Aplanes[z]; p.Bm[z] = Bmats[z]; p.Cm[z] = Cms[z];
        p.idxp[z] = idxb + (z < 3 ? 0 : PB*1024);
      }
      p.M = PB*1024; p.N = 128; p.K = 1024;
      kern_mgemm<64,2,0><<<dim3(1, PB*16, 6), 256, 0, stream>>>(p);
    }
    // k-split flash attention (h/score dead -> paoa aliases hbuf)
    kern_attn_part<<<dim3(4, 4, 2*PB*4), 256, 0, stream>>>(qbuf, kbuf, vbuf,
                                                           paoa, pml);
    kern_attn_comb<<<dim3(4, 4, 2*PB), 256, 0, stream>>>(paoa, pml, obuf,
                                                         IPint, PB, b0);
    {  // fused_sel = vs + o@Wo scattered into FULL, both branches
      GP p{};
      p.A0[0]=obuf; p.A0[1]=obuf+(size_t)PB*131072;
      p.Bm[0]=Wo; p.Bm[1]=Wo+131072;
      p.Cm[0]=OUT; p.Cm[1]=P4;
      p.vt[0]=P0; p.vt[1]=P1;
      p.idxp[0]=idxb; p.idxp[1]=idxb+PB*1024;
      p.M = PB*1024; p.N = 1024; p.K = 128;
      kern_mgemm<64,0,3><<<dim3(8, PB*16, 2), 256, 0, stream>>>(p);
    }

    // spec = famp * e^{i fph}; inverse FFT2 -> spatial into OUT (d_out slab)
    kern_ifft_rows_spec<<<PB*4096, 256, 0, stream>>>(OUT, P4, P0, P1);
    kern_fft_cols<1>   <<<PB*1024, 256, 0, stream>>>(P0, P1, OUT, nullptr);
  }

  // convs (MFMA implicit GEMM): d_out(spatial) -> ws (conv1+relu) -> d_out (conv2+mod+res)
  kern_cmfma<1><<<dim3(256, 4), 256, 0, stream>>>((float*)d_out, wtb, c1b, ws,
                                                  nullptr, nullptr, nullptr, nullptr);
  kern_cmfma<2><<<dim3(256, 4), 256, 0, stream>>>(ws, wtb + 36864, c2b, (float*)d_out,
                                                  modg, modb, vis, irf);
}

// Round 7
// 1851.695 us; speedup vs baseline: 7.3129x; 1.2196x over previous
//
#include <hip/hip_runtime.h>

typedef unsigned int uint;
typedef unsigned long long u64;
typedef __attribute__((ext_vector_type(8))) short short8;
typedef __attribute__((ext_vector_type(4))) float f32x4;

__device__ __forceinline__ uint brev8(uint x){ return __brev(x) >> 24; }
__device__ __forceinline__ float geluf(float x){
  return 0.5f*x*(1.f + tanhf(0.7978845608028654f*(x + 0.044715f*x*x*x)));
}
__device__ __forceinline__ unsigned short f2bf(float f){
  unsigned u = __float_as_uint(f);
  unsigned r = u + 0x7FFFu + ((u >> 16) & 1u);
  return (unsigned short)(r >> 16);
}
__device__ __forceinline__ short8 cvt8(float4 f0, float4 f1){
  short8 v;
  v[0]=(short)f2bf(f0.x); v[1]=(short)f2bf(f0.y);
  v[2]=(short)f2bf(f0.z); v[3]=(short)f2bf(f0.w);
  v[4]=(short)f2bf(f1.x); v[5]=(short)f2bf(f1.y);
  v[6]=(short)f2bf(f1.z); v[7]=(short)f2bf(f1.w);
  return v;
}

// ---------------- pooled mean ----------------
__global__ __launch_bounds__(256) void kern_pool(const float* __restrict__ vis,
                                                 const float* __restrict__ irf,
                                                 float* __restrict__ pooled){
  __shared__ float red[256];
  int bc = blockIdx.x;
  int b = bc >> 7, cc = bc & 127;
  const float* src = (cc < 64) ? (vis + (size_t)(b*64+cc)*65536)
                               : (irf + (size_t)(b*64+(cc-64))*65536);
  float s = 0.f;
  for (int i = threadIdx.x; i < 65536; i += 256) s += src[i];
  red[threadIdx.x] = s;
  __syncthreads();
  for (int off = 128; off > 0; off >>= 1){
    if (threadIdx.x < off) red[threadIdx.x] += red[threadIdx.x + off];
    __syncthreads();
  }
  if (threadIdx.x == 0) pooled[bc] = red[0] * (1.f/65536.f);
}

// ---------------- prompt/intent/affine small ops ----------------
__global__ __launch_bounds__(256) void kern_small(const float* __restrict__ pooled,
    const float* __restrict__ Wr, const float* __restrict__ br,
    const float* __restrict__ bank, const float* __restrict__ Wpri,
    const float* __restrict__ Wint, const float* __restrict__ Wa1,
    const float* __restrict__ ba1, const float* __restrict__ Wa2,
    const float* __restrict__ ba2,
    float* __restrict__ IP, float* __restrict__ IPint,
    float* __restrict__ modg, float* __restrict__ modb){
  __shared__ float logit_s[16];
  __shared__ float pw_s[16];
  __shared__ float intent_s[4][64];
  __shared__ float t1_s[4][128];
  int t = threadIdx.x;
  if (t < 16){
    int b = t >> 2, j = t & 3;
    float s = br[j];
    for (int k = 0; k < 128; ++k) s += pooled[b*128+k]*Wr[k*4+j];
    logit_s[t] = s;
  }
  __syncthreads();
  if (t < 4){
    int b = t;
    float m = logit_s[b*4];
    for (int j = 1; j < 4; ++j) m = fmaxf(m, logit_s[b*4+j]);
    float e[4], sum = 0.f;
    for (int j = 0; j < 4; ++j){ e[j] = expf(logit_s[b*4+j]-m); sum += e[j]; }
    for (int j = 0; j < 4; ++j) pw_s[b*4+j] = e[j]/sum;
  }
  __syncthreads();
  {
    int b = t >> 6, p = t & 63;
    float s = 0.f;
    for (int j = 0; j < 4; ++j) s += pw_s[b*4+j]*bank[j*64+p];
    intent_s[b][p] = s;
  }
  __syncthreads();
  for (int o = t; o < 1024; o += 256){
    int i = o >> 9, rem = o & 511, b = rem >> 7, n = rem & 127;
    float s1 = 0.f, s2 = 0.f;
    for (int p = 0; p < 64; ++p){
      float iv = intent_s[b][p];
      s1 += iv * Wpri[(i*64+p)*128 + n];
      s2 += iv * Wint[(i*64+p)*128 + n];
    }
    IP[o] = s1; IPint[o] = s2;
  }
  for (int o = t; o < 512; o += 256){
    int b = o >> 7, n = o & 127;
    float s = ba1[n];
    for (int p = 0; p < 64; ++p) s += intent_s[b][p]*Wa1[p*128+n];
    t1_s[b][n] = geluf(s);
  }
  __syncthreads();
  for (int o = t; o < 512; o += 256){
    int b = o >> 7, n = o & 127;
    float s = ba2[n];
    for (int p = 0; p < 128; ++p) s += t1_s[b][p]*Wa2[p*128+n];
    if (n < 64) modg[b*64+n] = 1.f + 0.1f*tanhf(s);
    else        modb[b*64+(n-64)] = 0.1f*s;
  }
}

// ---------------- forward row FFT ----------------
__global__ __launch_bounds__(256) void kern_fft_rows_fwd(const float* __restrict__ x,
    float* __restrict__ sre, float* __restrict__ sim){
  __shared__ float re[2][256], im[2][256];
  __shared__ float twr[128], twi[128];
  int t = threadIdx.x;
  if (t < 128){
    float a = -6.2831853071795864f * (float)t * (1.f/256.f);
    sincosf(a, &twi[t], &twr[t]);
  }
  int r = t >> 7, jj = t & 127;
  size_t row = (size_t)blockIdx.x*2 + r;
  {
    const float* xp = x + row*256;
    re[r][jj] = xp[jj]; re[r][jj+128] = xp[jj+128];
    im[r][jj] = 0.f;    im[r][jj+128] = 0.f;
  }
  __syncthreads();
  for (int s = 0; s < 8; ++s){
    int half = 128 >> s;
    int j = jj & (half-1);
    int g = jj >> (7-s);
    int k = (g << (8-s)) + j;
    int m = j << s;
    float wc = twr[m], ws = twi[m];
    float are = re[r][k],      aim = im[r][k];
    float bre = re[r][k+half], bim = im[r][k+half];
    re[r][k] = are + bre; im[r][k] = aim + bim;
    float tr = are - bre, ti = aim - bim;
    re[r][k+half] = tr*wc - ti*ws;
    im[r][k+half] = tr*ws + ti*wc;
    __syncthreads();
  }
  {
    float* orp = sre + row*256; float* oip = sim + row*256;
    int w1 = jj, w2 = jj + 128;
    orp[w1] = re[r][brev8(w1)]; oip[w1] = im[r][brev8(w1)];
    orp[w2] = re[r][brev8(w2)]; oip[w2] = im[r][brev8(w2)];
  }
}

// ---------------- inverse row FFT with spec construction ----------------
__global__ __launch_bounds__(256) void kern_ifft_rows_spec(const float* __restrict__ famp,
    const float* __restrict__ fph, float* __restrict__ sre, float* __restrict__ sim){
  __shared__ float re[4][256], im[4][256];
  __shared__ float twr[128], twi[128];
  int t = threadIdx.x;
  if (t < 128){
    float a = -6.2831853071795864f * (float)t * (1.f/256.f);
    sincosf(a, &twi[t], &twr[t]);
  }
  int R = blockIdx.x * 4;
  {
    int r = t >> 6, q = t & 63;
    int row = R + r;
    int bc = row >> 8, h = row & 255;
    int b = bc >> 6, c = bc & 63;
    size_t addr = ((size_t)(b*4096 + (h>>2)*64 + q))*1024 + c*16 + (h&3)*4;
    float4 a4 = *(const float4*)(famp + addr);
    float4 p4 = *(const float4*)(fph + addr);
    float sn, cs;
    sincosf(p4.x, &sn, &cs); re[r][4*q+0] = a4.x*cs; im[r][4*q+0] = a4.x*sn;
    sincosf(p4.y, &sn, &cs); re[r][4*q+1] = a4.y*cs; im[r][4*q+1] = a4.y*sn;
    sincosf(p4.z, &sn, &cs); re[r][4*q+2] = a4.z*cs; im[r][4*q+2] = a4.z*sn;
    sincosf(p4.w, &sn, &cs); re[r][4*q+3] = a4.w*cs; im[r][4*q+3] = a4.w*sn;
  }
  __syncthreads();
  for (int s = 0; s < 8; ++s){
    int half = 128 >> s;
    #pragma unroll
    for (int bi0 = 0; bi0 < 2; ++bi0){
      int bi = t + bi0*256;
      int r = bi >> 7, tj = bi & 127;
      int j = tj & (half-1);
      int g = tj >> (7-s);
      int k = (g << (8-s)) + j;
      int m = j << s;
      float wc = twr[m], ws = -twi[m];
      float are = re[r][k],      aim = im[r][k];
      float bre = re[r][k+half], bim = im[r][k+half];
      re[r][k] = are + bre; im[r][k] = aim + bim;
      float tr = are - bre, ti = aim - bim;
      re[r][k+half] = tr*wc - ti*ws;
      im[r][k+half] = tr*ws + ti*wc;
    }
    __syncthreads();
  }
  {
    int r = t >> 6, q = t & 63;
    size_t row = (size_t)R + r;
    float4 vr, vi;
    vr.x = re[r][brev8(4*q+0)]; vi.x = im[r][brev8(4*q+0)];
    vr.y = re[r][brev8(4*q+1)]; vi.y = im[r][brev8(4*q+1)];
    vr.z = re[r][brev8(4*q+2)]; vi.z = im[r][brev8(4*q+2)];
    vr.w = re[r][brev8(4*q+3)]; vi.w = im[r][brev8(4*q+3)];
    *(float4*)(sre + row*256 + 4*q) = vr;
    *(float4*)(sim + row*256 + 4*q) = vi;
  }
}

// ---------------- column FFT ----------------
template<int DIR>
__global__ __launch_bounds__(256) void kern_fft_cols(const float* __restrict__ sre,
    const float* __restrict__ sim, float* __restrict__ out0, float* __restrict__ out1){
  __shared__ float reL[256*17];
  __shared__ float imL[256*17];
  __shared__ float twr[128], twi[128];
  int t = threadIdx.x;
  if (t < 128){
    float a = -6.2831853071795864f * (float)t * (1.f/256.f);
    sincosf(a, &twi[t], &twr[t]);
  }
  int img = blockIdx.x >> 4;
  int c0 = (blockIdx.x & 15) * 16;
  {
    const float* pr = sre + ((size_t)img*256 + t)*256 + c0;
    const float* pi = sim + ((size_t)img*256 + t)*256 + c0;
    #pragma unroll
    for (int p = 0; p < 4; ++p){
      float4 vr = *(const float4*)(pr + 4*p);
      float4 vi = *(const float4*)(pi + 4*p);
      int base = t*17 + 4*p;
      reL[base+0]=vr.x; reL[base+1]=vr.y; reL[base+2]=vr.z; reL[base+3]=vr.w;
      imL[base+0]=vi.x; imL[base+1]=vi.y; imL[base+2]=vi.z; imL[base+3]=vi.w;
    }
  }
  __syncthreads();
  int col = t & 15, tb = t >> 4;
  for (int s = 0; s < 8; ++s){
    int half = 128 >> s;
    #pragma unroll
    for (int it = 0; it < 8; ++it){
      int tj = tb + it*16;
      int j = tj & (half-1);
      int g = tj >> (7-s);
      int k = (g << (8-s)) + j;
      int m = j << s;
      float wc = twr[m];
      float ws = (DIR == 0) ? twi[m] : -twi[m];
      int i0 = k*17 + col, i1 = (k+half)*17 + col;
      float are = reL[i0], aim = imL[i0];
      float bre = reL[i1], bim = imL[i1];
      reL[i0] = are + bre; imL[i0] = aim + bim;
      float tr = are - bre, ti = aim - bim;
      reL[i1] = tr*wc - ti*ws;
      imL[i1] = tr*ws + ti*wc;
    }
    __syncthreads();
  }
  int b = img >> 6, c = img & 63;
  int h = t; int src = (int)brev8((uint)h);
  if (DIR == 0){
    int gy = h >> 2, py = h & 3;
    #pragma unroll
    for (int p = 0; p < 4; ++p){
      float4 av, pv;
      int base = src*17 + 4*p;
      float rr, ii;
      rr = reL[base+0]; ii = imL[base+0]; av.x = sqrtf(rr*rr+ii*ii); pv.x = atan2f(ii, rr);
      rr = reL[base+1]; ii = imL[base+1]; av.y = sqrtf(rr*rr+ii*ii); pv.y = atan2f(ii, rr);
      rr = reL[base+2]; ii = imL[base+2]; av.z = sqrtf(rr*rr+ii*ii); pv.z = atan2f(ii, rr);
      rr = reL[base+3]; ii = imL[base+3]; av.w = sqrtf(rr*rr+ii*ii); pv.w = atan2f(ii, rr);
      size_t addr = ((size_t)(b*4096 + gy*64 + (c0>>2) + p))*1024 + c*16 + py*4;
      *(float4*)(out0 + addr) = av;
      *(float4*)(out1 + addr) = pv;
    }
  } else {
    float* op = out0 + ((size_t)img*256 + h)*256 + c0;
    #pragma unroll
    for (int p = 0; p < 4; ++p){
      int base = src*17 + 4*p;
      float4 v;
      v.x = reL[base+0]*(1.f/65536.f);
      v.y = reL[base+1]*(1.f/65536.f);
      v.z = reL[base+2]*(1.f/65536.f);
      v.w = reL[base+3]*(1.f/65536.f);
      *(float4*)(op + 4*p) = v;
    }
  }
}

// ---------------- transpose-convert: fp32 [K][N] -> bf16 [N][K], 10 mats ----------
struct TRS {
  const float* src[10];
  unsigned short* dst[10];
  int K[10], N[10];
  int start[11];
};
__global__ __launch_bounds__(256) void kern_tr(TRS p){
  __shared__ float lds[32][33];
  int bid = blockIdx.x;
  int e = 0;
  while (bid >= p.start[e+1]) ++e;
  int tloc = bid - p.start[e];
  int tilesN = p.N[e] >> 5;
  int tn = tloc % tilesN, tk = tloc / tilesN;
  int k0 = tk << 5, n0 = tn << 5;
  const float* src = p.src[e];
  unsigned short* dst = p.dst[e];
  int K = p.K[e], N = p.N[e];
  int r = threadIdx.x >> 5, c = threadIdx.x & 31;
  #pragma unroll
  for (int i = 0; i < 4; ++i)
    lds[r + 8*i][c] = src[(size_t)(k0 + r + 8*i)*N + n0 + c];
  __syncthreads();
  #pragma unroll
  for (int i = 0; i < 4; ++i)
    dst[(size_t)(n0 + r + 8*i)*K + k0 + c] = f2bf(lds[c][r + 8*i]);
}

// ---------------- NEW MFMA GEMM: BM=64, BN=128, BK=64, bf16 B^T, XOR-swizzled LDS --
// grid (m-blocks, n-blocks, z).  AMODE: 1 cat(A0|A1) along K (1024 each), 2 gather.
// EPI: 0 plain store, 1 h-epi, 2 bypass blend.
struct GP2 {
  const float* A0[6];
  const float* A1[2];
  const unsigned short* Bt[6];
  float* Cm[6];
  const int* idxp[6];
  const float* ep0[2];
  const float* ep1[2];
  const float* ep2[2];
  const float* vt[2];
  const float* it[2];
  int N, K;
};

template<int AMODE, int EPI>
__global__ __launch_bounds__(256) void kern_mgemm2(GP2 p){
  __shared__ __align__(16) unsigned short Asb[64*64];
  __shared__ __align__(16) unsigned short Bsb[128*64];
  __shared__ int idx_s[64];
  int z = blockIdx.z;
  const float* A0 = p.A0[z];
  const unsigned short* Bt = p.Bt[z];
  float* Cm = p.Cm[z];
  int tid = threadIdx.x;
  int m0 = blockIdx.x * 64;     // x = m: same-A blocks share an XCD
  int n0 = blockIdx.y * 128;
  int lane = tid & 63, w = tid >> 6;
  int wr = w & 1, wc = w >> 1;
  int lr = lane & 15, ql = lane >> 4;

  if (AMODE == 2){
    if (tid < 64){
      int m = m0 + tid;
      idx_s[tid] = p.idxp[z][(m >> 10)*1024 + (m & 1023)];
    }
    __syncthreads();
  }
  int gb = m0 >> 10;

  f32x4 acc[2][4];
  #pragma unroll
  for (int i = 0; i < 2; ++i)
    #pragma unroll
    for (int j = 0; j < 4; ++j) acc[i][j] = (f32x4){0.f,0.f,0.f,0.f};

  int kh = tid & 7;             // k-chunk (8 bf16) within BK
  int rA = tid >> 3;            // row scan base (0..31)
  for (int k0 = 0; k0 < p.K; k0 += 64){
    // ---- stage A: fp32 -> bf16, rows rA, rA+32 ----
    #pragma unroll
    for (int s = 0; s < 2; ++s){
      int m = rA + 32*s;
      const float* ap;
      if (AMODE == 1){
        const float* srcp = (k0 < 1024) ? A0 : p.A1[z];
        ap = srcp + (size_t)(m0+m)*1024 + (k0 & 1023) + kh*8;
      } else {
        ap = A0 + ((size_t)(gb << 12) + idx_s[m])*(size_t)p.K + k0 + kh*8;
      }
      float4 f0 = *(const float4*)ap;
      float4 f1 = *(const float4*)(ap + 4);
      int byte = m*128 + ((kh*16) ^ ((m & 7)*16));
      *(short8*)((char*)Asb + byte) = cvt8(f0, f1);
    }
    // ---- stage B: bf16 direct, rows rA + 32s ----
    #pragma unroll
    for (int s = 0; s < 4; ++s){
      int n = rA + 32*s;
      short8 v = *(const short8*)(Bt + (size_t)(n0+n)*p.K + k0 + kh*8);
      int byte = n*128 + ((kh*16) ^ ((n & 7)*16));
      *(short8*)((char*)Bsb + byte) = v;
    }
    __syncthreads();
    short8 af[2][2], bf[4][2];
    #pragma unroll
    for (int fm = 0; fm < 2; ++fm){
      int row = wr*32 + fm*16 + lr;
      #pragma unroll
      for (int kq = 0; kq < 2; ++kq){
        int byte = row*128 + ((kq*64 + ql*16) ^ ((row & 7)*16));
        af[fm][kq] = *(const short8*)((const char*)Asb + byte);
      }
    }
    #pragma unroll
    for (int fn = 0; fn < 4; ++fn){
      int row = wc*64 + fn*16 + lr;
      #pragma unroll
      for (int kq = 0; kq < 2; ++kq){
        int byte = row*128 + ((kq*64 + ql*16) ^ ((row & 7)*16));
        bf[fn][kq] = *(const short8*)((const char*)Bsb + byte);
      }
    }
    #pragma unroll
    for (int kq = 0; kq < 2; ++kq)
      #pragma unroll
      for (int fm = 0; fm < 2; ++fm)
        #pragma unroll
        for (int fn = 0; fn < 4; ++fn)
          acc[fm][fn] = __builtin_amdgcn_mfma_f32_16x16x32_bf16(af[fm][kq], bf[fn][kq],
                                                                acc[fm][fn], 0, 0, 0);
    __syncthreads();
  }

  #pragma unroll
  for (int fm = 0; fm < 2; ++fm){
    #pragma unroll
    for (int fn = 0; fn < 4; ++fn){
      int n = n0 + wc*64 + fn*16 + lr;
      #pragma unroll
      for (int reg = 0; reg < 4; ++reg){
        int m = m0 + wr*32 + fm*16 + ql*4 + reg;
        float v = acc[fm][fn][reg];
        if (EPI == 0){
          Cm[(size_t)m*p.N + n] = v;
        } else if (EPI == 1){
          int bl = m >> 12, g = m & 4095;
          int gy = g >> 6, gx = g & 63;
          float cy = ((float)gy + 0.5f)*(1.f/64.f);
          float cx = ((float)gx + 0.5f)*(1.f/64.f);
          float o = v + p.ep0[z][bl*128 + n] + cy*p.ep1[z][n]
                  + cx*p.ep1[z][128 + n] + p.ep2[z][n];
          Cm[(size_t)m*128 + n] = o;
        } else {
          float vt = p.vt[z][(size_t)m*1024 + n];
          float it = p.it[z][(size_t)m*1024 + n];
          float gg = 1.f/(1.f + expf(-(v + p.ep0[z][n])));
          Cm[(size_t)m*1024 + n] = gg*vt + (1.f-gg)*it;
        }
      }
    }
  }
}

// ---------------- OLD MFMA GEMM (fallback + scatter EPI=3) ----------
struct GP {
  const float* A0[6];
  const float* A1[2];
  const float* Bm[6];
  float*       Cm[6];
  const int*   idxp[6];
  const float* ep0[2];
  const float* ep1[2];
  const float* ep2[2];
  const float* vt[2];
  const float* it[2];
  int M, N, K;
};

template<int BM, int AMODE, int EPI>
__global__ __launch_bounds__(256) void kern_mgemm(GP p){
  constexpr int LBM = (BM == 128) ? 7 : 6;
  constexpr int FR  = BM / 32;
  constexpr int HB  = BM / 2;
  __shared__ __align__(16) unsigned short Asb[BM*40];
  __shared__ __align__(16) unsigned short Bsb[128*40];
  __shared__ int idx_s[BM];
  int z = blockIdx.z;
  const float* A0 = p.A0[z];
  const float* Bm = p.Bm[z];
  float* Cm = p.Cm[z];
  int tid = threadIdx.x;
  int m0 = blockIdx.y * BM;
  int n0 = blockIdx.x * 128;
  int lane = tid & 63;
  int w = tid >> 6;
  int wr = w & 1, wc = w >> 1;
  int lr = lane & 15, ql = lane >> 4;

  if (AMODE == 2 || EPI == 3){
    if (tid < BM){
      int m = m0 + tid;
      idx_s[tid] = p.idxp[z][(m >> 10)*1024 + (m & 1023)];
    }
    __syncthreads();
  }
  int gb = m0 >> 10;

  f32x4 acc[FR][4];
  #pragma unroll
  for (int i = 0; i < FR; ++i)
    #pragma unroll
    for (int j = 0; j < 4; ++j) acc[i][j] = (f32x4){0.f,0.f,0.f,0.f};

  for (int k0 = 0; k0 < p.K; k0 += 32){
    #pragma unroll
    for (int e0 = 0; e0 < BM*4; e0 += 256){
      int e = e0 + tid;
      int m = e & (BM-1);
      int khh = (e >> LBM) * 8;
      int k2 = k0 + khh;
      const float* ap;
      if (AMODE == 0){
        ap = A0 + (size_t)(m0+m)*p.K + k2;
      } else if (AMODE == 1){
        const float* src = (k2 < 1024) ? A0 : p.A1[z];
        int kk = (k2 < 1024) ? k2 : (k2 - 1024);
        ap = src + (size_t)(m0+m)*1024 + kk;
      } else {
        ap = A0 + ((size_t)(gb << 12) + idx_s[m])*(size_t)p.K + k2;
      }
      float4 f0 = *(const float4*)ap;
      float4 f1 = *(const float4*)(ap + 4);
      *(short8*)&Asb[m*40 + khh] = cvt8(f0, f1);
    }
    #pragma unroll
    for (int e0 = 0; e0 < 512; e0 += 256){
      int e = e0 + tid;
      int n = e & 127;
      int khh = (e >> 7) * 8;
      const float* bp = Bm + (size_t)(k0+khh)*p.N + n0 + n;
      short8 v;
      #pragma unroll
      for (int j = 0; j < 8; ++j) v[j] = (short)f2bf(bp[(size_t)j*p.N]);
      *(short8*)&Bsb[n*40 + khh] = v;
    }
    __syncthreads();
    short8 af[FR], bf[4];
    #pragma unroll
    for (int fr = 0; fr < FR; ++fr)
      af[fr] = *(const short8*)&Asb[(wr*HB + fr*16 + lr)*40 + ql*8];
    #pragma unroll
    for (int fc = 0; fc < 4; ++fc)
      bf[fc] = *(const short8*)&Bsb[(wc*64 + fc*16 + lr)*40 + ql*8];
    #pragma unroll
    for (int fr = 0; fr < FR; ++fr)
      #pragma unroll
      for (int fc = 0; fc < 4; ++fc)
        acc[fr][fc] = __builtin_amdgcn_mfma_f32_16x16x32_bf16(af[fr], bf[fc],
                                                              acc[fr][fc], 0, 0, 0);
    __syncthreads();
  }

  #pragma unroll
  for (int fr = 0; fr < FR; ++fr){
    #pragma unroll
    for (int fc = 0; fc < 4; ++fc){
      int n = n0 + wc*64 + fc*16 + lr;
      #pragma unroll
      for (int reg = 0; reg < 4; ++reg){
        int mloc = wr*HB + fr*16 + ql*4 + reg;
        int m = m0 + mloc;
        float v = acc[fr][fc][reg];
        if (EPI == 0){
          Cm[(size_t)m*p.N + n] = v;
        } else if (EPI == 1){
          int bl = m >> 12, g = m & 4095;
          int gy = g >> 6, gx = g & 63;
          float cy = ((float)gy + 0.5f)*(1.f/64.f);
          float cx = ((float)gx + 0.5f)*(1.f/64.f);
          float o = v + p.ep0[z][bl*128 + n] + cy*p.ep1[z][n]
                  + cx*p.ep1[z][128 + n] + p.ep2[z][n];
          Cm[(size_t)m*128 + n] = o;
        } else if (EPI == 2){
          float vt = p.vt[z][(size_t)m*1024 + n];
          float it = p.it[z][(size_t)m*1024 + n];
          float gg = 1.f/(1.f + expf(-(v + p.ep0[z][n])));
          Cm[(size_t)m*1024 + n] = gg*vt + (1.f-gg)*it;
        } else {
          int gt = idx_s[mloc];
          size_t off = ((size_t)(gb << 12) + gt)*1024 + n;
          Cm[off] = v + p.vt[z][off];
        }
      }
    }
  }
}

// ---------------- score ----------------
__global__ __launch_bounds__(64) void kern_score(const float* __restrict__ h,
    const float* __restrict__ wout, const float* __restrict__ bout,
    float* __restrict__ score, int Mper){
  int m = blockIdx.x, br = blockIdx.y, t = threadIdx.x;
  const float* hp = h + ((size_t)br*Mper + m)*128;
  const float* wp = wout + br*128;
  float s = geluf(hp[t])*wp[t] + geluf(hp[t+64])*wp[t+64];
  #pragma unroll
  for (int off = 32; off > 0; off >>= 1) s += __shfl_down(s, off);
  if (t == 0) score[(size_t)br*Mper + m] = s + bout[br];
}

// ---------------- top-1024 of 4096 (bitonic, jax tie-break) ----------------
__global__ __launch_bounds__(1024) void kern_topk(const float* __restrict__ score,
    int* __restrict__ idx_out){
  __shared__ u64 keys[4096];
  int b = blockIdx.x, t = threadIdx.x;
  for (int i = t; i < 4096; i += 1024){
    float s = score[b*4096 + i];
    uint u = __float_as_uint(s);
    uint msk = (u & 0x80000000u) ? ~u : (u | 0x80000000u);
    keys[i] = ((u64)msk << 32) | (uint)(4095 - i);
  }
  __syncthreads();
  for (int k = 2; k <= 4096; k <<= 1){
    for (int j = k >> 1; j > 0; j >>= 1){
      for (int i = t; i < 4096; i += 1024){
        int l = i ^ j;
        if (l > i){
          u64 a = keys[i], c = keys[l];
          bool descB = ((i & k) == 0);
          bool sw = descB ? (a < c) : (a > c);
          if (sw){ keys[i] = c; keys[l] = a; }
        }
      }
      __syncthreads();
    }
  }
  idx_out[b*1024 + t] = 4095 - (int)(keys[t] & 0xFFFFFFFFu);
}

// ---------------- attention partials (k-split flash) ----------------
__global__ __launch_bounds__(256) void kern_attn_part(const float* __restrict__ qb,
    const float* __restrict__ kb, const float* __restrict__ vb,
    float* __restrict__ paoa, float* __restrict__ pml){
  __shared__ float Ks[64][32];
  __shared__ float Vs[64][32];
  int t = threadIdx.x;
  int hh = blockIdx.y;
  int zc = blockIdx.z;
  int zf = zc >> 2, c = zc & 3;
  size_t boff = (size_t)zf*131072;
  int jq = blockIdx.x*256 + t;
  float qv[32];
  {
    const float4* qp = (const float4*)(qb + boff + (size_t)jq*128 + hh*32);
    #pragma unroll
    for (int d = 0; d < 8; ++d) ((float4*)qv)[d] = qp[d];
  }
  float mrun = -3.0e38f, lrun = 0.f;
  float oa[32];
  #pragma unroll
  for (int d = 0; d < 32; ++d) oa[d] = 0.f;
  for (int kt = 0; kt < 4; ++kt){
    int k0 = c*256 + kt*64;
    #pragma unroll
    for (int rep = 0; rep < 2; ++rep){
      int f = t + rep*256;
      int r = f >> 3, q4 = f & 7;
      size_t base = boff + (size_t)(k0 + r)*128 + hh*32 + 4*q4;
      *(float4*)&Ks[r][4*q4] = *(const float4*)(kb + base);
      *(float4*)&Vs[r][4*q4] = *(const float4*)(vb + base);
    }
    __syncthreads();
    #pragma unroll
    for (int st = 0; st < 4; ++st){
      float s[16];
      #pragma unroll
      for (int j = 0; j < 16; ++j){
        float v = 0.f;
        #pragma unroll
        for (int d = 0; d < 32; ++d) v += qv[d]*Ks[st*16+j][d];
        s[j] = v * 0.17677669529663687f;
      }
      float mt = s[0];
      #pragma unroll
      for (int j = 1; j < 16; ++j) mt = fmaxf(mt, s[j]);
      float mnew = fmaxf(mrun, mt);
      float alpha = expf(mrun - mnew);
      lrun *= alpha;
      #pragma unroll
      for (int d = 0; d < 32; ++d) oa[d] *= alpha;
      #pragma unroll
      for (int j = 0; j < 16; ++j){
        float pe = expf(s[j] - mnew);
        lrun += pe;
        #pragma unroll
        for (int d = 0; d < 32; ++d) oa[d] += pe*Vs[st*16+j][d];
      }
      mrun = mnew;
    }
    __syncthreads();
  }
  size_t rec = (((size_t)zf*4 + hh)*4 + c)*1024 + jq;
  float* pp = paoa + rec*32;
  #pragma unroll
  for (int d = 0; d < 8; ++d) ((float4*)pp)[d] = ((float4*)oa)[d];
  pml[rec*2]   = mrun;
  pml[rec*2+1] = lrun;
}

// ---------------- attention combine ----------------
__global__ __launch_bounds__(256) void kern_attn_comb(const float* __restrict__ paoa,
    const float* __restrict__ pml, float* __restrict__ ob,
    const float* __restrict__ ipint, int PB, int b0){
  int t = threadIdx.x;
  int hh = blockIdx.y, zf = blockIdx.z;
  int jq = blockIdx.x*256 + t;
  size_t rbase = (((size_t)zf*4 + hh)*4)*1024 + jq;
  float mc[4], lc[4];
  #pragma unroll
  for (int c = 0; c < 4; ++c){
    mc[c] = pml[(rbase + c*1024)*2];
    lc[c] = pml[(rbase + c*1024)*2 + 1];
  }
  float M = fmaxf(fmaxf(mc[0], mc[1]), fmaxf(mc[2], mc[3]));
  float wgt[4], L = 0.f;
  #pragma unroll
  for (int c = 0; c < 4; ++c){ wgt[c] = expf(mc[c] - M); L += lc[c]*wgt[c]; }
  float inv = 1.f/L;
  int br = (zf >= PB) ? 1 : 0;
  int bb = zf - br*PB;
  const float* ip = ipint + br*512 + (b0+bb)*128 + hh*32;
  float* op = ob + (size_t)zf*131072 + (size_t)jq*128 + hh*32;
  #pragma unroll
  for (int d = 0; d < 32; ++d){
    float o = 0.f;
    #pragma unroll
    for (int c = 0; c < 4; ++c) o += paoa[(rbase + c*1024)*32 + d]*wgt[c];
    op[d] = o*inv + ip[d];
  }
}

// ---------------- conv weight transform ----------------
__global__ __launch_bounds__(256) void kern_wt(const float* __restrict__ w1,
    const float* __restrict__ w2, unsigned short* __restrict__ wt){
  int blk = blockIdx.x;
  const float* src = (blk < 9) ? w1 : w2;
  int tap = blk - (blk < 9 ? 0 : 9);
  unsigned short* dst = wt + (blk < 9 ? 0 : 36864) + tap*4096;
  for (int e = threadIdx.x; e < 4096; e += 256){
    dst[e] = f2bf(src[(size_t)e*9 + tap]);
  }
}

// ---------------- implicit-GEMM 3x3 conv via MFMA ----------------
template<int MODE>
__global__ __launch_bounds__(256) void kern_cmfma(const float* __restrict__ in,
    const unsigned short* __restrict__ wt, const float* __restrict__ bias,
    float* __restrict__ out,
    const float* __restrict__ modg, const float* __restrict__ modb,
    const float* __restrict__ vis, const float* __restrict__ irf){
  __shared__ __align__(16) unsigned short ins[64][268];
  int t = threadIdx.x;
  int y = blockIdx.x, b = blockIdx.y;
  int lane = t & 63, w = t >> 6;
  int wc = w & 1, wx = w >> 1;
  int lr = lane & 15, ql = lane >> 4;

  f32x4 acc[2][8];
  #pragma unroll
  for (int f = 0; f < 2; ++f)
    #pragma unroll
    for (int xf = 0; xf < 8; ++xf) acc[f][xf] = (f32x4){0.f,0.f,0.f,0.f};

  for (int dy = 0; dy < 3; ++dy){
    int yy = y + dy - 1;
    if (yy < 0 || yy > 255) continue;
    const float* src = in + ((size_t)(b*64)*256 + yy)*256;
    #pragma unroll
    for (int s = 0; s < 16; ++s){
      int e = t + s*256;
      int ci = e >> 6, q = e & 63;
      float4 f4 = *(const float4*)(src + (size_t)ci*65536 + 4*q);
      uint lo = (uint)f2bf(f4.x) | ((uint)f2bf(f4.y) << 16);
      uint hi = (uint)f2bf(f4.z) | ((uint)f2bf(f4.w) << 16);
      *(uint2*)&ins[ci][4*q + 4] = make_uint2(lo, hi);
    }
    if (t < 128){
      int r = t & 63;
      ins[r][(t >> 6) ? 260 : 3] = 0;
    }
    __syncthreads();
    short8 wf[2][3][2];
    #pragma unroll
    for (int kk = 0; kk < 2; ++kk)
      #pragma unroll
      for (int dx = 0; dx < 3; ++dx)
        #pragma unroll
        for (int f = 0; f < 2; ++f)
          wf[kk][dx][f] = *(const short8*)(wt +
            (size_t)((dy*3 + dx)*64 + 32*wc + 16*f + lr)*64 + kk*32 + ql*8);
    #pragma unroll
    for (int kk = 0; kk < 2; ++kk){
      const unsigned short* bp = &ins[kk*32 + ql*8][0];
      #pragma unroll
      for (int dx = 0; dx < 3; ++dx){
        int xb = 128*wx + lr + dx + 3;
        #pragma unroll
        for (int xf = 0; xf < 8; ++xf){
          int xi = xb + 16*xf;
          short8 bf;
          #pragma unroll
          for (int e = 0; e < 8; ++e) bf[e] = (short)bp[e*268 + xi];
          acc[0][xf] = __builtin_amdgcn_mfma_f32_16x16x32_bf16(wf[kk][dx][0], bf,
                                                               acc[0][xf], 0, 0, 0);
          acc[1][xf] = __builtin_amdgcn_mfma_f32_16x16x32_bf16(wf[kk][dx][1], bf,
                                                               acc[1][xf], 0, 0, 0);
        }
      }
    }
    __syncthreads();
  }

  #pragma unroll
  for (int f = 0; f < 2; ++f){
    #pragma unroll
    for (int xf = 0; xf < 8; ++xf){
      int x = 128*wx + 16*xf + lr;
      #pragma unroll
      for (int reg = 0; reg < 4; ++reg){
        int co = 32*wc + 16*f + ql*4 + reg;
        float v = acc[f][xf][reg] + bias[co];
        size_t oi = ((size_t)(b*64 + co)*256 + y)*256 + x;
        if (MODE == 1){
          out[oi] = fmaxf(v, 0.f);
        } else {
          out[oi] = v*modg[b*64+co] + modb[b*64+co] + 0.5f*(vis[oi] + irf[oi]);
        }
      }
    }
  }
}

// ---------------- launch ----------------
extern "C" void kernel_launch(void* const* d_in, const int* in_sizes, int n_in,
                              void* d_out, int out_size, void* d_ws, size_t ws_size,
                              hipStream_t stream){
  (void)in_sizes; (void)n_in; (void)out_size;
  const float* vis  = (const float*)d_in[0];
  const float* irf  = (const float*)d_in[1];
  const float* bank = (const float*)d_in[2];
  const float* Wr   = (const float*)d_in[3];
  const float* br   = (const float*)d_in[4];
  const float* Wtok = (const float*)d_in[5];
  const float* Wpri = (const float*)d_in[6];
  const float* Wco  = (const float*)d_in[7];
  const float* bs   = (const float*)d_in[8];
  const float* Wout = (const float*)d_in[9];
  const float* bout = (const float*)d_in[10];
  const float* Wq   = (const float*)d_in[11];
  const float* Wk   = (const float*)d_in[12];
  const float* Wv   = (const float*)d_in[13];
  const float* Wo   = (const float*)d_in[14];
  const float* Wint = (const float*)d_in[15];
  const float* Wbyp = (const float*)d_in[16];
  const float* bbyp = (const float*)d_in[17];
  const float* c1w  = (const float*)d_in[18];
  const float* c1b  = (const float*)d_in[19];
  const float* c2w  = (const float*)d_in[20];
  const float* c2b  = (const float*)d_in[21];
  const float* Wa1  = (const float*)d_in[22];
  const float* ba1  = (const float*)d_in[23];
  const float* Wa2  = (const float*)d_in[24];
  const float* ba2  = (const float*)d_in[25];

  auto needOld = [](int PB)->size_t{
    return ((size_t)5*PB*4194304 + (size_t)2*PB*524288 + (size_t)2*PB*4096
          + (size_t)2*PB*1024 + (size_t)8*PB*131072 + (size_t)PB*65536
          + 4096 + 36864) * 4;
  };
  const size_t BTfl = 2752512;   // bf16 B^T buffers, in floats
  auto needNew = [&](int PB)->size_t{ return needOld(PB) + BTfl*4; };
  int PB; bool NEW;
  if      (ws_size >= needNew(4)){ PB = 4; NEW = true; }
  else if (ws_size >= needNew(2)){ PB = 2; NEW = true; }
  else if (ws_size >= needNew(1)){ PB = 1; NEW = true; }
  else { NEW = false; PB = (ws_size >= needOld(4)) ? 4 : (ws_size >= needOld(2)) ? 2 : 1; }

  float* ws = (float*)d_ws;
  const size_t SL = (size_t)PB*4194304;
  float* P0 = ws;
  float* P1 = P0 + SL;
  float* P2 = P1 + SL;
  float* P3 = P2 + SL;
  float* P4 = P3 + SL;
  float* sm = P4 + SL;
  float* hbuf  = sm; sm += (size_t)2*PB*524288;
  float* score = sm; sm += (size_t)2*PB*4096;
  int*   idxb  = (int*)sm; sm += (size_t)2*PB*1024;
  float* qbuf  = sm; sm += (size_t)2*PB*131072;
  float* kbuf  = sm; sm += (size_t)2*PB*131072;
  float* vbuf  = sm; sm += (size_t)2*PB*131072;
  float* obuf  = sm; sm += (size_t)2*PB*131072;
  float* pml   = sm; sm += (size_t)PB*65536;
  float* pooled= sm; sm += 512;
  float* IP    = sm; sm += 1024;
  float* IPint = sm; sm += 1024;
  float* modg  = sm; sm += 256;
  float* modb  = sm; sm += 256;
  unsigned short* wtb = (unsigned short*)sm; sm += 36864;
  unsigned short* BTtok = (unsigned short*)sm;   // [2][128][2048]
  unsigned short* BTbyp = BTtok + 524288;        // [2][1024][2048]
  unsigned short* BTq   = BTbyp + 4194304;       // [2][128][1024]
  unsigned short* BTk   = BTq + 262144;
  unsigned short* BTv   = BTk + 262144;
  float* paoa = hbuf;

  kern_pool <<<512, 256, 0, stream>>>(vis, irf, pooled);
  kern_small<<<1, 256, 0, stream>>>(pooled, Wr, br, bank, Wpri, Wint,
                                    Wa1, ba1, Wa2, ba2, IP, IPint, modg, modb);
  kern_wt   <<<18, 256, 0, stream>>>(c1w, c2w, wtb);
  if (NEW){
    TRS tr{};
    const float* srcs[10] = {Wtok, Wtok+262144, Wbyp, Wbyp+2097152,
                             Wq, Wq+131072, Wk, Wk+131072, Wv, Wv+131072};
    unsigned short* dsts[10] = {BTtok, BTtok+262144, BTbyp, BTbyp+2097152,
                                BTq, BTq+131072, BTk, BTk+131072, BTv, BTv+131072};
    int Ks[10] = {2048,2048,2048,2048,1024,1024,1024,1024,1024,1024};
    int Ns[10] = {128,128,1024,1024,128,128,128,128,128,128};
    int tiles[10] = {256,256,2048,2048,128,128,128,128,128,128};
    int acc0 = 0;
    for (int i = 0; i < 10; ++i){
      tr.src[i] = srcs[i]; tr.dst[i] = dsts[i];
      tr.K[i] = Ks[i]; tr.N[i] = Ns[i];
      tr.start[i] = acc0; acc0 += tiles[i];
    }
    tr.start[10] = acc0;
    kern_tr<<<acc0, 256, 0, stream>>>(tr);
  }

  for (int b0 = 0; b0 < 4; b0 += PB){
    const float* vis_b = vis + (size_t)b0*4194304;
    const float* ir_b  = irf + (size_t)b0*4194304;
    float* OUT = (float*)d_out + (size_t)b0*4194304;

    kern_fft_rows_fwd<<<PB*8192, 256, 0, stream>>>(vis_b, OUT, P4);
    kern_fft_cols<0> <<<PB*1024, 256, 0, stream>>>(OUT, P4, P0, P1);
    kern_fft_rows_fwd<<<PB*8192, 256, 0, stream>>>(ir_b, OUT, P4);
    kern_fft_cols<0> <<<PB*1024, 256, 0, stream>>>(OUT, P4, P2, P3);

    if (NEW){
      {  // h-GEMM
        GP2 p{};
        p.A0[0]=P0; p.A1[0]=P2; p.A0[1]=P1; p.A1[1]=P3;
        for (int z = 0; z < 2; ++z){
          p.Bt[z] = BTtok + (size_t)z*262144;
          p.Cm[z] = hbuf + (size_t)z*PB*524288;
          p.ep0[z] = IP + z*512 + b0*128;
          p.ep1[z] = Wco + z*256;
          p.ep2[z] = bs + z*128;
        }
        p.N = 128; p.K = 2048;
        kern_mgemm2<1,1><<<dim3(PB*64, 1, 2), 256, 0, stream>>>(p);
      }
      kern_score<<<dim3(PB*4096, 2), 64, 0, stream>>>(hbuf, Wout, bout, score, PB*4096);
      kern_topk <<<2*PB, 1024, 0, stream>>>(score, idxb);
      {  // bypass
        GP2 p{};
        p.A0[0]=P0; p.A1[0]=P2; p.A0[1]=P1; p.A1[1]=P3;
        p.vt[0]=P0; p.it[0]=P2; p.vt[1]=P1; p.it[1]=P3;
        p.Cm[0]=OUT; p.Cm[1]=P4;
        for (int z = 0; z < 2; ++z){
          p.Bt[z] = BTbyp + (size_t)z*2097152;
          p.ep0[z] = bbyp + z*1024;
        }
        p.N = 1024; p.K = 2048;
        kern_mgemm2<1,2><<<dim3(PB*64, 8, 2), 256, 0, stream>>>(p);
      }
      {  // qkv gather
        GP2 p{};
        const float* Aplanes[6] = {P0, P2, P2, P1, P3, P3};
        const unsigned short* Bmats[6] = {BTq, BTk, BTv,
                                          BTq+131072, BTk+131072, BTv+131072};
        float* Cms[6] = {qbuf, kbuf, vbuf,
                         qbuf+(size_t)PB*131072, kbuf+(size_t)PB*131072,
                         vbuf+(size_t)PB*131072};
        for (int z = 0; z < 6; ++z){
          p.A0[z] = Aplanes[z]; p.Bt[z] = Bmats[z]; p.Cm[z] = Cms[z];
          p.idxp[z] = idxb + (z < 3 ? 0 : PB*1024);
        }
        p.N = 128; p.K = 1024;
        kern_mgemm2<2,0><<<dim3(PB*16, 1, 6), 256, 0, stream>>>(p);
      }
    } else {
      {  // h-GEMM (old)
        GP p{};
        p.A0[0]=P0; p.A1[0]=P2; p.A0[1]=P1; p.A1[1]=P3;
        for (int z = 0; z < 2; ++z){
          p.Bm[z] = Wtok + (size_t)z*262144;
          p.Cm[z] = hbuf + (size_t)z*PB*524288;
          p.ep0[z] = IP + z*512 + b0*128;
          p.ep1[z] = Wco + z*256;
          p.ep2[z] = bs + z*128;
        }
        p.M = PB*4096; p.N = 128; p.K = 2048;
        kern_mgemm<64,1,1><<<dim3(1, PB*64, 2), 256, 0, stream>>>(p);
      }
      kern_score<<<dim3(PB*4096, 2), 64, 0, stream>>>(hbuf, Wout, bout, score, PB*4096);
      kern_topk <<<2*PB, 1024, 0, stream>>>(score, idxb);
      {  // bypass (old)
        GP p{};
        p.A0[0]=P0; p.A1[0]=P2; p.A0[1]=P1; p.A1[1]=P3;
        p.vt[0]=P0; p.it[0]=P2; p.vt[1]=P1; p.it[1]=P3;
        p.Cm[0]=OUT; p.Cm[1]=P4;
        for (int z = 0; z < 2; ++z){
          p.Bm[z] = Wbyp + (size_t)z*2097152;
          p.ep0[z] = bbyp + z*1024;
        }
        p.M = PB*4096; p.N = 1024; p.K = 2048;
        kern_mgemm<128,1,2><<<dim3(8, PB*32, 2), 256, 0, stream>>>(p);
      }
      {  // qkv (old)
        GP p{};
        const float* Aplanes[6] = {P0, P2, P2, P1, P3, P3};
        const float* Bmats[6] = {Wq, Wk, Wv, Wq+131072, Wk+131072, Wv+131072};
        float* Cms[6] = {qbuf, kbuf, vbuf,
                         qbuf+(size_t)PB*131072, kbuf+(size_t)PB*131072,
                         vbuf+(size_t)PB*131072};
        for (int z = 0; z < 6; ++z){
          p.A0[z] = Aplanes[z]; p.Bm[z] = Bmats[z]; p.Cm[z] = Cms[z];
          p.idxp[z] = idxb + (z < 3 ? 0 : PB*1024);
        }
        p.M = PB*1024; p.N = 128; p.K = 1024;
        kern_mgemm<64,2,0><<<dim3(1, PB*16, 6), 256, 0, stream>>>(p);
      }
    }
    kern_attn_part<<<dim3(4, 4, 2*PB*4), 256, 0, stream>>>(qbuf, kbuf, vbuf,
                                                           paoa, pml);
    kern_attn_comb<<<dim3(4, 4, 2*PB), 256, 0, stream>>>(paoa, pml, obuf,
                                                         IPint, PB, b0);
    {  // fused_sel scatter (old kernel, fp32 A)
      GP p{};
      p.A0[0]=obuf; p.A0[1]=obuf+(size_t)PB*131072;
      p.Bm[0]=Wo; p.Bm[1]=Wo+131072;
      p.Cm[0]=OUT; p.Cm[1]=P4;
      p.vt[0]=P0; p.vt[1]=P1;
      p.idxp[0]=idxb; p.idxp[1]=idxb+PB*1024;
      p.M = PB*1024; p.N = 1024; p.K = 128;
      kern_mgemm<64,0,3><<<dim3(8, PB*16, 2), 256, 0, stream>>>(p);
    }

    kern_ifft_rows_spec<<<PB*4096, 256, 0, stream>>>(OUT, P4, P0, P1);
    kern_fft_cols<1>   <<<PB*1024, 256, 0, stream>>>(P0, P1, OUT, nullptr);
  }

  kern_cmfma<1><<<dim3(256, 4), 256, 0, stream>>>((float*)d_out, wtb, c1b, ws,
                                                  nullptr, nullptr, nullptr, nullptr);
  kern_cmfma<2><<<dim3(256, 4), 256, 0, stream>>>(ws, wtb + 36864, c2b, (float*)d_out,
                                                  modg, modb, vis, irf);
}

// Round 9
// 1419.303 us; speedup vs baseline: 9.5407x; 1.3047x over previous
//
#include <hip/hip_runtime.h>

typedef unsigned int uint;
typedef unsigned long long u64;
typedef __attribute__((ext_vector_type(8))) short short8;
typedef __attribute__((ext_vector_type(4))) float f32x4;

__device__ __forceinline__ uint brev8(uint x){ return __brev(x) >> 24; }
__device__ __forceinline__ float geluf(float x){
  return 0.5f*x*(1.f + tanhf(0.7978845608028654f*(x + 0.044715f*x*x*x)));
}
__device__ __forceinline__ unsigned short f2bf(float f){
  unsigned u = __float_as_uint(f);
  unsigned r = u + 0x7FFFu + ((u >> 16) & 1u);
  return (unsigned short)(r >> 16);
}
__device__ __forceinline__ float bf2f(unsigned short u){
  return __uint_as_float((uint)u << 16);
}

// ---------------- pooled mean ----------------
__global__ __launch_bounds__(256) void kern_pool(const float* __restrict__ vis,
                                                 const float* __restrict__ irf,
                                                 float* __restrict__ pooled){
  __shared__ float red[256];
  int bc = blockIdx.x;
  int b = bc >> 7, cc = bc & 127;
  const float* src = (cc < 64) ? (vis + (size_t)(b*64+cc)*65536)
                               : (irf + (size_t)(b*64+(cc-64))*65536);
  float s = 0.f;
  for (int i = threadIdx.x; i < 65536; i += 256) s += src[i];
  red[threadIdx.x] = s;
  __syncthreads();
  for (int off = 128; off > 0; off >>= 1){
    if (threadIdx.x < off) red[threadIdx.x] += red[threadIdx.x + off];
    __syncthreads();
  }
  if (threadIdx.x == 0) pooled[bc] = red[0] * (1.f/65536.f);
}

// ---------------- prompt/intent/affine small ops ----------------
__global__ __launch_bounds__(256) void kern_small(const float* __restrict__ pooled,
    const float* __restrict__ Wr, const float* __restrict__ br,
    const float* __restrict__ bank, const float* __restrict__ Wpri,
    const float* __restrict__ Wint, const float* __restrict__ Wa1,
    const float* __restrict__ ba1, const float* __restrict__ Wa2,
    const float* __restrict__ ba2,
    float* __restrict__ IP, float* __restrict__ IPint,
    float* __restrict__ modg, float* __restrict__ modb){
  __shared__ float logit_s[16];
  __shared__ float pw_s[16];
  __shared__ float intent_s[4][64];
  __shared__ float t1_s[4][128];
  int t = threadIdx.x;
  if (t < 16){
    int b = t >> 2, j = t & 3;
    float s = br[j];
    for (int k = 0; k < 128; ++k) s += pooled[b*128+k]*Wr[k*4+j];
    logit_s[t] = s;
  }
  __syncthreads();
  if (t < 4){
    int b = t;
    float m = logit_s[b*4];
    for (int j = 1; j < 4; ++j) m = fmaxf(m, logit_s[b*4+j]);
    float e[4], sum = 0.f;
    for (int j = 0; j < 4; ++j){ e[j] = expf(logit_s[b*4+j]-m); sum += e[j]; }
    for (int j = 0; j < 4; ++j) pw_s[b*4+j] = e[j]/sum;
  }
  __syncthreads();
  {
    int b = t >> 6, p = t & 63;
    float s = 0.f;
    for (int j = 0; j < 4; ++j) s += pw_s[b*4+j]*bank[j*64+p];
    intent_s[b][p] = s;
  }
  __syncthreads();
  for (int o = t; o < 1024; o += 256){
    int i = o >> 9, rem = o & 511, b = rem >> 7, n = rem & 127;
    float s1 = 0.f, s2 = 0.f;
    for (int p = 0; p < 64; ++p){
      float iv = intent_s[b][p];
      s1 += iv * Wpri[(i*64+p)*128 + n];
      s2 += iv * Wint[(i*64+p)*128 + n];
    }
    IP[o] = s1; IPint[o] = s2;
  }
  for (int o = t; o < 512; o += 256){
    int b = o >> 7, n = o & 127;
    float s = ba1[n];
    for (int p = 0; p < 64; ++p) s += intent_s[b][p]*Wa1[p*128+n];
    t1_s[b][n] = geluf(s);
  }
  __syncthreads();
  for (int o = t; o < 512; o += 256){
    int b = o >> 7, n = o & 127;
    float s = ba2[n];
    for (int p = 0; p < 128; ++p) s += t1_s[b][p]*Wa2[p*128+n];
    if (n < 64) modg[b*64+n] = 1.f + 0.1f*tanhf(s);
    else        modb[b*64+(n-64)] = 0.1f*s;
  }
}

// ---------------- forward row FFT ----------------
__global__ __launch_bounds__(256) void kern_fft_rows_fwd(const float* __restrict__ x,
    float* __restrict__ sre, float* __restrict__ sim){
  __shared__ float re[2][256], im[2][256];
  __shared__ float twr[128], twi[128];
  int t = threadIdx.x;
  if (t < 128){
    float a = -6.2831853071795864f * (float)t * (1.f/256.f);
    sincosf(a, &twi[t], &twr[t]);
  }
  int r = t >> 7, jj = t & 127;
  size_t row = (size_t)blockIdx.x*2 + r;
  {
    const float* xp = x + row*256;
    re[r][jj] = xp[jj]; re[r][jj+128] = xp[jj+128];
    im[r][jj] = 0.f;    im[r][jj+128] = 0.f;
  }
  __syncthreads();
  for (int s = 0; s < 8; ++s){
    int half = 128 >> s;
    int j = jj & (half-1);
    int g = jj >> (7-s);
    int k = (g << (8-s)) + j;
    int m = j << s;
    float wc = twr[m], ws = twi[m];
    float are = re[r][k],      aim = im[r][k];
    float bre = re[r][k+half], bim = im[r][k+half];
    re[r][k] = are + bre; im[r][k] = aim + bim;
    float tr = are - bre, ti = aim - bim;
    re[r][k+half] = tr*wc - ti*ws;
    im[r][k+half] = tr*ws + ti*wc;
    __syncthreads();
  }
  {
    float* orp = sre + row*256; float* oip = sim + row*256;
    int w1 = jj, w2 = jj + 128;
    orp[w1] = re[r][brev8(w1)]; oip[w1] = im[r][brev8(w1)];
    orp[w2] = re[r][brev8(w2)]; oip[w2] = im[r][brev8(w2)];
  }
}

// ---------------- inverse row FFT with spec construction ----------------
__global__ __launch_bounds__(256) void kern_ifft_rows_spec(const float* __restrict__ famp,
    const float* __restrict__ fph, float* __restrict__ sre, float* __restrict__ sim){
  __shared__ float re[4][256], im[4][256];
  __shared__ float twr[128], twi[128];
  int t = threadIdx.x;
  if (t < 128){
    float a = -6.2831853071795864f * (float)t * (1.f/256.f);
    sincosf(a, &twi[t], &twr[t]);
  }
  int R = blockIdx.x * 4;
  {
    int r = t >> 6, q = t & 63;
    int row = R + r;
    int bc = row >> 8, h = row & 255;
    int b = bc >> 6, c = bc & 63;
    size_t addr = ((size_t)(b*4096 + (h>>2)*64 + q))*1024 + c*16 + (h&3)*4;
    float4 a4 = *(const float4*)(famp + addr);
    float4 p4 = *(const float4*)(fph + addr);
    float sn, cs;
    sincosf(p4.x, &sn, &cs); re[r][4*q+0] = a4.x*cs; im[r][4*q+0] = a4.x*sn;
    sincosf(p4.y, &sn, &cs); re[r][4*q+1] = a4.y*cs; im[r][4*q+1] = a4.y*sn;
    sincosf(p4.z, &sn, &cs); re[r][4*q+2] = a4.z*cs; im[r][4*q+2] = a4.z*sn;
    sincosf(p4.w, &sn, &cs); re[r][4*q+3] = a4.w*cs; im[r][4*q+3] = a4.w*sn;
  }
  __syncthreads();
  for (int s = 0; s < 8; ++s){
    int half = 128 >> s;
    #pragma unroll
    for (int bi0 = 0; bi0 < 2; ++bi0){
      int bi = t + bi0*256;
      int r = bi >> 7, tj = bi & 127;
      int j = tj & (half-1);
      int g = tj >> (7-s);
      int k = (g << (8-s)) + j;
      int m = j << s;
      float wc = twr[m], ws = -twi[m];
      float are = re[r][k],      aim = im[r][k];
      float bre = re[r][k+half], bim = im[r][k+half];
      re[r][k] = are + bre; im[r][k] = aim + bim;
      float tr = are - bre, ti = aim - bim;
      re[r][k+half] = tr*wc - ti*ws;
      im[r][k+half] = tr*ws + ti*wc;
    }
    __syncthreads();
  }
  {
    int r = t >> 6, q = t & 63;
    size_t row = (size_t)R + r;
    float4 vr, vi;
    vr.x = re[r][brev8(4*q+0)]; vi.x = im[r][brev8(4*q+0)];
    vr.y = re[r][brev8(4*q+1)]; vi.y = im[r][brev8(4*q+1)];
    vr.z = re[r][brev8(4*q+2)]; vi.z = im[r][brev8(4*q+2)];
    vr.w = re[r][brev8(4*q+3)]; vi.w = im[r][brev8(4*q+3)];
    *(float4*)(sre + row*256 + 4*q) = vr;
    *(float4*)(sim + row*256 + 4*q) = vi;
  }
}

// ---------------- column FFT: DIR=0 fwd (bf16 amp/ph patchified), DIR=1 inv (fp32) ---
template<int DIR>
__global__ __launch_bounds__(256) void kern_fft_cols(const float* __restrict__ sre,
    const float* __restrict__ sim, void* __restrict__ out0, void* __restrict__ out1){
  __shared__ float reL[256*17];
  __shared__ float imL[256*17];
  __shared__ float twr[128], twi[128];
  int t = threadIdx.x;
  if (t < 128){
    float a = -6.2831853071795864f * (float)t * (1.f/256.f);
    sincosf(a, &twi[t], &twr[t]);
  }
  int img = blockIdx.x >> 4;
  int c0 = (blockIdx.x & 15) * 16;
  {
    const float* pr = sre + ((size_t)img*256 + t)*256 + c0;
    const float* pi = sim + ((size_t)img*256 + t)*256 + c0;
    #pragma unroll
    for (int p = 0; p < 4; ++p){
      float4 vr = *(const float4*)(pr + 4*p);
      float4 vi = *(const float4*)(pi + 4*p);
      int base = t*17 + 4*p;
      reL[base+0]=vr.x; reL[base+1]=vr.y; reL[base+2]=vr.z; reL[base+3]=vr.w;
      imL[base+0]=vi.x; imL[base+1]=vi.y; imL[base+2]=vi.z; imL[base+3]=vi.w;
    }
  }
  __syncthreads();
  int col = t & 15, tb = t >> 4;
  for (int s = 0; s < 8; ++s){
    int half = 128 >> s;
    #pragma unroll
    for (int it = 0; it < 8; ++it){
      int tj = tb + it*16;
      int j = tj & (half-1);
      int g = tj >> (7-s);
      int k = (g << (8-s)) + j;
      int m = j << s;
      float wc = twr[m];
      float ws = (DIR == 0) ? twi[m] : -twi[m];
      int i0 = k*17 + col, i1 = (k+half)*17 + col;
      float are = reL[i0], aim = imL[i0];
      float bre = reL[i1], bim = imL[i1];
      reL[i0] = are + bre; imL[i0] = aim + bim;
      float tr = are - bre, ti = aim - bim;
      reL[i1] = tr*wc - ti*ws;
      imL[i1] = tr*ws + ti*wc;
    }
    __syncthreads();
  }
  int b = img >> 6, c = img & 63;
  int h = t; int src = (int)brev8((uint)h);
  if (DIR == 0){
    unsigned short* oa = (unsigned short*)out0;
    unsigned short* op = (unsigned short*)out1;
    int gy = h >> 2, py = h & 3;
    #pragma unroll
    for (int p = 0; p < 4; ++p){
      int base = src*17 + 4*p;
      float a0, a1, a2, a3, p0, p1, p2, p3;
      float rr, ii;
      rr = reL[base+0]; ii = imL[base+0]; a0 = sqrtf(rr*rr+ii*ii); p0 = atan2f(ii, rr);
      rr = reL[base+1]; ii = imL[base+1]; a1 = sqrtf(rr*rr+ii*ii); p1 = atan2f(ii, rr);
      rr = reL[base+2]; ii = imL[base+2]; a2 = sqrtf(rr*rr+ii*ii); p2 = atan2f(ii, rr);
      rr = reL[base+3]; ii = imL[base+3]; a3 = sqrtf(rr*rr+ii*ii); p3 = atan2f(ii, rr);
      size_t addr = ((size_t)(b*4096 + gy*64 + (c0>>2) + p))*1024 + c*16 + py*4;
      uint2 av, pv;
      av.x = (uint)f2bf(a0) | ((uint)f2bf(a1) << 16);
      av.y = (uint)f2bf(a2) | ((uint)f2bf(a3) << 16);
      pv.x = (uint)f2bf(p0) | ((uint)f2bf(p1) << 16);
      pv.y = (uint)f2bf(p2) | ((uint)f2bf(p3) << 16);
      *(uint2*)(oa + addr) = av;
      *(uint2*)(op + addr) = pv;
    }
  } else {
    float* op = (float*)out0 + ((size_t)img*256 + h)*256 + c0;
    #pragma unroll
    for (int p = 0; p < 4; ++p){
      int base = src*17 + 4*p;
      float4 v;
      v.x = reL[base+0]*(1.f/65536.f);
      v.y = reL[base+1]*(1.f/65536.f);
      v.z = reL[base+2]*(1.f/65536.f);
      v.w = reL[base+3]*(1.f/65536.f);
      *(float4*)(op + 4*p) = v;
    }
  }
}

// ---------------- transpose-convert: fp32 [K][N] -> bf16 [N][K], 10 mats ----------
struct TRS {
  const float* src[10];
  unsigned short* dst[10];
  int K[10], N[10];
  int start[11];
};
__global__ __launch_bounds__(256) void kern_tr(TRS p){
  __shared__ float lds[32][33];
  int bid = blockIdx.x;
  int e = 0;
  while (bid >= p.start[e+1]) ++e;
  int tloc = bid - p.start[e];
  int tilesN = p.N[e] >> 5;
  int tn = tloc % tilesN, tk = tloc / tilesN;
  int k0 = tk << 5, n0 = tn << 5;
  const float* src = p.src[e];
  unsigned short* dst = p.dst[e];
  int K = p.K[e], N = p.N[e];
  int r = threadIdx.x >> 5, c = threadIdx.x & 31;
  #pragma unroll
  for (int i = 0; i < 4; ++i)
    lds[r + 8*i][c] = src[(size_t)(k0 + r + 8*i)*N + n0 + c];
  __syncthreads();
  #pragma unroll
  for (int i = 0; i < 4; ++i)
    dst[(size_t)(n0 + r + 8*i)*K + k0 + c] = f2bf(lds[c][r + 8*i]);
}

// ---------------- mgemm2: BM=64 BN=128 BK=64, bf16 A + bf16 B^T, swizzled LDS -----
// AMODE: 1 cat(A0|A1) along K (1024 each), 2 gather rows via idx.  EPI: 0 plain, 1 h-epi.
struct GP2 {
  const unsigned short* A0[6];
  const unsigned short* A1[2];
  const unsigned short* Bt[6];
  float* Cm[6];
  const int* idxp[6];
  const float* ep0[2];
  const float* ep1[2];
  const float* ep2[2];
  int N, K;
};

template<int AMODE, int EPI>
__global__ __launch_bounds__(256) void kern_mgemm2(GP2 p){
  __shared__ __align__(16) unsigned short Asb[64*64];
  __shared__ __align__(16) unsigned short Bsb[128*64];
  __shared__ int idx_s[64];
  int z = blockIdx.z;
  const unsigned short* A0 = p.A0[z];
  const unsigned short* Bt = p.Bt[z];
  float* Cm = p.Cm[z];
  int tid = threadIdx.x;
  int m0 = blockIdx.x * 64;
  int n0 = blockIdx.y * 128;
  int lane = tid & 63, w = tid >> 6;
  int wr = w & 1, wc = w >> 1;
  int lr = lane & 15, ql = lane >> 4;

  if (AMODE == 2){
    if (tid < 64){
      int m = m0 + tid;
      idx_s[tid] = p.idxp[z][(m >> 10)*1024 + (m & 1023)];
    }
    __syncthreads();
  }
  int gb = m0 >> 10;

  f32x4 acc[2][4];
  #pragma unroll
  for (int i = 0; i < 2; ++i)
    #pragma unroll
    for (int j = 0; j < 4; ++j) acc[i][j] = (f32x4){0.f,0.f,0.f,0.f};

  int kh = tid & 7;
  int rA = tid >> 3;
  for (int k0 = 0; k0 < p.K; k0 += 64){
    #pragma unroll
    for (int s = 0; s < 2; ++s){
      int m = rA + 32*s;
      const unsigned short* ap;
      if (AMODE == 1){
        const unsigned short* srcp = (k0 < 1024) ? A0 : p.A1[z];
        ap = srcp + (size_t)(m0+m)*1024 + (k0 & 1023) + kh*8;
      } else {
        ap = A0 + ((size_t)(gb << 12) + idx_s[m])*(size_t)p.K + k0 + kh*8;
      }
      short8 v = *(const short8*)ap;
      int byte = m*128 + ((kh*16) ^ ((m & 7)*16));
      *(short8*)((char*)Asb + byte) = v;
    }
    #pragma unroll
    for (int s = 0; s < 4; ++s){
      int n = rA + 32*s;
      short8 v = *(const short8*)(Bt + (size_t)(n0+n)*p.K + k0 + kh*8);
      int byte = n*128 + ((kh*16) ^ ((n & 7)*16));
      *(short8*)((char*)Bsb + byte) = v;
    }
    __syncthreads();
    short8 af[2][2], bf[4][2];
    #pragma unroll
    for (int fm = 0; fm < 2; ++fm){
      int row = wr*32 + fm*16 + lr;
      #pragma unroll
      for (int kq = 0; kq < 2; ++kq){
        int byte = row*128 + ((kq*64 + ql*16) ^ ((row & 7)*16));
        af[fm][kq] = *(const short8*)((const char*)Asb + byte);
      }
    }
    #pragma unroll
    for (int fn = 0; fn < 4; ++fn){
      int row = wc*64 + fn*16 + lr;
      #pragma unroll
      for (int kq = 0; kq < 2; ++kq){
        int byte = row*128 + ((kq*64 + ql*16) ^ ((row & 7)*16));
        bf[fn][kq] = *(const short8*)((const char*)Bsb + byte);
      }
    }
    #pragma unroll
    for (int kq = 0; kq < 2; ++kq)
      #pragma unroll
      for (int fm = 0; fm < 2; ++fm)
        #pragma unroll
        for (int fn = 0; fn < 4; ++fn)
          acc[fm][fn] = __builtin_amdgcn_mfma_f32_16x16x32_bf16(af[fm][kq], bf[fn][kq],
                                                                acc[fm][fn], 0, 0, 0);
    __syncthreads();
  }

  #pragma unroll
  for (int fm = 0; fm < 2; ++fm){
    #pragma unroll
    for (int fn = 0; fn < 4; ++fn){
      int n = n0 + wc*64 + fn*16 + lr;
      #pragma unroll
      for (int reg = 0; reg < 4; ++reg){
        int m = m0 + wr*32 + fm*16 + ql*4 + reg;
        float v = acc[fm][fn][reg];
        if (EPI == 0){
          Cm[(size_t)m*p.N + n] = v;
        } else {
          int bl = m >> 12, g = m & 4095;
          int gy = g >> 6, gx = g & 63;
          float cy = ((float)gy + 0.5f)*(1.f/64.f);
          float cx = ((float)gx + 0.5f)*(1.f/64.f);
          float o = v + p.ep0[z][bl*128 + n] + cy*p.ep1[z][n]
                  + cx*p.ep1[z][128 + n] + p.ep2[z][n];
          Cm[(size_t)m*128 + n] = o;
        }
      }
    }
  }
}

// ---------------- mgemm3: bypass blend, BM=128 BN=128 BK=64, bf16 both, swizzled ---
struct GP3 {
  const unsigned short* A0[2];
  const unsigned short* A1[2];
  const unsigned short* Bt[2];
  float* Cm[2];
  const float* bias[2];
  const unsigned short* vt[2];
  const unsigned short* it[2];
  int K;
};

__global__ __launch_bounds__(256) void kern_mgemm3(GP3 p){
  __shared__ __align__(16) unsigned short Asb[128*64];
  __shared__ __align__(16) unsigned short Bsb[128*64];
  int z = blockIdx.z;
  const unsigned short* Bt = p.Bt[z];
  float* Cm = p.Cm[z];
  int tid = threadIdx.x;
  int m0 = blockIdx.x * 128;
  int n0 = blockIdx.y * 128;
  int lane = tid & 63, w = tid >> 6;
  int wr = w & 1, wc = w >> 1;
  int lr = lane & 15, ql = lane >> 4;

  f32x4 acc[4][4];
  #pragma unroll
  for (int i = 0; i < 4; ++i)
    #pragma unroll
    for (int j = 0; j < 4; ++j) acc[i][j] = (f32x4){0.f,0.f,0.f,0.f};

  int kh = tid & 7;
  int rA = tid >> 3;
  for (int k0 = 0; k0 < p.K; k0 += 64){
    const unsigned short* Asrc = (k0 < 1024) ? p.A0[z] : p.A1[z];
    int kk = (k0 & 1023) + kh*8;
    #pragma unroll
    for (int s = 0; s < 4; ++s){
      int m = rA + 32*s;
      short8 v = *(const short8*)(Asrc + (size_t)(m0+m)*1024 + kk);
      int byte = m*128 + ((kh*16) ^ ((m & 7)*16));
      *(short8*)((char*)Asb + byte) = v;
    }
    #pragma unroll
    for (int s = 0; s < 4; ++s){
      int n = rA + 32*s;
      short8 v = *(const short8*)(Bt + (size_t)(n0+n)*p.K + k0 + kh*8);
      int byte = n*128 + ((kh*16) ^ ((n & 7)*16));
      *(short8*)((char*)Bsb + byte) = v;
    }
    __syncthreads();
    short8 af[4][2], bf[4][2];
    #pragma unroll
    for (int fm = 0; fm < 4; ++fm){
      int row = wr*64 + fm*16 + lr;
      #pragma unroll
      for (int kq = 0; kq < 2; ++kq){
        int byte = row*128 + ((kq*64 + ql*16) ^ ((row & 7)*16));
        af[fm][kq] = *(const short8*)((const char*)Asb + byte);
      }
    }
    #pragma unroll
    for (int fn = 0; fn < 4; ++fn){
      int row = wc*64 + fn*16 + lr;
      #pragma unroll
      for (int kq = 0; kq < 2; ++kq){
        int byte = row*128 + ((kq*64 + ql*16) ^ ((row & 7)*16));
        bf[fn][kq] = *(const short8*)((const char*)Bsb + byte);
      }
    }
    #pragma unroll
    for (int kq = 0; kq < 2; ++kq)
      #pragma unroll
      for (int fm = 0; fm < 4; ++fm)
        #pragma unroll
        for (int fn = 0; fn < 4; ++fn)
          acc[fm][fn] = __builtin_amdgcn_mfma_f32_16x16x32_bf16(af[fm][kq], bf[fn][kq],
                                                                acc[fm][fn], 0, 0, 0);
    __syncthreads();
  }

  const unsigned short* vtp = p.vt[z];
  const unsigned short* itp = p.it[z];
  #pragma unroll
  for (int fm = 0; fm < 4; ++fm){
    #pragma unroll
    for (int fn = 0; fn < 4; ++fn){
      int n = n0 + wc*64 + fn*16 + lr;
      float bia = p.bias[z][n];
      #pragma unroll
      for (int reg = 0; reg < 4; ++reg){
        int m = m0 + wr*64 + fm*16 + ql*4 + reg;
        size_t off = (size_t)m*1024 + n;
        float vt = bf2f(vtp[off]);
        float it = bf2f(itp[off]);
        float gg = 1.f/(1.f + expf(-(acc[fm][fn][reg] + bia)));
        Cm[off] = gg*vt + (1.f-gg)*it;
      }
    }
  }
}

// ---------------- scatter GEMM: fused_sel = vs(bf16) + o@Wo, K=128 ----------------
struct SCP {
  const float* A0[2];
  const float* Bm[2];
  float* Cm[2];
  const int* idxp[2];
  const unsigned short* vtb[2];
};

__global__ __launch_bounds__(256) void kern_scat(SCP p){
  __shared__ __align__(16) unsigned short Asb[64*40];
  __shared__ __align__(16) unsigned short Bsb[128*40];
  __shared__ int idx_s[64];
  int z = blockIdx.z;
  const float* A0 = p.A0[z];
  const float* Bm = p.Bm[z];
  float* Cm = p.Cm[z];
  int tid = threadIdx.x;
  int m0 = blockIdx.y * 64;
  int n0 = blockIdx.x * 128;
  int lane = tid & 63, w = tid >> 6;
  int wr = w & 1, wc = w >> 1;
  int lr = lane & 15, ql = lane >> 4;
  if (tid < 64){
    int m = m0 + tid;
    idx_s[tid] = p.idxp[z][(m >> 10)*1024 + (m & 1023)];
  }
  __syncthreads();
  int gb = m0 >> 10;

  f32x4 acc[2][4];
  #pragma unroll
  for (int i = 0; i < 2; ++i)
    #pragma unroll
    for (int j = 0; j < 4; ++j) acc[i][j] = (f32x4){0.f,0.f,0.f,0.f};

  for (int k0 = 0; k0 < 128; k0 += 32){
    {
      int m = tid & 63;
      int khh = (tid >> 6) * 8;
      const float* ap = A0 + (size_t)(m0+m)*128 + k0 + khh;
      float4 f0 = *(const float4*)ap;
      float4 f1 = *(const float4*)(ap + 4);
      short8 v;
      v[0]=(short)f2bf(f0.x); v[1]=(short)f2bf(f0.y);
      v[2]=(short)f2bf(f0.z); v[3]=(short)f2bf(f0.w);
      v[4]=(short)f2bf(f1.x); v[5]=(short)f2bf(f1.y);
      v[6]=(short)f2bf(f1.z); v[7]=(short)f2bf(f1.w);
      *(short8*)&Asb[m*40 + khh] = v;
    }
    #pragma unroll
    for (int e0 = 0; e0 < 512; e0 += 256){
      int e = e0 + tid;
      int n = e & 127;
      int khh = (e >> 7) * 8;
      const float* bp = Bm + (size_t)(k0+khh)*1024 + n0 + n;
      short8 v;
      #pragma unroll
      for (int j = 0; j < 8; ++j) v[j] = (short)f2bf(bp[(size_t)j*1024]);
      *(short8*)&Bsb[n*40 + khh] = v;
    }
    __syncthreads();
    short8 af[2], bf[4];
    #pragma unroll
    for (int fr = 0; fr < 2; ++fr)
      af[fr] = *(const short8*)&Asb[(wr*32 + fr*16 + lr)*40 + ql*8];
    #pragma unroll
    for (int fc = 0; fc < 4; ++fc)
      bf[fc] = *(const short8*)&Bsb[(wc*64 + fc*16 + lr)*40 + ql*8];
    #pragma unroll
    for (int fr = 0; fr < 2; ++fr)
      #pragma unroll
      for (int fc = 0; fc < 4; ++fc)
        acc[fr][fc] = __builtin_amdgcn_mfma_f32_16x16x32_bf16(af[fr], bf[fc],
                                                              acc[fr][fc], 0, 0, 0);
    __syncthreads();
  }

  #pragma unroll
  for (int fr = 0; fr < 2; ++fr){
    #pragma unroll
    for (int fc = 0; fc < 4; ++fc){
      int n = n0 + wc*64 + fc*16 + lr;
      #pragma unroll
      for (int reg = 0; reg < 4; ++reg){
        int mloc = wr*32 + fr*16 + ql*4 + reg;
        int gt = idx_s[mloc];
        size_t off = ((size_t)(gb << 12) + gt)*1024 + n;
        Cm[off] = acc[fr][fc][reg] + bf2f(p.vtb[z][off]);
      }
    }
  }
}

// ---------------- score ----------------
__global__ __launch_bounds__(64) void kern_score(const float* __restrict__ h,
    const float* __restrict__ wout, const float* __restrict__ bout,
    float* __restrict__ score, int Mper){
  int m = blockIdx.x, br = blockIdx.y, t = threadIdx.x;
  const float* hp = h + ((size_t)br*Mper + m)*128;
  const float* wp = wout + br*128;
  float s = geluf(hp[t])*wp[t] + geluf(hp[t+64])*wp[t+64];
  #pragma unroll
  for (int off = 32; off > 0; off >>= 1) s += __shfl_down(s, off);
  if (t == 0) score[(size_t)br*Mper + m] = s + bout[br];
}

// ---------------- top-1024 of 4096 (bitonic, jax tie-break) ----------------
__global__ __launch_bounds__(1024) void kern_topk(const float* __restrict__ score,
    int* __restrict__ idx_out){
  __shared__ u64 keys[4096];
  int b = blockIdx.x, t = threadIdx.x;
  for (int i = t; i < 4096; i += 1024){
    float s = score[b*4096 + i];
    uint u = __float_as_uint(s);
    uint msk = (u & 0x80000000u) ? ~u : (u | 0x80000000u);
    keys[i] = ((u64)msk << 32) | (uint)(4095 - i);
  }
  __syncthreads();
  for (int k = 2; k <= 4096; k <<= 1){
    for (int j = k >> 1; j > 0; j >>= 1){
      for (int i = t; i < 4096; i += 1024){
        int l = i ^ j;
        if (l > i){
          u64 a = keys[i], c = keys[l];
          bool descB = ((i & k) == 0);
          bool sw = descB ? (a < c) : (a > c);
          if (sw){ keys[i] = c; keys[l] = a; }
        }
      }
      __syncthreads();
    }
  }
  idx_out[b*1024 + t] = 4095 - (int)(keys[t] & 0xFFFFFFFFu);
}

// ---------------- attention partials (k-split flash, 128-thr q-split) ----------
__global__ __launch_bounds__(128) void kern_attn_part(const float* __restrict__ qb,
    const float* __restrict__ kb, const float* __restrict__ vb,
    float* __restrict__ paoa, float* __restrict__ pml){
  __shared__ float Ks[64][32];
  __shared__ float Vs[64][32];
  int t = threadIdx.x;
  int hh = blockIdx.y;
  int zc = blockIdx.z;
  int zf = zc >> 2, c = zc & 3;
  size_t boff = (size_t)zf*131072;
  int jq = blockIdx.x*128 + t;
  float qv[32];
  {
    const float4* qp = (const float4*)(qb + boff + (size_t)jq*128 + hh*32);
    #pragma unroll
    for (int d = 0; d < 8; ++d) ((float4*)qv)[d] = qp[d];
  }
  float mrun = -3.0e38f, lrun = 0.f;
  float oa[32];
  #pragma unroll
  for (int d = 0; d < 32; ++d) oa[d] = 0.f;
  for (int kt = 0; kt < 4; ++kt){
    int k0 = c*256 + kt*64;
    #pragma unroll
    for (int rep = 0; rep < 4; ++rep){
      int f = t + rep*128;
      int r = f >> 3, q4 = f & 7;
      size_t base = boff + (size_t)(k0 + r)*128 + hh*32 + 4*q4;
      *(float4*)&Ks[r][4*q4] = *(const float4*)(kb + base);
      *(float4*)&Vs[r][4*q4] = *(const float4*)(vb + base);
    }
    __syncthreads();
    #pragma unroll
    for (int st = 0; st < 4; ++st){
      float s[16];
      #pragma unroll
      for (int j = 0; j < 16; ++j){
        float v = 0.f;
        #pragma unroll
        for (int d = 0; d < 32; ++d) v += qv[d]*Ks[st*16+j][d];
        s[j] = v * 0.17677669529663687f;
      }
      float mt = s[0];
      #pragma unroll
      for (int j = 1; j < 16; ++j) mt = fmaxf(mt, s[j]);
      float mnew = fmaxf(mrun, mt);
      float alpha = expf(mrun - mnew);
      lrun *= alpha;
      #pragma unroll
      for (int d = 0; d < 32; ++d) oa[d] *= alpha;
      #pragma unroll
      for (int j = 0; j < 16; ++j){
        float pe = expf(s[j] - mnew);
        lrun += pe;
        #pragma unroll
        for (int d = 0; d < 32; ++d) oa[d] += pe*Vs[st*16+j][d];
      }
      mrun = mnew;
    }
    __syncthreads();
  }
  size_t rec = (((size_t)zf*4 + hh)*4 + c)*1024 + jq;
  float* pp = paoa + rec*32;
  #pragma unroll
  for (int d = 0; d < 8; ++d) ((float4*)pp)[d] = ((float4*)oa)[d];
  pml[rec*2]   = mrun;
  pml[rec*2+1] = lrun;
}

// ---------------- attention combine ----------------
__global__ __launch_bounds__(256) void kern_attn_comb(const float* __restrict__ paoa,
    const float* __restrict__ pml, float* __restrict__ ob,
    const float* __restrict__ ipint, int PB, int b0){
  int t = threadIdx.x;
  int hh = blockIdx.y, zf = blockIdx.z;
  int jq = blockIdx.x*256 + t;
  size_t rbase = (((size_t)zf*4 + hh)*4)*1024 + jq;
  float mc[4], lc[4];
  #pragma unroll
  for (int c = 0; c < 4; ++c){
    mc[c] = pml[(rbase + c*1024)*2];
    lc[c] = pml[(rbase + c*1024)*2 + 1];
  }
  float M = fmaxf(fmaxf(mc[0], mc[1]), fmaxf(mc[2], mc[3]));
  float wgt[4], L = 0.f;
  #pragma unroll
  for (int c = 0; c < 4; ++c){ wgt[c] = expf(mc[c] - M); L += lc[c]*wgt[c]; }
  float inv = 1.f/L;
  int br = (zf >= PB) ? 1 : 0;
  int bb = zf - br*PB;
  const float* ip = ipint + br*512 + (b0+bb)*128 + hh*32;
  float* op = ob + (size_t)zf*131072 + (size_t)jq*128 + hh*32;
  #pragma unroll
  for (int d = 0; d < 32; ++d){
    float o = 0.f;
    #pragma unroll
    for (int c = 0; c < 4; ++c) o += paoa[(rbase + c*1024)*32 + d]*wgt[c];
    op[d] = o*inv + ip[d];
  }
}

// ---------------- conv weight transform ----------------
__global__ __launch_bounds__(256) void kern_wt(const float* __restrict__ w1,
    const float* __restrict__ w2, unsigned short* __restrict__ wt){
  int blk = blockIdx.x;
  const float* src = (blk < 9) ? w1 : w2;
  int tap = blk - (blk < 9 ? 0 : 9);
  unsigned short* dst = wt + (blk < 9 ? 0 : 36864) + tap*4096;
  for (int e = threadIdx.x; e < 4096; e += 256){
    dst[e] = f2bf(src[(size_t)e*9 + tap]);
  }
}

// ---------------- implicit-GEMM 3x3 conv via MFMA ----------------
template<int MODE>
__global__ __launch_bounds__(256) void kern_cmfma(const float* __restrict__ in,
    const unsigned short* __restrict__ wt, const float* __restrict__ bias,
    float* __restrict__ out,
    const float* __restrict__ modg, const float* __restrict__ modb,
    const float* __restrict__ vis, const float* __restrict__ irf){
  __shared__ __align__(16) unsigned short ins[64][268];
  int t = threadIdx.x;
  int y = blockIdx.x, b = blockIdx.y;
  int lane = t & 63, w = t >> 6;
  int wc = w & 1, wx = w >> 1;
  int lr = lane & 15, ql = lane >> 4;

  f32x4 acc[2][8];
  #pragma unroll
  for (int f = 0; f < 2; ++f)
    #pragma unroll
    for (int xf = 0; xf < 8; ++xf) acc[f][xf] = (f32x4){0.f,0.f,0.f,0.f};

  for (int dy = 0; dy < 3; ++dy){
    int yy = y + dy - 1;
    if (yy < 0 || yy > 255) continue;
    const float* src = in + ((size_t)(b*64)*256 + yy)*256;
    #pragma unroll
    for (int s = 0; s < 16; ++s){
      int e = t + s*256;
      int ci = e >> 6, q = e & 63;
      float4 f4 = *(const float4*)(src + (size_t)ci*65536 + 4*q);
      uint lo = (uint)f2bf(f4.x) | ((uint)f2bf(f4.y) << 16);
      uint hi = (uint)f2bf(f4.z) | ((uint)f2bf(f4.w) << 16);
      *(uint2*)&ins[ci][4*q + 4] = make_uint2(lo, hi);
    }
    if (t < 128){
      int r = t & 63;
      ins[r][(t >> 6) ? 260 : 3] = 0;
    }
    __syncthreads();
    short8 wf[2][3][2];
    #pragma unroll
    for (int kk = 0; kk < 2; ++kk)
      #pragma unroll
      for (int dx = 0; dx < 3; ++dx)
        #pragma unroll
        for (int f = 0; f < 2; ++f)
          wf[kk][dx][f] = *(const short8*)(wt +
            (size_t)((dy*3 + dx)*64 + 32*wc + 16*f + lr)*64 + kk*32 + ql*8);
    #pragma unroll
    for (int kk = 0; kk < 2; ++kk){
      const unsigned short* bp = &ins[kk*32 + ql*8][0];
      #pragma unroll
      for (int dx = 0; dx < 3; ++dx){
        int xb = 128*wx + lr + dx + 3;
        #pragma unroll
        for (int xf = 0; xf < 8; ++xf){
          int xi = xb + 16*xf;
          short8 bf;
          #pragma unroll
          for (int e = 0; e < 8; ++e) bf[e] = (short)bp[e*268 + xi];
          acc[0][xf] = __builtin_amdgcn_mfma_f32_16x16x32_bf16(wf[kk][dx][0], bf,
                                                               acc[0][xf], 0, 0, 0);
          acc[1][xf] = __builtin_amdgcn_mfma_f32_16x16x32_bf16(wf[kk][dx][1], bf,
                                                               acc[1][xf], 0, 0, 0);
        }
      }
    }
    __syncthreads();
  }

  #pragma unroll
  for (int f = 0; f < 2; ++f){
    #pragma unroll
    for (int xf = 0; xf < 8; ++xf){
      int x = 128*wx + 16*xf + lr;
      #pragma unroll
      for (int reg = 0; reg < 4; ++reg){
        int co = 32*wc + 16*f + ql*4 + reg;
        float v = acc[f][xf][reg] + bias[co];
        size_t oi = ((size_t)(b*64 + co)*256 + y)*256 + x;
        if (MODE == 1){
          out[oi] = fmaxf(v, 0.f);
        } else {
          out[oi] = v*modg[b*64+co] + modb[b*64+co] + 0.5f*(vis[oi] + irf[oi]);
        }
      }
    }
  }
}

// ---------------- launch ----------------
extern "C" void kernel_launch(void* const* d_in, const int* in_sizes, int n_in,
                              void* d_out, int out_size, void* d_ws, size_t ws_size,
                              hipStream_t stream){
  (void)in_sizes; (void)n_in; (void)out_size;
  const float* vis  = (const float*)d_in[0];
  const float* irf  = (const float*)d_in[1];
  const float* bank = (const float*)d_in[2];
  const float* Wr   = (const float*)d_in[3];
  const float* br   = (const float*)d_in[4];
  const float* Wtok = (const float*)d_in[5];
  const float* Wpri = (const float*)d_in[6];
  const float* Wco  = (const float*)d_in[7];
  const float* bs   = (const float*)d_in[8];
  const float* Wout = (const float*)d_in[9];
  const float* bout = (const float*)d_in[10];
  const float* Wq   = (const float*)d_in[11];
  const float* Wk   = (const float*)d_in[12];
  const float* Wv   = (const float*)d_in[13];
  const float* Wo   = (const float*)d_in[14];
  const float* Wint = (const float*)d_in[15];
  const float* Wbyp = (const float*)d_in[16];
  const float* bbyp = (const float*)d_in[17];
  const float* c1w  = (const float*)d_in[18];
  const float* c1b  = (const float*)d_in[19];
  const float* c2w  = (const float*)d_in[20];
  const float* c2b  = (const float*)d_in[21];
  const float* Wa1  = (const float*)d_in[22];
  const float* ba1  = (const float*)d_in[23];
  const float* Wa2  = (const float*)d_in[24];
  const float* ba2  = (const float*)d_in[25];

  // EXACT usage in floats: 3 plane-equivalents (PH4 fp32 + bf16 region aliased by
  // S0/S1) + per-PB small buffers + BT + persistents.
  // floats(PB) = PB*14,755,840 + 2,792,448  (PB=1: 70.2MB, 2: 129.2MB, 4: 247.3MB)
  auto needB = [](int PB)->size_t{
    return ((size_t)PB*14755840 + 2792448) * 4;
  };
  const int PB = (ws_size >= needB(4)) ? 4 : (ws_size >= needB(2)) ? 2 : 1;

  float* ws = (float*)d_ws;
  const size_t PLF = (size_t)PB*4194304;           // one fp32 plane (floats)
  float* PH4 = ws;                                 // fwd im transient + FULL_ph
  unsigned short* ABV = (unsigned short*)(ws + PLF);   // 4 bf16 planes = 2*PLF floats
  unsigned short* PBV = ABV + PLF;
  unsigned short* ABI = PBV + PLF;
  unsigned short* PBI = ABI + PLF;
  float* S0 = ws + PLF;                            // iFFT transients ALIAS bf16 region
  float* S1 = S0 + PLF;                            //  (bf16 planes dead by iFFT time)
  float* sm = ws + 3*PLF;
  float* hbuf  = sm; sm += (size_t)2*PB*524288;    // h; later aliased by paoa
  float* qbuf  = sm; sm += (size_t)2*PB*131072;
  float* kbuf  = sm; sm += (size_t)2*PB*131072;
  float* vbuf  = sm; sm += (size_t)2*PB*131072;
  float* obuf  = sm; sm += (size_t)2*PB*131072;
  float* score = sm; sm += (size_t)2*PB*4096;
  int*   idxb  = (int*)sm; sm += (size_t)2*PB*1024;
  float* pml   = sm; sm += (size_t)PB*65536;
  unsigned short* BTtok = (unsigned short*)sm;     // [2][128][2048]
  unsigned short* BTbyp = BTtok + 524288;          // [2][1024][2048]
  unsigned short* BTq   = BTbyp + 4194304;         // [2][128][1024]
  unsigned short* BTk   = BTq + 262144;
  unsigned short* BTv   = BTk + 262144;
  sm += 2752512;
  // persistents (live until the convs; conv1 dst covers ws[0..16,777,216) floats —
  // for PB=1 these start at 17,508,352 > that; for PB>=2 far beyond)
  float* pooled= sm; sm += 512;
  float* IP    = sm; sm += 1024;
  float* IPint = sm; sm += 1024;
  float* modg  = sm; sm += 256;
  float* modb  = sm; sm += 256;
  unsigned short* wtb = (unsigned short*)sm; sm += 36864;  // [2][9][64][64] bf16
  float* paoa = hbuf;

  kern_pool <<<512, 256, 0, stream>>>(vis, irf, pooled);
  kern_small<<<1, 256, 0, stream>>>(pooled, Wr, br, bank, Wpri, Wint,
                                    Wa1, ba1, Wa2, ba2, IP, IPint, modg, modb);
  kern_wt   <<<18, 256, 0, stream>>>(c1w, c2w, wtb);
  {
    TRS tr{};
    const float* srcs[10] = {Wtok, Wtok+262144, Wbyp, Wbyp+2097152,
                             Wq, Wq+131072, Wk, Wk+131072, Wv, Wv+131072};
    unsigned short* dsts[10] = {BTtok, BTtok+262144, BTbyp, BTbyp+2097152,
                                BTq, BTq+131072, BTk, BTk+131072, BTv, BTv+131072};
    int Ks[10] = {2048,2048,2048,2048,1024,1024,1024,1024,1024,1024};
    int Ns[10] = {128,128,1024,1024,128,128,128,128,128,128};
    int tiles[10] = {256,256,2048,2048,128,128,128,128,128,128};
    int acc0 = 0;
    for (int i = 0; i < 10; ++i){
      tr.src[i] = srcs[i]; tr.dst[i] = dsts[i];
      tr.K[i] = Ks[i]; tr.N[i] = Ns[i];
      tr.start[i] = acc0; acc0 += tiles[i];
    }
    tr.start[10] = acc0;
    kern_tr<<<acc0, 256, 0, stream>>>(tr);
  }

  for (int b0 = 0; b0 < 4; b0 += PB){
    const float* vis_b = vis + (size_t)b0*4194304;
    const float* ir_b  = irf + (size_t)b0*4194304;
    float* OUT = (float*)d_out + (size_t)b0*4194304;  // re transient / FULL_amp / spatial

    // forward FFT2 -> bf16 amp/ph (patchified)
    kern_fft_rows_fwd<<<PB*8192, 256, 0, stream>>>(vis_b, OUT, PH4);
    kern_fft_cols<0> <<<PB*1024, 256, 0, stream>>>(OUT, PH4, ABV, PBV);
    kern_fft_rows_fwd<<<PB*8192, 256, 0, stream>>>(ir_b, OUT, PH4);
    kern_fft_cols<0> <<<PB*1024, 256, 0, stream>>>(OUT, PH4, ABI, PBI);

    {  // h = cat(vt,it)@Wtok + IP + coords@Wco + bs
      GP2 p{};
      p.A0[0]=ABV; p.A1[0]=ABI; p.A0[1]=PBV; p.A1[1]=PBI;
      for (int z = 0; z < 2; ++z){
        p.Bt[z] = BTtok + (size_t)z*262144;
        p.Cm[z] = hbuf + (size_t)z*PB*524288;
        p.ep0[z] = IP + z*512 + b0*128;
        p.ep1[z] = Wco + z*256;
        p.ep2[z] = bs + z*128;
      }
      p.N = 128; p.K = 2048;
      kern_mgemm2<1,1><<<dim3(PB*64, 1, 2), 256, 0, stream>>>(p);
    }
    kern_score<<<dim3(PB*4096, 2), 64, 0, stream>>>(hbuf, Wout, bout, score, PB*4096);
    kern_topk <<<2*PB, 1024, 0, stream>>>(score, idxb);
    {  // bypass blend -> FULL (amp: OUT fp32, ph: PH4 fp32)
      GP3 p{};
      p.A0[0]=ABV; p.A1[0]=ABI; p.A0[1]=PBV; p.A1[1]=PBI;
      p.vt[0]=ABV; p.it[0]=ABI; p.vt[1]=PBV; p.it[1]=PBI;
      p.Cm[0]=OUT; p.Cm[1]=PH4;
      for (int z = 0; z < 2; ++z){
        p.Bt[z] = BTbyp + (size_t)z*2097152;
        p.bias[z] = bbyp + z*1024;
      }
      p.K = 2048;
      kern_mgemm3<<<dim3(PB*32, 8, 2), 256, 0, stream>>>(p);
    }
    {  // q,k,v gathered rows
      GP2 p{};
      const unsigned short* Aplanes[6] = {ABV, ABI, ABI, PBV, PBI, PBI};
      const unsigned short* Bmats[6] = {BTq, BTk, BTv,
                                        BTq+131072, BTk+131072, BTv+131072};
      float* Cms[6] = {qbuf, kbuf, vbuf,
                       qbuf+(size_t)PB*131072, kbuf+(size_t)PB*131072,
                       vbuf+(size_t)PB*131072};
      for (int z = 0; z < 6; ++z){
        p.A0[z] = Aplanes[z]; p.Bt[z] = Bmats[z]; p.Cm[z] = Cms[z];
        p.idxp[z] = idxb + (z < 3 ? 0 : PB*1024);
      }
      p.N = 128; p.K = 1024;
      kern_mgemm2<2,0><<<dim3(PB*16, 1, 6), 256, 0, stream>>>(p);
    }
    // k-split flash attention (h dead -> paoa aliases hbuf)
    kern_attn_part<<<dim3(8, 4, 2*PB*4), 128, 0, stream>>>(qbuf, kbuf, vbuf,
                                                           paoa, pml);
    kern_attn_comb<<<dim3(4, 4, 2*PB), 256, 0, stream>>>(paoa, pml, obuf,
                                                         IPint, PB, b0);
    {  // fused_sel = vs(bf16) + o@Wo, scatter into FULL
      SCP p{};
      p.A0[0]=obuf; p.A0[1]=obuf+(size_t)PB*131072;
      p.Bm[0]=Wo; p.Bm[1]=Wo+131072;
      p.Cm[0]=OUT; p.Cm[1]=PH4;
      p.vtb[0]=ABV; p.vtb[1]=PBV;
      p.idxp[0]=idxb; p.idxp[1]=idxb+PB*1024;
      kern_scat<<<dim3(8, PB*16, 2), 256, 0, stream>>>(p);
    }

    // spec = famp*e^{i fph}; inverse FFT2 -> spatial into OUT
    // (bf16 planes dead here -> S0/S1 alias them)
    kern_ifft_rows_spec<<<PB*4096, 256, 0, stream>>>(OUT, PH4, S0, S1);
    kern_fft_cols<1>   <<<PB*1024, 256, 0, stream>>>(S0, S1, OUT, nullptr);
  }

  // convs (MFMA): d_out(spatial) -> ws[0..16.78M floats) (conv1+relu) -> d_out
  kern_cmfma<1><<<dim3(256, 4), 256, 0, stream>>>((float*)d_out, wtb, c1b, ws,
                                                  nullptr, nullptr, nullptr, nullptr);
  kern_cmfma<2><<<dim3(256, 4), 256, 0, stream>>>(ws, wtb + 36864, c2b, (float*)d_out,
                                                  modg, modb, vis, irf);
}